// Round 12
// baseline (441.825 us; speedup 1.0000x reference)
//
#include <hip/hip_runtime.h>
#include <hip/hip_bf16.h>
#include <math.h>

#define DD 128

typedef __attribute__((ext_vector_type(8))) short short8;
typedef __attribute__((ext_vector_type(4))) float f32x4;

// ---------- helpers ----------

__device__ __forceinline__ unsigned short f2b(float f) {
    unsigned u = __float_as_uint(f);
    return (unsigned short)((u + 0x7FFFu + ((u >> 16) & 1u)) >> 16);
}
__device__ __forceinline__ float b2f(unsigned short b) {
    return __uint_as_float(((unsigned)b) << 16);
}
__device__ __forceinline__ unsigned packbf(float a, float b) {
    return (unsigned)f2b(a) | ((unsigned)f2b(b) << 16);
}

__device__ __forceinline__ void redsum2_128(float& a, float& b) {
    #pragma unroll
    for (int off = 32; off > 0; off >>= 1) {
        a += __shfl_down(a, off);
        b += __shfl_down(b, off);
    }
    __shared__ float sa[2], sb[2];
    int w = threadIdx.x >> 6;
    if ((threadIdx.x & 63) == 0) { sa[w] = a; sb[w] = b; }
    __syncthreads();
    a = sa[0] + sa[1];
    b = sb[0] + sb[1];
    __syncthreads();
}

// ---------- weight packing ----------
// Packed blob (8192 u32): Bt[((n<<6)+kp)^((n&7)<<2)] = bf16pair(W[2kp][n], W[2kp+1][n])

__global__ void packw12_kernel(const float* __restrict__ Wq, const float* __restrict__ Wk,
                               const float* __restrict__ Wv, const float* __restrict__ Ws,
                               unsigned* __restrict__ Wp) {
    int bid = blockIdx.x, y = blockIdx.y, d = threadIdx.x;  // 64 x 12, 128 thr
    int l = y >> 2, wt = y & 3;
    const float* W = (wt == 0 ? Wq : wt == 1 ? Wk : wt == 2 ? Wv : Ws) + (size_t)l * DD * DD;
    float w0 = W[(size_t)(2 * bid) * DD + d];
    float w1 = W[(size_t)(2 * bid + 1) * DD + d];
    Wp[y * 8192 + (((d << 6) + bid) ^ ((d & 7) << 2))] = packbf(w0, w1);
}

// folded edge weight W2@We_y packed; block 64 = bias fold (f32)
__global__ void wcombp_kernel(const float* __restrict__ W2, const float* __restrict__ b2,
                              const float* __restrict__ We, unsigned* __restrict__ Wp,
                              float* __restrict__ b2We) {
    int bid = blockIdx.x, y = blockIdx.y, d = threadIdx.x;  // 65 x 3 blocks, 128 thr
    const float* We_l = We + (size_t)y * DD * DD;
    __shared__ float sa0[DD], sa1[DD];
    if (bid < 64) { sa0[d] = W2[(2 * bid) * DD + d]; sa1[d] = W2[(2 * bid + 1) * DD + d]; }
    else          { sa0[d] = b2[d]; sa1[d] = 0.f; }
    __syncthreads();
    float acc0 = 0.f, acc1 = 0.f;
    #pragma unroll 8
    for (int kk = 0; kk < DD; ++kk) {
        float w = We_l[kk * DD + d];
        acc0 += sa0[kk] * w;
        acc1 += sa1[kk] * w;
    }
    if (bid < 64) Wp[y * 8192 + (((d << 6) + bid) ^ ((d & 7) << 2))] = packbf(acc0, acc1);
    else          b2We[y * DD + d] = acc0;
}

// ---------- merged projection kernel: ee GEMM (on-the-fly A) + q/k/v/skip GEMMs ----------
// qkv row layout: [q pairs 0:64) | interleaved (k-pair, v-pair) 64:192) ]
struct B4 { const float* b[4]; };

__global__ __launch_bounds__(256) void proj_kernel(
        const unsigned short* __restrict__ xb, const unsigned* __restrict__ Wp4, B4 bias,
        unsigned short* __restrict__ qkv, float* __restrict__ rbuf, int rowsN, int rtN,
        const float4* __restrict__ rel4, const float* __restrict__ pw,
        const float* __restrict__ bbp, const unsigned* __restrict__ Wpee,
        const float* __restrict__ biasee, unsigned short* __restrict__ eeout,
        int rowsE, int rtE) {
    __shared__ unsigned Bt[8192];
    __shared__ float sc[640];
    const int t = threadIdx.x;
    const int lane = t & 63, wid = t >> 6;
    const int kqo = (lane >> 4) * 8;

    if ((int)blockIdx.x < rtE) {
        const int rowBase = (int)blockIdx.x << 6;
        #pragma unroll
        for (int i = 0; i < 8; ++i)
            *(uint4*)&Bt[(i * 256 + t) * 4] = *(const uint4*)&Wpee[(i * 256 + t) * 4];
        for (int i = t; i < 640; i += 256)
            sc[i] = (i < 512) ? pw[i] : bbp[i - 512];
        int arow = rowBase + wid * 16 + (lane & 15);
        if (arow > rowsE - 1) arow = rowsE - 1;
        float4 rv = rel4[arow];
        __syncthreads();
        short8 a[4];
        #pragma unroll
        for (int kc = 0; kc < 4; ++kc) {
            union { short8 s; unsigned short u[8]; } cv;
            #pragma unroll
            for (int j = 0; j < 8; ++j) {
                int d = kc * 32 + kqo + j;
                float y = fmaf(rv.x, sc[d], fmaf(rv.y, sc[128 + d], fmaf(rv.z, sc[256 + d], sc[384 + d])));
                cv.u[j] = f2b(fmaxf(fmaf(y, rv.w, sc[512 + d]), 0.f));
            }
            a[kc] = cv.s;
        }
        f32x4 acc[8];
        #pragma unroll
        for (int i = 0; i < 8; ++i) acc[i] = (f32x4){0.f, 0.f, 0.f, 0.f};
        #pragma unroll
        for (int ng = 0; ng < 8; ++ng) {
            int col = ng * 16 + (lane & 15);
            #pragma unroll
            for (int kc = 0; kc < 4; ++kc) {
                int kidx = kc * 16 + (lane >> 4) * 4;
                const short8 b = *(const short8*)((const char*)Bt +
                        ((((col << 6) + kidx) ^ ((col & 7) << 2)) << 2));
                acc[ng] = __builtin_amdgcn_mfma_f32_16x16x32_bf16(a[kc], b, acc[ng], 0, 0, 0);
            }
        }
        __syncthreads();
        unsigned short* sb16 = (unsigned short*)Bt;
        #pragma unroll
        for (int ng = 0; ng < 8; ++ng) {
            int col = ng * 16 + (lane & 15);
            float bv = biasee[col];
            int cp = col >> 1, cb = col & 1;
            #pragma unroll
            for (int r = 0; r < 4; ++r) {
                int row = wid * 16 + (lane >> 4) * 4 + r;
                sb16[((row << 6) + (cp ^ ((row & 7) << 2))) * 2 + cb] = f2b(acc[ng][r] + bv);
            }
        }
        __syncthreads();
        unsigned* outw = (unsigned*)eeout;
        #pragma unroll
        for (int i = 0; i < 4; ++i) {
            int j = i * 1024 + t * 4;
            int row = j >> 6, cp = j & 63;
            uint4 v = *(const uint4*)&Bt[(row << 6) + (cp ^ ((row & 7) << 2))];
            int grow = rowBase + row;
            if (grow < rowsE) *(uint4*)&outw[(size_t)grow * 64 + cp] = v;
        }
    } else {
        int bidx = (int)blockIdx.x - rtE;
        const int y = bidx / rtN;
        const int rowBase = (bidx % rtN) << 6;
        const unsigned* Wp = Wp4 + y * 8192;
        #pragma unroll
        for (int i = 0; i < 8; ++i)
            *(uint4*)&Bt[(i * 256 + t) * 4] = *(const uint4*)&Wp[(i * 256 + t) * 4];
        int arow = rowBase + wid * 16 + (lane & 15);
        if (arow > rowsN - 1) arow = rowsN - 1;
        short8 a[4];
        #pragma unroll
        for (int kc = 0; kc < 4; ++kc)
            a[kc] = *(const short8*)(xb + (size_t)arow * DD + kc * 32 + kqo);
        __syncthreads();
        f32x4 acc[8];
        #pragma unroll
        for (int i = 0; i < 8; ++i) acc[i] = (f32x4){0.f, 0.f, 0.f, 0.f};
        #pragma unroll
        for (int ng = 0; ng < 8; ++ng) {
            int col = ng * 16 + (lane & 15);
            #pragma unroll
            for (int kc = 0; kc < 4; ++kc) {
                int kidx = kc * 16 + (lane >> 4) * 4;
                const short8 b = *(const short8*)((const char*)Bt +
                        ((((col << 6) + kidx) ^ ((col & 7) << 2)) << 2));
                acc[ng] = __builtin_amdgcn_mfma_f32_16x16x32_bf16(a[kc], b, acc[ng], 0, 0, 0);
            }
        }
        const float* bs = bias.b[y];
        if (y == 3) {
            #pragma unroll
            for (int ng = 0; ng < 8; ++ng) {
                int col = ng * 16 + (lane & 15);
                float bv = bs[col];
                #pragma unroll
                for (int r = 0; r < 4; ++r) {
                    int grow = rowBase + wid * 16 + (lane >> 4) * 4 + r;
                    if (grow < rowsN) rbuf[(size_t)grow * DD + col] = acc[ng][r] + bv;
                }
            }
            return;
        }
        __syncthreads();
        unsigned short* sb16 = (unsigned short*)Bt;
        #pragma unroll
        for (int ng = 0; ng < 8; ++ng) {
            int col = ng * 16 + (lane & 15);
            float bv = bs[col];
            int cp = col >> 1, cb = col & 1;
            #pragma unroll
            for (int r = 0; r < 4; ++r) {
                int row = wid * 16 + (lane >> 4) * 4 + r;
                sb16[((row << 6) + (cp ^ ((row & 7) << 2))) * 2 + cb] = f2b(acc[ng][r] + bv);
            }
        }
        __syncthreads();
        unsigned* outw = (unsigned*)qkv;
        if (y == 0) {
            #pragma unroll
            for (int i = 0; i < 4; ++i) {
                int j = i * 1024 + t * 4;
                int row = j >> 6, cp = j & 63;
                uint4 v = *(const uint4*)&Bt[(row << 6) + (cp ^ ((row & 7) << 2))];
                int grow = rowBase + row;
                if (grow < rowsN) *(uint4*)&outw[(size_t)grow * 192 + cp] = v;
            }
        } else {
            // kv-interleave: k pair -> 64+2cp, v pair -> 64+2cp+1
            const int sub = y - 1;  // 0 for k, 1 for v
            #pragma unroll
            for (int i = 0; i < 4; ++i) {
                int j = i * 1024 + t * 4;
                int row = j >> 6, cp = j & 63;
                uint4 v = *(const uint4*)&Bt[(row << 6) + (cp ^ ((row & 7) << 2))];
                int grow = rowBase + row;
                if (grow < rowsN) {
                    unsigned* base = &outw[(size_t)grow * 192 + 64 + 2 * cp + sub];
                    base[0] = v.x; base[2] = v.y; base[4] = v.z; base[6] = v.w;
                }
            }
        }
    }
}

// ---------- generic MFMA GEMM (f32 weights, bf16 A), bf16 out (used by heads) ----------
template <int ACT>
__global__ __launch_bounds__(256) void mgemm(
        const unsigned short* __restrict__ A, const float* __restrict__ W,
        const float* __restrict__ bias, unsigned short* __restrict__ out,
        int rows, int K, int Dout) {
    __shared__ unsigned Bt[8192];
    const int t = threadIdx.x;
    const int rowBase = blockIdx.x << 6;
    const int colBase = blockIdx.y << 7;
    const int lane = t & 63, wid = t >> 6;
    f32x4 acc[8];
    #pragma unroll
    for (int i = 0; i < 8; ++i) acc[i] = (f32x4){0.f, 0.f, 0.f, 0.f};
    int arow = rowBase + wid * 16 + (lane & 15);
    if (arow > rows - 1) arow = rows - 1;
    const int kqo = (lane >> 4) * 8;
    for (int k0 = 0; k0 < K; k0 += 128) {
        if (k0) __syncthreads();
        #pragma unroll 8
        for (int it = 0; it < 32; ++it) {
            int idx = it * 256 + t;
            int n = idx & 127, kp = idx >> 7;
            int krow = k0 + kp * 2;
            float w0 = W[(size_t)krow * Dout + colBase + n];
            float w1 = W[(size_t)(krow + 1) * Dout + colBase + n];
            Bt[((n << 6) + kp) ^ ((n & 7) << 2)] = packbf(w0, w1);
        }
        __syncthreads();
        short8 a[4];
        #pragma unroll
        for (int kc = 0; kc < 4; ++kc)
            a[kc] = *(const short8*)(A + (size_t)arow * K + k0 + kc * 32 + kqo);
        #pragma unroll
        for (int ng = 0; ng < 8; ++ng) {
            int col = ng * 16 + (lane & 15);
            #pragma unroll
            for (int kc = 0; kc < 4; ++kc) {
                int kidx = kc * 16 + (lane >> 4) * 4;
                const short8 b = *(const short8*)((const char*)Bt +
                        ((((col << 6) + kidx) ^ ((col & 7) << 2)) << 2));
                acc[ng] = __builtin_amdgcn_mfma_f32_16x16x32_bf16(a[kc], b, acc[ng], 0, 0, 0);
            }
        }
    }
    __syncthreads();
    unsigned short* sb16 = (unsigned short*)Bt;
    #pragma unroll
    for (int ng = 0; ng < 8; ++ng) {
        int col = ng * 16 + (lane & 15);
        float bv = bias[colBase + col];
        int cp = col >> 1, cb = col & 1;
        #pragma unroll
        for (int r = 0; r < 4; ++r) {
            int row = wid * 16 + (lane >> 4) * 4 + r;
            float val = acc[ng][r] + bv;
            if (ACT == 1) val = 0.5f * val * (1.f + erff(val * 0.70710678118654752f));
            else if (ACT == 2) val = fmaxf(val, 0.f);
            sb16[((row << 6) + (cp ^ ((row & 7) << 2))) * 2 + cb] = f2b(val);
        }
    }
    __syncthreads();
    unsigned* outw = (unsigned*)out;
    const int strideU = Dout >> 1, cbU = colBase >> 1;
    #pragma unroll
    for (int i = 0; i < 4; ++i) {
        int j = i * 1024 + t * 4;
        int row = j >> 6, cp = j & 63;
        uint4 v = *(const uint4*)&Bt[(row << 6) + (cp ^ ((row & 7) << 2))];
        int grow = rowBase + row;
        if (grow < rows) *(uint4*)&outw[(size_t)grow * strideU + cbU + cp] = v;
    }
}

// ---------- fused FFN: h1 = gelu(xb@fW1+fb1) in LDS; x,xb = LN(h1@fW2+fb2 + x) ----------
__global__ __launch_bounds__(256) void ffn_fused(
        const unsigned short* __restrict__ xbin, const float* __restrict__ W1,
        const float* __restrict__ b1f, const float* __restrict__ W2,
        const float* __restrict__ b2f, const float* __restrict__ g,
        const float* __restrict__ bbn, float* __restrict__ x,
        unsigned short* __restrict__ xb, int rows) {
    __shared__ unsigned Bt[8192];   // weight staging / final transpose-out
    __shared__ unsigned h1t[8192];  // 64 x 256 bf16 h1 tile
    const int t = threadIdx.x;
    const int rowBase = blockIdx.x << 6;
    const int lane = t & 63, wid = t >> 6;
    const int kqo = (lane >> 4) * 8;
    int arow = rowBase + wid * 16 + (lane & 15);
    if (arow > rows - 1) arow = rows - 1;

    short8 a[4];
    #pragma unroll
    for (int kc = 0; kc < 4; ++kc)
        a[kc] = *(const short8*)(xbin + (size_t)arow * DD + kc * 32 + kqo);

    unsigned short* h16 = (unsigned short*)h1t;
    for (int half = 0; half < 2; ++half) {
        if (half) __syncthreads();
        #pragma unroll 8
        for (int it = 0; it < 32; ++it) {
            int idx = it * 256 + t;
            int n = idx & 127, kp = idx >> 7;
            float w0 = W1[(size_t)(2 * kp) * 256 + half * 128 + n];
            float w1 = W1[(size_t)(2 * kp + 1) * 256 + half * 128 + n];
            Bt[((n << 6) + kp) ^ ((n & 7) << 2)] = packbf(w0, w1);
        }
        __syncthreads();
        f32x4 acc[8];
        #pragma unroll
        for (int i = 0; i < 8; ++i) acc[i] = (f32x4){0.f, 0.f, 0.f, 0.f};
        #pragma unroll
        for (int ng = 0; ng < 8; ++ng) {
            int col = ng * 16 + (lane & 15);
            #pragma unroll
            for (int kc = 0; kc < 4; ++kc) {
                int kidx = kc * 16 + (lane >> 4) * 4;
                const short8 b = *(const short8*)((const char*)Bt +
                        ((((col << 6) + kidx) ^ ((col & 7) << 2)) << 2));
                acc[ng] = __builtin_amdgcn_mfma_f32_16x16x32_bf16(a[kc], b, acc[ng], 0, 0, 0);
            }
        }
        #pragma unroll
        for (int ng = 0; ng < 8; ++ng) {
            int col = half * 128 + ng * 16 + (lane & 15);
            float bv = b1f[col];
            int cp = col >> 1, cb = col & 1;
            #pragma unroll
            for (int r = 0; r < 4; ++r) {
                int row = wid * 16 + (lane >> 4) * 4 + r;
                float val = acc[ng][r] + bv;
                val = 0.5f * val * (1.f + erff(val * 0.70710678118654752f));
                h16[((row << 7) + (cp ^ ((row & 7) << 2))) * 2 + cb] = f2b(val);
            }
        }
    }
    f32x4 accF[8];
    #pragma unroll
    for (int i = 0; i < 8; ++i) accF[i] = (f32x4){0.f, 0.f, 0.f, 0.f};
    const int lrow = wid * 16 + (lane & 15);
    for (int c = 0; c < 2; ++c) {
        __syncthreads();
        #pragma unroll 8
        for (int it = 0; it < 32; ++it) {
            int idx = it * 256 + t;
            int n = idx & 127, kp = idx >> 7;
            int krow = c * 128 + kp * 2;
            float w0 = W2[(size_t)krow * DD + n];
            float w1 = W2[(size_t)(krow + 1) * DD + n];
            Bt[((n << 6) + kp) ^ ((n & 7) << 2)] = packbf(w0, w1);
        }
        __syncthreads();
        short8 ah[4];
        #pragma unroll
        for (int kc = 0; kc < 4; ++kc) {
            int cp4 = c * 64 + kc * 16 + (lane >> 4) * 4;
            ah[kc] = *(const short8*)&h1t[(lrow << 7) + (cp4 ^ ((lrow & 7) << 2))];
        }
        #pragma unroll
        for (int ng = 0; ng < 8; ++ng) {
            int col = ng * 16 + (lane & 15);
            #pragma unroll
            for (int kc = 0; kc < 4; ++kc) {
                int kidx = kc * 16 + (lane >> 4) * 4;
                const short8 b = *(const short8*)((const char*)Bt +
                        ((((col << 6) + kidx) ^ ((col & 7) << 2)) << 2));
                accF[ng] = __builtin_amdgcn_mfma_f32_16x16x32_bf16(ah[kc], b, accF[ng], 0, 0, 0);
            }
        }
    }
    float tt[8][4];
    float rs[4] = {0.f, 0.f, 0.f, 0.f}, rs2[4] = {0.f, 0.f, 0.f, 0.f};
    #pragma unroll
    for (int ng = 0; ng < 8; ++ng) {
        int col = ng * 16 + (lane & 15);
        float bv = b2f[col];
        #pragma unroll
        for (int r = 0; r < 4; ++r) {
            int grow = rowBase + wid * 16 + (lane >> 4) * 4 + r;
            float xo = (grow < rows) ? x[(size_t)grow * DD + col] : 0.f;
            float v = accF[ng][r] + bv + xo;
            tt[ng][r] = v;
            rs[r] += v;
            rs2[r] += v * v;
        }
    }
    #pragma unroll
    for (int r = 0; r < 4; ++r) {
        #pragma unroll
        for (int m = 1; m < 16; m <<= 1) {
            rs[r] += __shfl_xor(rs[r], m);
            rs2[r] += __shfl_xor(rs2[r], m);
        }
    }
    __syncthreads();
    unsigned short* sb16 = (unsigned short*)Bt;
    #pragma unroll
    for (int ng = 0; ng < 8; ++ng) {
        int col = ng * 16 + (lane & 15);
        float gg = g[col], bbb = bbn[col];
        int cp = col >> 1, cb = col & 1;
        #pragma unroll
        for (int r = 0; r < 4; ++r) {
            int grow = rowBase + wid * 16 + (lane >> 4) * 4 + r;
            float mean = rs[r] * (1.f / DD);
            float var = rs2[r] * (1.f / DD) - mean * mean;
            float val = (tt[ng][r] - mean) * rsqrtf(var + 1e-5f) * gg + bbb;
            if (grow < rows) x[(size_t)grow * DD + col] = val;
            int row = wid * 16 + (lane >> 4) * 4 + r;
            sb16[((row << 6) + (cp ^ ((row & 7) << 2))) * 2 + cb] = f2b(val);
        }
    }
    __syncthreads();
    unsigned* outw = (unsigned*)xb;
    #pragma unroll
    for (int i = 0; i < 4; ++i) {
        int j = i * 1024 + t * 4;
        int row = j >> 6, cp = j & 63;
        uint4 v = *(const uint4*)&Bt[(row << 6) + (cp ^ ((row & 7) << 2))];
        int grow = rowBase + row;
        if (grow < rows) *(uint4*)&outw[(size_t)grow * 64 + cp] = v;
    }
}

// ---------- small kernels ----------

__global__ void enc_kernel(const float* __restrict__ xyz, const float* __restrict__ attr,
                           const float* __restrict__ W, const float* __restrict__ b,
                           const float* __restrict__ g, const float* __restrict__ bb,
                           float* __restrict__ x, unsigned short* __restrict__ xb) {
    int i = blockIdx.x, d = threadIdx.x;
    __shared__ float sin4[4];
    if (d < 3) sin4[d] = xyz[i * 3 + d];
    if (d == 3) sin4[3] = attr[i];
    __syncthreads();
    float y = b[d];
    #pragma unroll
    for (int kk = 0; kk < 4; ++kk) y += sin4[kk] * W[kk * DD + d];
    float s = y, s2 = y * y;
    redsum2_128(s, s2);
    float mean = s * (1.0f / DD);
    float var = s2 * (1.0f / DD) - mean * mean;
    float xn = fmaxf((y - mean) * rsqrtf(var + 1e-5f) * g[d] + bb[d], 0.f);
    x[i * DD + d] = xn;
    xb[(size_t)i * DD + d] = f2b(xn);
}

// pw[0:512): gc0,gc1,gc2,gbc (g-scaled centered cols); pw[512:522): quad consts
__global__ void posprep_kernel(const float* __restrict__ W1, const float* __restrict__ b1,
                               const float* __restrict__ g, float* __restrict__ pw) {
    int d = threadIdx.x;
    float w0 = W1[d], w1 = W1[DD + d], w2 = W1[2 * DD + d], b = b1[d];
    float s0 = w0, s1 = w1;
    redsum2_128(s0, s1);
    float s2 = w2, s3 = b;
    redsum2_128(s2, s3);
    float c0 = w0 - s0 * (1.f / DD), c1 = w1 - s1 * (1.f / DD);
    float c2 = w2 - s2 * (1.f / DD), bc = b - s3 * (1.f / DD);
    float gd = g[d];
    pw[d] = c0 * gd; pw[DD + d] = c1 * gd; pw[2 * DD + d] = c2 * gd; pw[3 * DD + d] = bc * gd;
    float p0 = c0 * c0, p1 = c0 * c1; redsum2_128(p0, p1);
    float p2 = c0 * c2, p3 = c1 * c1; redsum2_128(p2, p3);
    float p4 = c1 * c2, p5 = c2 * c2; redsum2_128(p4, p5);
    float p6 = c0 * bc, p7 = c1 * bc; redsum2_128(p6, p7);
    float p8 = c2 * bc, p9 = bc * bc; redsum2_128(p8, p9);
    if (d == 0) {
        pw[512] = p0 * (1.f / DD); pw[513] = p1 * (1.f / DD); pw[514] = p2 * (1.f / DD);
        pw[515] = p3 * (1.f / DD); pw[516] = p4 * (1.f / DD); pw[517] = p5 * (1.f / DD);
        pw[518] = p6 * (1.f / DD); pw[519] = p7 * (1.f / DD); pw[520] = p8 * (1.f / DD);
        pw[521] = p9 * (1.f / DD);
    }
}

// ---------- CSR build ----------

__global__ void hist_kernel(const int* __restrict__ ei, int* __restrict__ deg, int E) {
    int e = blockIdx.x * blockDim.x + threadIdx.x;
    if (e < E) atomicAdd(&deg[ei[E + e]], 1);
}

__global__ void scan_kernel(const int* __restrict__ deg, int* __restrict__ ptr, int n) {
    __shared__ int partial[1024];
    int t = threadIdx.x;
    int CH = (n + 1023) >> 10;
    int beg = t * CH;
    int end = beg + CH; if (end > n) end = n;
    int s = 0;
    for (int i = beg; i < end; ++i) s += deg[i];
    partial[t] = s;
    __syncthreads();
    for (int off = 1; off < 1024; off <<= 1) {
        int add = (t >= off) ? partial[t - off] : 0;
        __syncthreads();
        partial[t] += add;
        __syncthreads();
    }
    int base = (t == 0) ? 0 : partial[t - 1];
    for (int i = beg; i < end; ++i) {
        ptr[i] = base;
        base += deg[i];
    }
    if (end == n && beg < n) ptr[n] = base;
}

// scatter + per-edge rel/LN-inv (rel4, cs_src in CSR slot order)
__global__ void scatter_kernel(const int* __restrict__ ei, const float* __restrict__ xyz,
                               const float* __restrict__ pw, const int* __restrict__ ptr,
                               int* __restrict__ cur, int* __restrict__ cs_src,
                               float4* __restrict__ rel4, int E) {
    int e = blockIdx.x * blockDim.x + threadIdx.x;
    if (e >= E) return;
    int srcn = ei[e], dstn = ei[E + e];
    int p = atomicAdd(&cur[dstn], 1);
    int slot = ptr[dstn] + p;
    cs_src[slot] = srcn;
    float r0 = xyz[dstn * 3]     - xyz[srcn * 3];
    float r1 = xyz[dstn * 3 + 1] - xyz[srcn * 3 + 1];
    float r2 = xyz[dstn * 3 + 2] - xyz[srcn * 3 + 2];
    float var = pw[512] * r0 * r0 + pw[515] * r1 * r1 + pw[517] * r2 * r2
              + 2.f * (pw[513] * r0 * r1 + pw[514] * r0 * r2 + pw[516] * r1 * r2)
              + 2.f * (pw[518] * r0 + pw[519] * r1 + pw[520] * r2) + pw[521];
    rel4[slot] = make_float4(r0, r1, r2, rsqrtf(var + 1e-5f));
}

// ---------- fused agg: 4 waves per node (quarter edges each) + beta gate + LN1 ----------
__global__ __launch_bounds__(256) void aggc_kernel(
        const unsigned* __restrict__ qkv, const unsigned* __restrict__ ee,
        const int* __restrict__ ptr, const int* __restrict__ cs_src,
        const float* __restrict__ r, const float* __restrict__ Wb,
        const float* __restrict__ g1, const float* __restrict__ b1,
        float* __restrict__ x, unsigned* __restrict__ xbw, int N) {
    const int wave = threadIdx.x >> 6;        // 0..3
    const int lane = threadIdx.x & 63;
    const int node = blockIdx.x;
    __shared__ float sS[4];
    __shared__ float sA0[4][64];
    __shared__ float sA1[4][64];

    unsigned qp = qkv[(size_t)node * 192 + lane];
    float q0 = b2f((unsigned short)qp), q1 = b2f((unsigned short)(qp >> 16));
    int beg = ptr[node], end = ptr[node + 1];
    float s = 0.f, a0 = 0.f, a1 = 0.f;
    int idx = beg + wave;
    unsigned epN = 0;
    uint2 kvN = make_uint2(0u, 0u);
    if (idx < end) {
        int j = cs_src[idx];
        epN = __builtin_nontemporal_load(&ee[(size_t)idx * 64 + lane]);
        kvN = *(const uint2*)&qkv[(size_t)j * 192 + 64 + 2 * lane];
    }
    for (; idx < end; idx += 4) {
        unsigned ep = epN;
        uint2 kv = kvN;
        int nidx = idx + 4;
        if (nidx < end) {
            int jn = cs_src[nidx];
            epN = __builtin_nontemporal_load(&ee[(size_t)nidx * 64 + lane]);
            kvN = *(const uint2*)&qkv[(size_t)jn * 192 + 64 + 2 * lane];
        }
        float e0 = b2f((unsigned short)ep), e1 = b2f((unsigned short)(ep >> 16));
        float kj0 = b2f((unsigned short)kv.x) + e0;
        float kj1 = b2f((unsigned short)(kv.x >> 16)) + e1;
        float p = q0 * kj0 + q1 * kj1;
        p += __shfl_xor(p, 1); p += __shfl_xor(p, 2);
        p += __shfl_xor(p, 4); p += __shfl_xor(p, 8);
        float w = __expf(p * 0.17677669529663687f);  // |alpha| << 1: max-shift not needed
        s += w;
        a0 += (b2f((unsigned short)kv.y) + e0) * w;
        a1 += (b2f((unsigned short)(kv.y >> 16)) + e1) * w;
    }
    sS[wave] = s;
    sA0[wave][lane] = a0;
    sA1[wave][lane] = a1;
    __syncthreads();
    if (wave != 0) return;
    s  = sS[0] + sS[1] + sS[2] + sS[3];
    a0 = sA0[0][lane] + sA0[1][lane] + sA0[2][lane] + sA0[3][lane];
    a1 = sA1[0][lane] + sA1[1][lane] + sA1[2][lane] + sA1[3][lane];

    float inv_s = (s > 0.f) ? 1.f / s : 0.f;
    float od0 = a0 * inv_s, od1 = a1 * inv_s;
    float2 rd = *(const float2*)&r[(size_t)node * DD + lane * 2];
    float2 wb0 = *(const float2*)&Wb[lane * 2];
    float2 wb1 = *(const float2*)&Wb[DD + lane * 2];
    float2 wb2 = *(const float2*)&Wb[2 * DD + lane * 2];
    float part = od0 * wb0.x + rd.x * wb1.x + (od0 - rd.x) * wb2.x
               + od1 * wb0.y + rd.y * wb1.y + (od1 - rd.y) * wb2.y;
    #pragma unroll
    for (int m = 1; m < 64; m <<= 1) part += __shfl_xor(part, m);
    float beta = 1.f / (1.f + __expf(-part));
    float2 xo = *(const float2*)&x[(size_t)node * DD + lane * 2];
    float t0 = beta * rd.x + (1.f - beta) * od0 + xo.x;
    float t1 = beta * rd.y + (1.f - beta) * od1 + xo.y;
    float ss = t0 + t1, ss2 = t0 * t0 + t1 * t1;
    #pragma unroll
    for (int m = 1; m < 64; m <<= 1) { ss += __shfl_xor(ss, m); ss2 += __shfl_xor(ss2, m); }
    float mean = ss * (1.f / DD);
    float var = ss2 * (1.f / DD) - mean * mean;
    float inv = rsqrtf(var + 1e-5f);
    float2 gg = *(const float2*)&g1[lane * 2];
    float2 bbv = *(const float2*)&b1[lane * 2];
    float2 res;
    res.x = (t0 - mean) * inv * gg.x + bbv.x;
    res.y = (t1 - mean) * inv * gg.y + bbv.y;
    *(float2*)&x[(size_t)node * DD + lane * 2] = res;
    xbw[(size_t)node * 64 + lane] = packbf(res.x, res.y);
}

// ---------- heads ----------

__global__ void headprep_kernel(const float* __restrict__ cW1, const float* __restrict__ cb1,
                                const float* __restrict__ bW1, const float* __restrict__ bb1,
                                float* __restrict__ W1cat, float* __restrict__ b1cat) {
    int kk = blockIdx.x, d = threadIdx.x;
    W1cat[kk * DD + d] = (d < 64) ? cW1[kk * 64 + d] : bW1[kk * 64 + (d - 64)];
    if (kk == 0) b1cat[d] = (d < 64) ? cb1[d] : bb1[d - 64];
}

__global__ __launch_bounds__(256) void heads2_kernel(
        const unsigned* __restrict__ hh, const float* __restrict__ cW2,
        const float* __restrict__ cb2, const float* __restrict__ bW2,
        const float* __restrict__ bb2, float* __restrict__ outc,
        float* __restrict__ outb, int N) {
    int node = (blockIdx.x << 2) + (threadIdx.x >> 6);
    if (node >= N) return;
    const int lane = threadIdx.x & 63;
    unsigned hp = hh[(size_t)node * 64 + lane];
    float h0 = b2f((unsigned short)hp), h1 = b2f((unsigned short)(hp >> 16));
    bool isCls = lane < 32;
    int dd = isCls ? 2 * lane : 2 * lane - 128 + 64;
    float c[4], bx[7];
    #pragma unroll
    for (int j = 0; j < 4; ++j)
        c[j] = isCls ? h0 * cW2[dd * 4 + j] + h1 * cW2[(dd + 1) * 4 + j] : 0.f;
    #pragma unroll
    for (int j = 0; j < 7; ++j)
        bx[j] = isCls ? 0.f : h0 * bW2[dd * 7 + j] + h1 * bW2[(dd + 1) * 7 + j];
    #pragma unroll
    for (int m = 1; m < 32; m <<= 1) {
        #pragma unroll
        for (int j = 0; j < 4; ++j) c[j] += __shfl_xor(c[j], m);
        #pragma unroll
        for (int j = 0; j < 7; ++j) bx[j] += __shfl_xor(bx[j], m);
    }
    if (lane == 0) {
        #pragma unroll
        for (int j = 0; j < 4; ++j) outc[(size_t)node * 4 + j] = c[j] + cb2[j];
    } else if (lane == 32) {
        #pragma unroll
        for (int j = 0; j < 7; ++j) outb[(size_t)node * 7 + j] = bx[j] + bb2[j];
    }
}

extern "C" void kernel_launch(void* const* d_in, const int* in_sizes, int n_in,
                              void* d_out, int out_size, void* d_ws, size_t ws_size,
                              hipStream_t stream) {
    const float* xyz   = (const float*)d_in[0];
    const float* attr  = (const float*)d_in[1];
    const int*   ei    = (const int*)d_in[2];
    const float* encW  = (const float*)d_in[3];
    const float* encb  = (const float*)d_in[4];
    const float* encg  = (const float*)d_in[5];
    const float* encbb = (const float*)d_in[6];
    const float* posW1 = (const float*)d_in[7];
    const float* posb1 = (const float*)d_in[8];
    const float* posg  = (const float*)d_in[9];
    const float* posbb = (const float*)d_in[10];
    const float* posW2 = (const float*)d_in[11];
    const float* posb2 = (const float*)d_in[12];
    const float* Wq    = (const float*)d_in[13];
    const float* bq    = (const float*)d_in[14];
    const float* Wk    = (const float*)d_in[15];
    const float* bk    = (const float*)d_in[16];
    const float* Wv    = (const float*)d_in[17];
    const float* bv    = (const float*)d_in[18];
    const float* We    = (const float*)d_in[19];
    const float* Wskip = (const float*)d_in[20];
    const float* bskip = (const float*)d_in[21];
    const float* Wbeta = (const float*)d_in[22];
    const float* ln1g  = (const float*)d_in[23];
    const float* ln1b  = (const float*)d_in[24];
    const float* ln2g  = (const float*)d_in[25];
    const float* ln2b  = (const float*)d_in[26];
    const float* fW1   = (const float*)d_in[27];
    const float* fb1   = (const float*)d_in[28];
    const float* fW2   = (const float*)d_in[29];
    const float* fb2   = (const float*)d_in[30];
    const float* cW1   = (const float*)d_in[31];
    const float* cb1   = (const float*)d_in[32];
    const float* cW2   = (const float*)d_in[33];
    const float* cb2   = (const float*)d_in[34];
    const float* bW1   = (const float*)d_in[35];
    const float* bb1   = (const float*)d_in[36];
    const float* bW2   = (const float*)d_in[37];
    const float* bb2   = (const float*)d_in[38];

    const int N = in_sizes[0] / 3;
    const int E = in_sizes[2] / 2;

    size_t off = 0;
    auto alloc = [&](size_t nelem) {
        char* p = (char*)d_ws + off;
        off += nelem * sizeof(float);
        return (float*)p;
    };
    float* x     = alloc((size_t)N * DD);
    unsigned short* qkv = (unsigned short*)alloc((size_t)N * 192);   // N*384 bf16 (q | kv-interleaved)
    float* r     = alloc((size_t)N * DD);
    unsigned short* h1 = (unsigned short*)alloc((size_t)N * 128);    // heads temp
    unsigned short* xb = (unsigned short*)alloc((size_t)N * 64);     // N*128 bf16
    float4* rel4 = (float4*)alloc((size_t)E * 4);                    // CSR-order rel + inv
    unsigned short* eeb = (unsigned short*)alloc((size_t)E * 64);    // E*128 bf16 (CSR order)
    unsigned* W2Wep = (unsigned*)alloc(3 * 8192);                    // folded packed weights
    float* b2We  = alloc(3 * DD);
    unsigned* Wp12 = (unsigned*)alloc(12 * 8192);                    // q/k/v/skip packed
    float* pw    = alloc(544);
    float* W1cat = alloc(DD * DD);
    float* b1cat = alloc(DD);
    int* deg     = (int*)alloc(N);
    int* ptr     = (int*)alloc(N + 1);
    int* cur     = (int*)alloc(N);
    int* cs_src  = (int*)alloc(E);

    const int rtN = (N + 63) / 64;
    const int rtE = (E + 63) / 64;

    // ---- once: encoder, CSR build (+rel4), packed weights ----
    enc_kernel<<<N, DD, 0, stream>>>(xyz, attr, encW, encb, encg, encbb, x, xb);
    hipMemsetAsync(deg, 0, N * sizeof(int), stream);
    hipMemsetAsync(cur, 0, N * sizeof(int), stream);
    hist_kernel<<<(E + 255) / 256, 256, 0, stream>>>(ei, deg, E);
    scan_kernel<<<1, 1024, 0, stream>>>(deg, ptr, N);
    posprep_kernel<<<1, DD, 0, stream>>>(posW1, posb1, posg, pw);
    scatter_kernel<<<(E + 255) / 256, 256, 0, stream>>>(ei, xyz, pw, ptr, cur, cs_src, rel4, E);
    wcombp_kernel<<<dim3(65, 3), DD, 0, stream>>>(posW2, posb2, We, W2Wep, b2We);
    packw12_kernel<<<dim3(64, 12), DD, 0, stream>>>(Wq, Wk, Wv, Wskip, Wp12);
    headprep_kernel<<<DD, DD, 0, stream>>>(cW1, cb1, bW1, bb1, W1cat, b1cat);

    for (int l = 0; l < 3; ++l) {
        const float* Wb_l = Wbeta + (size_t)l * 3 * DD;
        const float* fW1_l = fW1 + (size_t)l * DD * 256;
        const float* fW2_l = fW2 + (size_t)l * 256 * DD;
        B4 bs;
        bs.b[0] = bq + l * DD; bs.b[1] = bk + l * DD;
        bs.b[2] = bv + l * DD; bs.b[3] = bskip + l * DD;

        // merged: ee GEMM (on-the-fly A) + q/k/v/skip GEMMs in one dispatch
        proj_kernel<<<rtE + 4 * rtN, 256, 0, stream>>>(
            xb, Wp12 + (size_t)l * 4 * 8192, bs, qkv, r, N, rtN,
            rel4, pw, posbb, W2Wep + l * 8192, b2We + l * DD, eeb, E, rtE);

        // fused: softmax agg (4 waves/node, pipelined, uint2 kv) + beta gate + LN1
        aggc_kernel<<<N, 256, 0, stream>>>((const unsigned*)qkv, (const unsigned*)eeb,
                                           ptr, cs_src, r, Wb_l,
                                           ln1g + l * DD, ln1b + l * DD,
                                           x, (unsigned*)xb, N);

        // fused FFN: h1 in LDS; x,xb = LN(gelu(xb@fW1+fb1)@fW2+fb2 + x)
        ffn_fused<<<rtN, 256, 0, stream>>>(xb, fW1_l, fb1 + l * 256, fW2_l, fb2 + l * DD,
                                           ln2g + l * DD, ln2b + l * DD, x, xb, N);
    }

    // ---- heads ----
    float* outc  = (float*)d_out;
    float* outbx = (float*)d_out + (size_t)N * 4;
    mgemm<2><<<dim3(rtN, 1), 256, 0, stream>>>(xb, W1cat, b1cat, h1, N, DD, DD);
    heads2_kernel<<<(N + 3) / 4, 256, 0, stream>>>((const unsigned*)h1, cW2, cb2, bW2, bb2,
                                                   outc, outbx, N);
}

// Round 13
// 436.335 us; speedup vs baseline: 1.0126x; 1.0126x over previous
//
#include <hip/hip_runtime.h>
#include <hip/hip_bf16.h>
#include <math.h>

#define DD 128

typedef __attribute__((ext_vector_type(8))) short short8;
typedef __attribute__((ext_vector_type(4))) float f32x4;

// ---------- helpers ----------

__device__ __forceinline__ unsigned short f2b(float f) {
    unsigned u = __float_as_uint(f);
    return (unsigned short)((u + 0x7FFFu + ((u >> 16) & 1u)) >> 16);
}
__device__ __forceinline__ float b2f(unsigned short b) {
    return __uint_as_float(((unsigned)b) << 16);
}
__device__ __forceinline__ unsigned packbf(float a, float b) {
    return (unsigned)f2b(a) | ((unsigned)f2b(b) << 16);
}

__device__ __forceinline__ void redsum2_128(float& a, float& b) {
    #pragma unroll
    for (int off = 32; off > 0; off >>= 1) {
        a += __shfl_down(a, off);
        b += __shfl_down(b, off);
    }
    __shared__ float sa[2], sb[2];
    int w = threadIdx.x >> 6;
    if ((threadIdx.x & 63) == 0) { sa[w] = a; sb[w] = b; }
    __syncthreads();
    a = sa[0] + sb[0] * 0.f + sa[1];  // placeholder avoided; fixed below
    b = sb[0] + sb[1];
    __syncthreads();
}

// NOTE: redsum2_128 above must sum sa for a and sb for b; rewritten correctly:
__device__ __forceinline__ void redsum2_128b(float& a, float& b) {
    #pragma unroll
    for (int off = 32; off > 0; off >>= 1) {
        a += __shfl_down(a, off);
        b += __shfl_down(b, off);
    }
    __shared__ float sa[2], sb[2];
    int w = threadIdx.x >> 6;
    if ((threadIdx.x & 63) == 0) { sa[w] = a; sb[w] = b; }
    __syncthreads();
    a = sa[0] + sa[1];
    b = sb[0] + sb[1];
    __syncthreads();
}

// ---------- weight packing ----------
// Packed blob (8192 u32): Bt[((n<<6)+kp)^((n&7)<<2)] = bf16pair(W[2kp][n], W[2kp+1][n])

__global__ void packw12_kernel(const float* __restrict__ Wq, const float* __restrict__ Wk,
                               const float* __restrict__ Wv, const float* __restrict__ Ws,
                               unsigned* __restrict__ Wp) {
    int bid = blockIdx.x, y = blockIdx.y, d = threadIdx.x;  // 64 x 12, 128 thr
    int l = y >> 2, wt = y & 3;
    const float* W = (wt == 0 ? Wq : wt == 1 ? Wk : wt == 2 ? Wv : Ws) + (size_t)l * DD * DD;
    float w0 = W[(size_t)(2 * bid) * DD + d];
    float w1 = W[(size_t)(2 * bid + 1) * DD + d];
    Wp[y * 8192 + (((d << 6) + bid) ^ ((d & 7) << 2))] = packbf(w0, w1);
}

// folded edge weight W2@We_y packed; block 64 = bias fold (f32)
__global__ void wcombp_kernel(const float* __restrict__ W2, const float* __restrict__ b2,
                              const float* __restrict__ We, unsigned* __restrict__ Wp,
                              float* __restrict__ b2We) {
    int bid = blockIdx.x, y = blockIdx.y, d = threadIdx.x;  // 65 x 3 blocks, 128 thr
    const float* We_l = We + (size_t)y * DD * DD;
    __shared__ float sa0[DD], sa1[DD];
    if (bid < 64) { sa0[d] = W2[(2 * bid) * DD + d]; sa1[d] = W2[(2 * bid + 1) * DD + d]; }
    else          { sa0[d] = b2[d]; sa1[d] = 0.f; }
    __syncthreads();
    float acc0 = 0.f, acc1 = 0.f;
    #pragma unroll 8
    for (int kk = 0; kk < DD; ++kk) {
        float w = We_l[kk * DD + d];
        acc0 += sa0[kk] * w;
        acc1 += sa1[kk] * w;
    }
    if (bid < 64) Wp[y * 8192 + (((d << 6) + bid) ^ ((d & 7) << 2))] = packbf(acc0, acc1);
    else          b2We[y * DD + d] = acc0;
}

// ---------- merged projection kernel ----------
// Blocks [0,rtE): ee GEMM.  Then y=0: q; y=1: k+v merged (interleaved kv out); y=2: skip->r.
// qkv row layout: [q pairs 0:64) | interleaved (k-pair, v-pair) 64:192) ]
struct B4 { const float* b[4]; };

__global__ __launch_bounds__(256) void proj_kernel(
        const unsigned short* __restrict__ xb, const unsigned* __restrict__ Wp4, B4 bias,
        unsigned short* __restrict__ qkv, float* __restrict__ rbuf, int rowsN, int rtN,
        const float4* __restrict__ rel4, const float* __restrict__ pw,
        const float* __restrict__ bbp, const unsigned* __restrict__ Wpee,
        const float* __restrict__ biasee, unsigned short* __restrict__ eeout,
        int rowsE, int rtE) {
    __shared__ unsigned Bt[8192];
    __shared__ float sc[640];
    const int t = threadIdx.x;
    const int lane = t & 63, wid = t >> 6;
    const int kqo = (lane >> 4) * 8;

    if ((int)blockIdx.x < rtE) {
        // ---- ee GEMM: A generated from rel4 + constants ----
        const int rowBase = (int)blockIdx.x << 6;
        #pragma unroll
        for (int i = 0; i < 8; ++i)
            *(uint4*)&Bt[(i * 256 + t) * 4] = *(const uint4*)&Wpee[(i * 256 + t) * 4];
        for (int i = t; i < 640; i += 256)
            sc[i] = (i < 512) ? pw[i] : bbp[i - 512];
        int arow = rowBase + wid * 16 + (lane & 15);
        if (arow > rowsE - 1) arow = rowsE - 1;
        float4 rv = rel4[arow];
        __syncthreads();
        short8 a[4];
        #pragma unroll
        for (int kc = 0; kc < 4; ++kc) {
            union { short8 s; unsigned short u[8]; } cv;
            #pragma unroll
            for (int j = 0; j < 8; ++j) {
                int d = kc * 32 + kqo + j;
                float y = fmaf(rv.x, sc[d], fmaf(rv.y, sc[128 + d], fmaf(rv.z, sc[256 + d], sc[384 + d])));
                cv.u[j] = f2b(fmaxf(fmaf(y, rv.w, sc[512 + d]), 0.f));
            }
            a[kc] = cv.s;
        }
        f32x4 acc[8];
        #pragma unroll
        for (int i = 0; i < 8; ++i) acc[i] = (f32x4){0.f, 0.f, 0.f, 0.f};
        #pragma unroll
        for (int ng = 0; ng < 8; ++ng) {
            int col = ng * 16 + (lane & 15);
            #pragma unroll
            for (int kc = 0; kc < 4; ++kc) {
                int kidx = kc * 16 + (lane >> 4) * 4;
                const short8 b = *(const short8*)((const char*)Bt +
                        ((((col << 6) + kidx) ^ ((col & 7) << 2)) << 2));
                acc[ng] = __builtin_amdgcn_mfma_f32_16x16x32_bf16(a[kc], b, acc[ng], 0, 0, 0);
            }
        }
        __syncthreads();
        unsigned short* sb16 = (unsigned short*)Bt;
        #pragma unroll
        for (int ng = 0; ng < 8; ++ng) {
            int col = ng * 16 + (lane & 15);
            float bv = biasee[col];
            int cp = col >> 1, cb = col & 1;
            #pragma unroll
            for (int r = 0; r < 4; ++r) {
                int row = wid * 16 + (lane >> 4) * 4 + r;
                sb16[((row << 6) + (cp ^ ((row & 7) << 2))) * 2 + cb] = f2b(acc[ng][r] + bv);
            }
        }
        __syncthreads();
        unsigned* outw = (unsigned*)eeout;
        #pragma unroll
        for (int i = 0; i < 4; ++i) {
            int j = i * 1024 + t * 4;
            int row = j >> 6, cp = j & 63;
            uint4 v = *(const uint4*)&Bt[(row << 6) + (cp ^ ((row & 7) << 2))];
            int grow = rowBase + row;
            if (grow < rowsE) *(uint4*)&outw[(size_t)grow * 64 + cp] = v;
        }
        return;
    }

    int bidx = (int)blockIdx.x - rtE;
    const int y = bidx / rtN;                   // 0: q, 1: k+v, 2: skip
    const int rowBase = (bidx % rtN) << 6;
    int arow = rowBase + wid * 16 + (lane & 15);
    if (arow > rowsN - 1) arow = rowsN - 1;
    short8 a[4];
    #pragma unroll
    for (int kc = 0; kc < 4; ++kc)
        a[kc] = *(const short8*)(xb + (size_t)arow * DD + kc * 32 + kqo);

    if (y == 1) {
        // ---- k and v GEMMs merged; interleaved kv output, coalesced stores ----
        f32x4 accK[8], accV[8];
        #pragma unroll
        for (int i = 0; i < 8; ++i) { accK[i] = (f32x4){0.f,0.f,0.f,0.f}; accV[i] = (f32x4){0.f,0.f,0.f,0.f}; }
        const unsigned* Wk_ = Wp4 + 1 * 8192;
        const unsigned* Wv_ = Wp4 + 2 * 8192;
        #pragma unroll
        for (int i = 0; i < 8; ++i)
            *(uint4*)&Bt[(i * 256 + t) * 4] = *(const uint4*)&Wk_[(i * 256 + t) * 4];
        __syncthreads();
        #pragma unroll
        for (int ng = 0; ng < 8; ++ng) {
            int col = ng * 16 + (lane & 15);
            #pragma unroll
            for (int kc = 0; kc < 4; ++kc) {
                int kidx = kc * 16 + (lane >> 4) * 4;
                const short8 b = *(const short8*)((const char*)Bt +
                        ((((col << 6) + kidx) ^ ((col & 7) << 2)) << 2));
                accK[ng] = __builtin_amdgcn_mfma_f32_16x16x32_bf16(a[kc], b, accK[ng], 0, 0, 0);
            }
        }
        __syncthreads();
        #pragma unroll
        for (int i = 0; i < 8; ++i)
            *(uint4*)&Bt[(i * 256 + t) * 4] = *(const uint4*)&Wv_[(i * 256 + t) * 4];
        __syncthreads();
        #pragma unroll
        for (int ng = 0; ng < 8; ++ng) {
            int col = ng * 16 + (lane & 15);
            #pragma unroll
            for (int kc = 0; kc < 4; ++kc) {
                int kidx = kc * 16 + (lane >> 4) * 4;
                const short8 b = *(const short8*)((const char*)Bt +
                        ((((col << 6) + kidx) ^ ((col & 7) << 2)) << 2));
                accV[ng] = __builtin_amdgcn_mfma_f32_16x16x32_bf16(a[kc], b, accV[ng], 0, 0, 0);
            }
        }
        __syncthreads();
        // interleaved tile in LDS: [64 rows][128 words]; word = 2*cp + (0:k,1:v)
        unsigned short* sb16 = (unsigned short*)Bt;
        const float* bk_ = bias.b[1];
        const float* bv_ = bias.b[2];
        #pragma unroll
        for (int ng = 0; ng < 8; ++ng) {
            int col = ng * 16 + (lane & 15);
            float bk = bk_[col], bvv = bv_[col];
            int cp = col >> 1, cb = col & 1;
            #pragma unroll
            for (int r = 0; r < 4; ++r) {
                int row = wid * 16 + (lane >> 4) * 4 + r;
                int sw = (row & 7) << 2;
                sb16[((row << 7) + ((2 * cp) ^ sw)) * 2 + cb]     = f2b(accK[ng][r] + bk);
                sb16[((row << 7) + ((2 * cp + 1) ^ sw)) * 2 + cb] = f2b(accV[ng][r] + bvv);
            }
        }
        __syncthreads();
        unsigned* outw = (unsigned*)qkv;
        #pragma unroll
        for (int i = 0; i < 8; ++i) {
            int j = i * 256 + t;          // 0..2047 uint4s
            int row = j >> 5, c4 = j & 31;
            uint4 v = *(const uint4*)&Bt[(row << 7) + ((c4 << 2) ^ ((row & 7) << 2))];
            int grow = rowBase + row;
            if (grow < rowsN) *(uint4*)&outw[(size_t)grow * 192 + 64 + (c4 << 2)] = v;
        }
        return;
    }

    // ---- q (y=0) or skip (y=2) single GEMM ----
    const unsigned* Wp = Wp4 + (y == 0 ? 0 : 3) * 8192;
    const float* bs = bias.b[y == 0 ? 0 : 3];
    #pragma unroll
    for (int i = 0; i < 8; ++i)
        *(uint4*)&Bt[(i * 256 + t) * 4] = *(const uint4*)&Wp[(i * 256 + t) * 4];
    __syncthreads();
    f32x4 acc[8];
    #pragma unroll
    for (int i = 0; i < 8; ++i) acc[i] = (f32x4){0.f, 0.f, 0.f, 0.f};
    #pragma unroll
    for (int ng = 0; ng < 8; ++ng) {
        int col = ng * 16 + (lane & 15);
        #pragma unroll
        for (int kc = 0; kc < 4; ++kc) {
            int kidx = kc * 16 + (lane >> 4) * 4;
            const short8 b = *(const short8*)((const char*)Bt +
                    ((((col << 6) + kidx) ^ ((col & 7) << 2)) << 2));
            acc[ng] = __builtin_amdgcn_mfma_f32_16x16x32_bf16(a[kc], b, acc[ng], 0, 0, 0);
        }
    }
    if (y == 2) {
        #pragma unroll
        for (int ng = 0; ng < 8; ++ng) {
            int col = ng * 16 + (lane & 15);
            float bv = bs[col];
            #pragma unroll
            for (int r = 0; r < 4; ++r) {
                int grow = rowBase + wid * 16 + (lane >> 4) * 4 + r;
                if (grow < rowsN) rbuf[(size_t)grow * DD + col] = acc[ng][r] + bv;
            }
        }
        return;
    }
    __syncthreads();
    unsigned short* sb16 = (unsigned short*)Bt;
    #pragma unroll
    for (int ng = 0; ng < 8; ++ng) {
        int col = ng * 16 + (lane & 15);
        float bv = bs[col];
        int cp = col >> 1, cb = col & 1;
        #pragma unroll
        for (int r = 0; r < 4; ++r) {
            int row = wid * 16 + (lane >> 4) * 4 + r;
            sb16[((row << 6) + (cp ^ ((row & 7) << 2))) * 2 + cb] = f2b(acc[ng][r] + bv);
        }
    }
    __syncthreads();
    unsigned* outw = (unsigned*)qkv;
    #pragma unroll
    for (int i = 0; i < 4; ++i) {
        int j = i * 1024 + t * 4;
        int row = j >> 6, cp = j & 63;
        uint4 v = *(const uint4*)&Bt[(row << 6) + (cp ^ ((row & 7) << 2))];
        int grow = rowBase + row;
        if (grow < rowsN) *(uint4*)&outw[(size_t)grow * 192 + cp] = v;
    }
}

// ---------- generic MFMA GEMM (f32 weights, bf16 A), bf16 out (used by heads) ----------
template <int ACT>
__global__ __launch_bounds__(256) void mgemm(
        const unsigned short* __restrict__ A, const float* __restrict__ W,
        const float* __restrict__ bias, unsigned short* __restrict__ out,
        int rows, int K, int Dout) {
    __shared__ unsigned Bt[8192];
    const int t = threadIdx.x;
    const int rowBase = blockIdx.x << 6;
    const int colBase = blockIdx.y << 7;
    const int lane = t & 63, wid = t >> 6;
    f32x4 acc[8];
    #pragma unroll
    for (int i = 0; i < 8; ++i) acc[i] = (f32x4){0.f, 0.f, 0.f, 0.f};
    int arow = rowBase + wid * 16 + (lane & 15);
    if (arow > rows - 1) arow = rows - 1;
    const int kqo = (lane >> 4) * 8;
    for (int k0 = 0; k0 < K; k0 += 128) {
        if (k0) __syncthreads();
        #pragma unroll 8
        for (int it = 0; it < 32; ++it) {
            int idx = it * 256 + t;
            int n = idx & 127, kp = idx >> 7;
            int krow = k0 + kp * 2;
            float w0 = W[(size_t)krow * Dout + colBase + n];
            float w1 = W[(size_t)(krow + 1) * Dout + colBase + n];
            Bt[((n << 6) + kp) ^ ((n & 7) << 2)] = packbf(w0, w1);
        }
        __syncthreads();
        short8 a[4];
        #pragma unroll
        for (int kc = 0; kc < 4; ++kc)
            a[kc] = *(const short8*)(A + (size_t)arow * K + k0 + kc * 32 + kqo);
        #pragma unroll
        for (int ng = 0; ng < 8; ++ng) {
            int col = ng * 16 + (lane & 15);
            #pragma unroll
            for (int kc = 0; kc < 4; ++kc) {
                int kidx = kc * 16 + (lane >> 4) * 4;
                const short8 b = *(const short8*)((const char*)Bt +
                        ((((col << 6) + kidx) ^ ((col & 7) << 2)) << 2));
                acc[ng] = __builtin_amdgcn_mfma_f32_16x16x32_bf16(a[kc], b, acc[ng], 0, 0, 0);
            }
        }
    }
    __syncthreads();
    unsigned short* sb16 = (unsigned short*)Bt;
    #pragma unroll
    for (int ng = 0; ng < 8; ++ng) {
        int col = ng * 16 + (lane & 15);
        float bv = bias[colBase + col];
        int cp = col >> 1, cb = col & 1;
        #pragma unroll
        for (int r = 0; r < 4; ++r) {
            int row = wid * 16 + (lane >> 4) * 4 + r;
            float val = acc[ng][r] + bv;
            if (ACT == 1) val = 0.5f * val * (1.f + erff(val * 0.70710678118654752f));
            else if (ACT == 2) val = fmaxf(val, 0.f);
            sb16[((row << 6) + (cp ^ ((row & 7) << 2))) * 2 + cb] = f2b(val);
        }
    }
    __syncthreads();
    unsigned* outw = (unsigned*)out;
    const int strideU = Dout >> 1, cbU = colBase >> 1;
    #pragma unroll
    for (int i = 0; i < 4; ++i) {
        int j = i * 1024 + t * 4;
        int row = j >> 6, cp = j & 63;
        uint4 v = *(const uint4*)&Bt[(row << 6) + (cp ^ ((row & 7) << 2))];
        int grow = rowBase + row;
        if (grow < rows) *(uint4*)&outw[(size_t)grow * strideU + cbU + cp] = v;
    }
}

// ---------- fused FFN: h1 = gelu(xb@fW1+fb1) in LDS; x,xb = LN(h1@fW2+fb2 + x) ----------
__global__ __launch_bounds__(256) void ffn_fused(
        const unsigned short* __restrict__ xbin, const float* __restrict__ W1,
        const float* __restrict__ b1f, const float* __restrict__ W2,
        const float* __restrict__ b2f, const float* __restrict__ g,
        const float* __restrict__ bbn, float* __restrict__ x,
        unsigned short* __restrict__ xb, int rows) {
    __shared__ unsigned Bt[8192];   // weight staging / final transpose-out
    __shared__ unsigned h1t[8192];  // 64 x 256 bf16 h1 tile
    const int t = threadIdx.x;
    const int rowBase = blockIdx.x << 6;
    const int lane = t & 63, wid = t >> 6;
    const int kqo = (lane >> 4) * 8;
    int arow = rowBase + wid * 16 + (lane & 15);
    if (arow > rows - 1) arow = rows - 1;

    short8 a[4];
    #pragma unroll
    for (int kc = 0; kc < 4; ++kc)
        a[kc] = *(const short8*)(xbin + (size_t)arow * DD + kc * 32 + kqo);

    unsigned short* h16 = (unsigned short*)h1t;
    for (int half = 0; half < 2; ++half) {
        if (half) __syncthreads();
        #pragma unroll 8
        for (int it = 0; it < 32; ++it) {
            int idx = it * 256 + t;
            int n = idx & 127, kp = idx >> 7;
            float w0 = W1[(size_t)(2 * kp) * 256 + half * 128 + n];
            float w1 = W1[(size_t)(2 * kp + 1) * 256 + half * 128 + n];
            Bt[((n << 6) + kp) ^ ((n & 7) << 2)] = packbf(w0, w1);
        }
        __syncthreads();
        f32x4 acc[8];
        #pragma unroll
        for (int i = 0; i < 8; ++i) acc[i] = (f32x4){0.f, 0.f, 0.f, 0.f};
        #pragma unroll
        for (int ng = 0; ng < 8; ++ng) {
            int col = ng * 16 + (lane & 15);
            #pragma unroll
            for (int kc = 0; kc < 4; ++kc) {
                int kidx = kc * 16 + (lane >> 4) * 4;
                const short8 b = *(const short8*)((const char*)Bt +
                        ((((col << 6) + kidx) ^ ((col & 7) << 2)) << 2));
                acc[ng] = __builtin_amdgcn_mfma_f32_16x16x32_bf16(a[kc], b, acc[ng], 0, 0, 0);
            }
        }
        #pragma unroll
        for (int ng = 0; ng < 8; ++ng) {
            int col = half * 128 + ng * 16 + (lane & 15);
            float bv = b1f[col];
            int cp = col >> 1, cb = col & 1;
            #pragma unroll
            for (int r = 0; r < 4; ++r) {
                int row = wid * 16 + (lane >> 4) * 4 + r;
                float val = acc[ng][r] + bv;
                val = 0.5f * val * (1.f + erff(val * 0.70710678118654752f));
                h16[((row << 7) + (cp ^ ((row & 7) << 2))) * 2 + cb] = f2b(val);
            }
        }
    }
    f32x4 accF[8];
    #pragma unroll
    for (int i = 0; i < 8; ++i) accF[i] = (f32x4){0.f, 0.f, 0.f, 0.f};
    const int lrow = wid * 16 + (lane & 15);
    for (int c = 0; c < 2; ++c) {
        __syncthreads();
        #pragma unroll 8
        for (int it = 0; it < 32; ++it) {
            int idx = it * 256 + t;
            int n = idx & 127, kp = idx >> 7;
            int krow = c * 128 + kp * 2;
            float w0 = W2[(size_t)krow * DD + n];
            float w1 = W2[(size_t)(krow + 1) * DD + n];
            Bt[((n << 6) + kp) ^ ((n & 7) << 2)] = packbf(w0, w1);
        }
        __syncthreads();
        short8 ah[4];
        #pragma unroll
        for (int kc = 0; kc < 4; ++kc) {
            int cp4 = c * 64 + kc * 16 + (lane >> 4) * 4;
            ah[kc] = *(const short8*)&h1t[(lrow << 7) + (cp4 ^ ((lrow & 7) << 2))];
        }
        #pragma unroll
        for (int ng = 0; ng < 8; ++ng) {
            int col = ng * 16 + (lane & 15);
            #pragma unroll
            for (int kc = 0; kc < 4; ++kc) {
                int kidx = kc * 16 + (lane >> 4) * 4;
                const short8 b = *(const short8*)((const char*)Bt +
                        ((((col << 6) + kidx) ^ ((col & 7) << 2)) << 2));
                accF[ng] = __builtin_amdgcn_mfma_f32_16x16x32_bf16(ah[kc], b, accF[ng], 0, 0, 0);
            }
        }
    }
    float tt[8][4];
    float rs[4] = {0.f, 0.f, 0.f, 0.f}, rs2[4] = {0.f, 0.f, 0.f, 0.f};
    #pragma unroll
    for (int ng = 0; ng < 8; ++ng) {
        int col = ng * 16 + (lane & 15);
        float bv = b2f[col];
        #pragma unroll
        for (int r = 0; r < 4; ++r) {
            int grow = rowBase + wid * 16 + (lane >> 4) * 4 + r;
            float xo = (grow < rows) ? x[(size_t)grow * DD + col] : 0.f;
            float v = accF[ng][r] + bv + xo;
            tt[ng][r] = v;
            rs[r] += v;
            rs2[r] += v * v;
        }
    }
    #pragma unroll
    for (int r = 0; r < 4; ++r) {
        #pragma unroll
        for (int m = 1; m < 16; m <<= 1) {
            rs[r] += __shfl_xor(rs[r], m);
            rs2[r] += __shfl_xor(rs2[r], m);
        }
    }
    __syncthreads();
    unsigned short* sb16 = (unsigned short*)Bt;
    #pragma unroll
    for (int ng = 0; ng < 8; ++ng) {
        int col = ng * 16 + (lane & 15);
        float gg = g[col], bbb = bbn[col];
        int cp = col >> 1, cb = col & 1;
        #pragma unroll
        for (int r = 0; r < 4; ++r) {
            int grow = rowBase + wid * 16 + (lane >> 4) * 4 + r;
            float mean = rs[r] * (1.f / DD);
            float var = rs2[r] * (1.f / DD) - mean * mean;
            float val = (tt[ng][r] - mean) * rsqrtf(var + 1e-5f) * gg + bbb;
            if (grow < rows) x[(size_t)grow * DD + col] = val;
            int row = wid * 16 + (lane >> 4) * 4 + r;
            sb16[((row << 6) + (cp ^ ((row & 7) << 2))) * 2 + cb] = f2b(val);
        }
    }
    __syncthreads();
    unsigned* outw = (unsigned*)xb;
    #pragma unroll
    for (int i = 0; i < 4; ++i) {
        int j = i * 1024 + t * 4;
        int row = j >> 6, cp = j & 63;
        uint4 v = *(const uint4*)&Bt[(row << 6) + (cp ^ ((row & 7) << 2))];
        int grow = rowBase + row;
        if (grow < rows) *(uint4*)&outw[(size_t)grow * 64 + cp] = v;
    }
}

// ---------- small kernels ----------

__global__ void enc_kernel(const float* __restrict__ xyz, const float* __restrict__ attr,
                           const float* __restrict__ W, const float* __restrict__ b,
                           const float* __restrict__ g, const float* __restrict__ bb,
                           float* __restrict__ x, unsigned short* __restrict__ xb) {
    int i = blockIdx.x, d = threadIdx.x;
    __shared__ float sin4[4];
    if (d < 3) sin4[d] = xyz[i * 3 + d];
    if (d == 3) sin4[3] = attr[i];
    __syncthreads();
    float y = b[d];
    #pragma unroll
    for (int kk = 0; kk < 4; ++kk) y += sin4[kk] * W[kk * DD + d];
    float s = y, s2 = y * y;
    redsum2_128b(s, s2);
    float mean = s * (1.0f / DD);
    float var = s2 * (1.0f / DD) - mean * mean;
    float xn = fmaxf((y - mean) * rsqrtf(var + 1e-5f) * g[d] + bb[d], 0.f);
    x[i * DD + d] = xn;
    xb[(size_t)i * DD + d] = f2b(xn);
}

// pw[0:512): gc0,gc1,gc2,gbc (g-scaled centered cols); pw[512:522): quad consts
__global__ void posprep_kernel(const float* __restrict__ W1, const float* __restrict__ b1,
                               const float* __restrict__ g, float* __restrict__ pw) {
    int d = threadIdx.x;
    float w0 = W1[d], w1 = W1[DD + d], w2 = W1[2 * DD + d], b = b1[d];
    float s0 = w0, s1 = w1;
    redsum2_128b(s0, s1);
    float s2 = w2, s3 = b;
    redsum2_128b(s2, s3);
    float c0 = w0 - s0 * (1.f / DD), c1 = w1 - s1 * (1.f / DD);
    float c2 = w2 - s2 * (1.f / DD), bc = b - s3 * (1.f / DD);
    float gd = g[d];
    pw[d] = c0 * gd; pw[DD + d] = c1 * gd; pw[2 * DD + d] = c2 * gd; pw[3 * DD + d] = bc * gd;
    float p0 = c0 * c0, p1 = c0 * c1; redsum2_128b(p0, p1);
    float p2 = c0 * c2, p3 = c1 * c1; redsum2_128b(p2, p3);
    float p4 = c1 * c2, p5 = c2 * c2; redsum2_128b(p4, p5);
    float p6 = c0 * bc, p7 = c1 * bc; redsum2_128b(p6, p7);
    float p8 = c2 * bc, p9 = bc * bc; redsum2_128b(p8, p9);
    if (d == 0) {
        pw[512] = p0 * (1.f / DD); pw[513] = p1 * (1.f / DD); pw[514] = p2 * (1.f / DD);
        pw[515] = p3 * (1.f / DD); pw[516] = p4 * (1.f / DD); pw[517] = p5 * (1.f / DD);
        pw[518] = p6 * (1.f / DD); pw[519] = p7 * (1.f / DD); pw[520] = p8 * (1.f / DD);
        pw[521] = p9 * (1.f / DD);
    }
}

// ---------- CSR build ----------

__global__ void hist_kernel(const int* __restrict__ ei, int* __restrict__ deg, int E) {
    int e = blockIdx.x * blockDim.x + threadIdx.x;
    if (e < E) atomicAdd(&deg[ei[E + e]], 1);
}

__global__ void scan_kernel(const int* __restrict__ deg, int* __restrict__ ptr, int n) {
    __shared__ int partial[1024];
    int t = threadIdx.x;
    int CH = (n + 1023) >> 10;
    int beg = t * CH;
    int end = beg + CH; if (end > n) end = n;
    int s = 0;
    for (int i = beg; i < end; ++i) s += deg[i];
    partial[t] = s;
    __syncthreads();
    for (int off = 1; off < 1024; off <<= 1) {
        int add = (t >= off) ? partial[t - off] : 0;
        __syncthreads();
        partial[t] += add;
        __syncthreads();
    }
    int base = (t == 0) ? 0 : partial[t - 1];
    for (int i = beg; i < end; ++i) {
        ptr[i] = base;
        base += deg[i];
    }
    if (end == n && beg < n) ptr[n] = base;
}

// scatter + per-edge rel/LN-inv (rel4, cs_src in CSR slot order)
__global__ void scatter_kernel(const int* __restrict__ ei, const float* __restrict__ xyz,
                               const float* __restrict__ pw, const int* __restrict__ ptr,
                               int* __restrict__ cur, int* __restrict__ cs_src,
                               float4* __restrict__ rel4, int E) {
    int e = blockIdx.x * blockDim.x + threadIdx.x;
    if (e >= E) return;
    int srcn = ei[e], dstn = ei[E + e];
    int p = atomicAdd(&cur[dstn], 1);
    int slot = ptr[dstn] + p;
    cs_src[slot] = srcn;
    float r0 = xyz[dstn * 3]     - xyz[srcn * 3];
    float r1 = xyz[dstn * 3 + 1] - xyz[srcn * 3 + 1];
    float r2 = xyz[dstn * 3 + 2] - xyz[srcn * 3 + 2];
    float var = pw[512] * r0 * r0 + pw[515] * r1 * r1 + pw[517] * r2 * r2
              + 2.f * (pw[513] * r0 * r1 + pw[514] * r0 * r2 + pw[516] * r1 * r2)
              + 2.f * (pw[518] * r0 + pw[519] * r1 + pw[520] * r2) + pw[521];
    rel4[slot] = make_float4(r0, r1, r2, rsqrtf(var + 1e-5f));
}

// ---------- fused agg: 4 waves per node (quarter edges each) + beta gate + LN1 ----------
__global__ __launch_bounds__(256) void aggc_kernel(
        const unsigned* __restrict__ qkv, const unsigned* __restrict__ ee,
        const int* __restrict__ ptr, const int* __restrict__ cs_src,
        const float* __restrict__ r, const float* __restrict__ Wb,
        const float* __restrict__ g1, const float* __restrict__ b1,
        float* __restrict__ x, unsigned* __restrict__ xbw, int N) {
    const int wave = threadIdx.x >> 6;        // 0..3
    const int lane = threadIdx.x & 63;
    const int node = blockIdx.x;
    __shared__ float sS[4];
    __shared__ float sA0[4][64];
    __shared__ float sA1[4][64];

    unsigned qp = qkv[(size_t)node * 192 + lane];
    float q0 = b2f((unsigned short)qp), q1 = b2f((unsigned short)(qp >> 16));
    int beg = ptr[node], end = ptr[node + 1];
    float s = 0.f, a0 = 0.f, a1 = 0.f;
    int idx = beg + wave;
    unsigned epN = 0;
    uint2 kvN = make_uint2(0u, 0u);
    if (idx < end) {
        int j = cs_src[idx];
        epN = __builtin_nontemporal_load(&ee[(size_t)idx * 64 + lane]);
        kvN = *(const uint2*)&qkv[(size_t)j * 192 + 64 + 2 * lane];
    }
    for (; idx < end; idx += 4) {
        unsigned ep = epN;
        uint2 kv = kvN;
        int nidx = idx + 4;
        if (nidx < end) {
            int jn = cs_src[nidx];
            epN = __builtin_nontemporal_load(&ee[(size_t)nidx * 64 + lane]);
            kvN = *(const uint2*)&qkv[(size_t)jn * 192 + 64 + 2 * lane];
        }
        float e0 = b2f((unsigned short)ep), e1 = b2f((unsigned short)(ep >> 16));
        float kj0 = b2f((unsigned short)kv.x) + e0;
        float kj1 = b2f((unsigned short)(kv.x >> 16)) + e1;
        float p = q0 * kj0 + q1 * kj1;
        p += __shfl_xor(p, 1); p += __shfl_xor(p, 2);
        p += __shfl_xor(p, 4); p += __shfl_xor(p, 8);
        float w = __expf(p * 0.17677669529663687f);  // |alpha| << 1: max-shift not needed
        s += w;
        a0 += (b2f((unsigned short)kv.y) + e0) * w;
        a1 += (b2f((unsigned short)(kv.y >> 16)) + e1) * w;
    }
    sS[wave] = s;
    sA0[wave][lane] = a0;
    sA1[wave][lane] = a1;
    __syncthreads();
    if (wave != 0) return;
    s  = sS[0] + sS[1] + sS[2] + sS[3];
    a0 = sA0[0][lane] + sA0[1][lane] + sA0[2][lane] + sA0[3][lane];
    a1 = sA1[0][lane] + sA1[1][lane] + sA1[2][lane] + sA1[3][lane];

    float inv_s = (s > 0.f) ? 1.f / s : 0.f;
    float od0 = a0 * inv_s, od1 = a1 * inv_s;
    float2 rd = *(const float2*)&r[(size_t)node * DD + lane * 2];
    float2 wb0 = *(const float2*)&Wb[lane * 2];
    float2 wb1 = *(const float2*)&Wb[DD + lane * 2];
    float2 wb2 = *(const float2*)&Wb[2 * DD + lane * 2];
    float part = od0 * wb0.x + rd.x * wb1.x + (od0 - rd.x) * wb2.x
               + od1 * wb0.y + rd.y * wb1.y + (od1 - rd.y) * wb2.y;
    #pragma unroll
    for (int m = 1; m < 64; m <<= 1) part += __shfl_xor(part, m);
    float beta = 1.f / (1.f + __expf(-part));
    float2 xo = *(const float2*)&x[(size_t)node * DD + lane * 2];
    float t0 = beta * rd.x + (1.f - beta) * od0 + xo.x;
    float t1 = beta * rd.y + (1.f - beta) * od1 + xo.y;
    float ss = t0 + t1, ss2 = t0 * t0 + t1 * t1;
    #pragma unroll
    for (int m = 1; m < 64; m <<= 1) { ss += __shfl_xor(ss, m); ss2 += __shfl_xor(ss2, m); }
    float mean = ss * (1.f / DD);
    float var = ss2 * (1.f / DD) - mean * mean;
    float inv = rsqrtf(var + 1e-5f);
    float2 gg = *(const float2*)&g1[lane * 2];
    float2 bbv = *(const float2*)&b1[lane * 2];
    float2 res;
    res.x = (t0 - mean) * inv * gg.x + bbv.x;
    res.y = (t1 - mean) * inv * gg.y + bbv.y;
    *(float2*)&x[(size_t)node * DD + lane * 2] = res;
    xbw[(size_t)node * 64 + lane] = packbf(res.x, res.y);
}

// ---------- heads ----------

__global__ void headprep_kernel(const float* __restrict__ cW1, const float* __restrict__ cb1,
                                const float* __restrict__ bW1, const float* __restrict__ bb1,
                                float* __restrict__ W1cat, float* __restrict__ b1cat) {
    int kk = blockIdx.x, d = threadIdx.x;
    W1cat[kk * DD + d] = (d < 64) ? cW1[kk * 64 + d] : bW1[kk * 64 + (d - 64)];
    if (kk == 0) b1cat[d] = (d < 64) ? cb1[d] : bb1[d - 64];
}

__global__ __launch_bounds__(256) void heads2_kernel(
        const unsigned* __restrict__ hh, const float* __restrict__ cW2,
        const float* __restrict__ cb2, const float* __restrict__ bW2,
        const float* __restrict__ bb2, float* __restrict__ outc,
        float* __restrict__ outb, int N) {
    int node = (blockIdx.x << 2) + (threadIdx.x >> 6);
    if (node >= N) return;
    const int lane = threadIdx.x & 63;
    unsigned hp = hh[(size_t)node * 64 + lane];
    float h0 = b2f((unsigned short)hp), h1 = b2f((unsigned short)(hp >> 16));
    bool isCls = lane < 32;
    int dd = isCls ? 2 * lane : 2 * lane - 128 + 64;
    float c[4], bx[7];
    #pragma unroll
    for (int j = 0; j < 4; ++j)
        c[j] = isCls ? h0 * cW2[dd * 4 + j] + h1 * cW2[(dd + 1) * 4 + j] : 0.f;
    #pragma unroll
    for (int j = 0; j < 7; ++j)
        bx[j] = isCls ? 0.f : h0 * bW2[dd * 7 + j] + h1 * bW2[(dd + 1) * 7 + j];
    #pragma unroll
    for (int m = 1; m < 32; m <<= 1) {
        #pragma unroll
        for (int j = 0; j < 4; ++j) c[j] += __shfl_xor(c[j], m);
        #pragma unroll
        for (int j = 0; j < 7; ++j) bx[j] += __shfl_xor(bx[j], m);
    }
    if (lane == 0) {
        #pragma unroll
        for (int j = 0; j < 4; ++j) outc[(size_t)node * 4 + j] = c[j] + cb2[j];
    } else if (lane == 32) {
        #pragma unroll
        for (int j = 0; j < 7; ++j) outb[(size_t)node * 7 + j] = bx[j] + bb2[j];
    }
}

extern "C" void kernel_launch(void* const* d_in, const int* in_sizes, int n_in,
                              void* d_out, int out_size, void* d_ws, size_t ws_size,
                              hipStream_t stream) {
    const float* xyz   = (const float*)d_in[0];
    const float* attr  = (const float*)d_in[1];
    const int*   ei    = (const int*)d_in[2];
    const float* encW  = (const float*)d_in[3];
    const float* encb  = (const float*)d_in[4];
    const float* encg  = (const float*)d_in[5];
    const float* encbb = (const float*)d_in[6];
    const float* posW1 = (const float*)d_in[7];
    const float* posb1 = (const float*)d_in[8];
    const float* posg  = (const float*)d_in[9];
    const float* posbb = (const float*)d_in[10];
    const float* posW2 = (const float*)d_in[11];
    const float* posb2 = (const float*)d_in[12];
    const float* Wq    = (const float*)d_in[13];
    const float* bq    = (const float*)d_in[14];
    const float* Wk    = (const float*)d_in[15];
    const float* bk    = (const float*)d_in[16];
    const float* Wv    = (const float*)d_in[17];
    const float* bv    = (const float*)d_in[18];
    const float* We    = (const float*)d_in[19];
    const float* Wskip = (const float*)d_in[20];
    const float* bskip = (const float*)d_in[21];
    const float* Wbeta = (const float*)d_in[22];
    const float* ln1g  = (const float*)d_in[23];
    const float* ln1b  = (const float*)d_in[24];
    const float* ln2g  = (const float*)d_in[25];
    const float* ln2b  = (const float*)d_in[26];
    const float* fW1   = (const float*)d_in[27];
    const float* fb1   = (const float*)d_in[28];
    const float* fW2   = (const float*)d_in[29];
    const float* fb2   = (const float*)d_in[30];
    const float* cW1   = (const float*)d_in[31];
    const float* cb1   = (const float*)d_in[32];
    const float* cW2   = (const float*)d_in[33];
    const float* cb2   = (const float*)d_in[34];
    const float* bW1   = (const float*)d_in[35];
    const float* bb1   = (const float*)d_in[36];
    const float* bW2   = (const float*)d_in[37];
    const float* bb2   = (const float*)d_in[38];

    const int N = in_sizes[0] / 3;
    const int E = in_sizes[2] / 2;

    size_t off = 0;
    auto alloc = [&](size_t nelem) {
        char* p = (char*)d_ws + off;
        off += nelem * sizeof(float);
        return (float*)p;
    };
    float* x     = alloc((size_t)N * DD);
    unsigned short* qkv = (unsigned short*)alloc((size_t)N * 192);   // N*384 bf16 (q | kv-interleaved)
    float* r     = alloc((size_t)N * DD);
    unsigned short* h1 = (unsigned short*)alloc((size_t)N * 128);    // heads temp
    unsigned short* xb = (unsigned short*)alloc((size_t)N * 64);     // N*128 bf16
    float4* rel4 = (float4*)alloc((size_t)E * 4);                    // CSR-order rel + inv
    unsigned short* eeb = (unsigned short*)alloc((size_t)E * 64);    // E*128 bf16 (CSR order)
    unsigned* W2Wep = (unsigned*)alloc(3 * 8192);                    // folded packed weights
    float* b2We  = alloc(3 * DD);
    unsigned* Wp12 = (unsigned*)alloc(12 * 8192);                    // q/k/v/skip packed
    float* pw    = alloc(544);
    float* W1cat = alloc(DD * DD);
    float* b1cat = alloc(DD);
    int* deg     = (int*)alloc(N);
    int* ptr     = (int*)alloc(N + 1);
    int* cur     = (int*)alloc(N);
    int* cs_src  = (int*)alloc(E);

    const int rtN = (N + 63) / 64;
    const int rtE = (E + 63) / 64;

    // ---- once: encoder, CSR build (+rel4), packed weights ----
    enc_kernel<<<N, DD, 0, stream>>>(xyz, attr, encW, encb, encg, encbb, x, xb);
    hipMemsetAsync(deg, 0, N * sizeof(int), stream);
    hipMemsetAsync(cur, 0, N * sizeof(int), stream);
    hist_kernel<<<(E + 255) / 256, 256, 0, stream>>>(ei, deg, E);
    scan_kernel<<<1, 1024, 0, stream>>>(deg, ptr, N);
    posprep_kernel<<<1, DD, 0, stream>>>(posW1, posb1, posg, pw);
    scatter_kernel<<<(E + 255) / 256, 256, 0, stream>>>(ei, xyz, pw, ptr, cur, cs_src, rel4, E);
    wcombp_kernel<<<dim3(65, 3), DD, 0, stream>>>(posW2, posb2, We, W2Wep, b2We);
    packw12_kernel<<<dim3(64, 12), DD, 0, stream>>>(Wq, Wk, Wv, Wskip, Wp12);
    headprep_kernel<<<DD, DD, 0, stream>>>(cW1, cb1, bW1, bb1, W1cat, b1cat);

    for (int l = 0; l < 3; ++l) {
        const float* Wb_l = Wbeta + (size_t)l * 3 * DD;
        const float* fW1_l = fW1 + (size_t)l * DD * 256;
        const float* fW2_l = fW2 + (size_t)l * 256 * DD;
        B4 bs;
        bs.b[0] = bq + l * DD; bs.b[1] = bk + l * DD;
        bs.b[2] = bv + l * DD; bs.b[3] = bskip + l * DD;

        // merged: ee GEMM + q GEMM + (k,v) merged GEMM + skip GEMM
        proj_kernel<<<rtE + 3 * rtN, 256, 0, stream>>>(
            xb, Wp12 + (size_t)l * 4 * 8192, bs, qkv, r, N, rtN,
            rel4, pw, posbb, W2Wep + l * 8192, b2We + l * DD, eeb, E, rtE);

        // fused: softmax agg (4 waves/node, pipelined, uint2 kv) + beta gate + LN1
        aggc_kernel<<<N, 256, 0, stream>>>((const unsigned*)qkv, (const unsigned*)eeb,
                                           ptr, cs_src, r, Wb_l,
                                           ln1g + l * DD, ln1b + l * DD,
                                           x, (unsigned*)xb, N);

        // fused FFN: h1 in LDS; x,xb = LN(gelu(xb@fW1+fb1)@fW2+fb2 + x)
        ffn_fused<<<rtN, 256, 0, stream>>>(xb, fW1_l, fb1 + l * 256, fW2_l, fb2 + l * DD,
                                           ln2g + l * DD, ln2b + l * DD, x, xb, N);
    }

    // ---- heads ----
    float* outc  = (float*)d_out;
    float* outbx = (float*)d_out + (size_t)N * 4;
    mgemm<2><<<dim3(rtN, 1), 256, 0, stream>>>(xb, W1cat, b1cat, h1, N, DD, DD);
    heads2_kernel<<<(N + 3) / 4, 256, 0, stream>>>((const unsigned*)h1, cW2, cb2, bW2, bb2,
                                                   outc, outbx, N);
}

// Round 14
// 426.783 us; speedup vs baseline: 1.0352x; 1.0224x over previous
//
#include <hip/hip_runtime.h>
#include <hip/hip_bf16.h>
#include <math.h>

#define DD 128

typedef __attribute__((ext_vector_type(8))) short short8;
typedef __attribute__((ext_vector_type(4))) float f32x4;

// ---------- helpers ----------

__device__ __forceinline__ unsigned short f2b(float f) {
    unsigned u = __float_as_uint(f);
    return (unsigned short)((u + 0x7FFFu + ((u >> 16) & 1u)) >> 16);
}
__device__ __forceinline__ float b2f(unsigned short b) {
    return __uint_as_float(((unsigned)b) << 16);
}
__device__ __forceinline__ unsigned packbf(float a, float b) {
    return (unsigned)f2b(a) | ((unsigned)f2b(b) << 16);
}

__device__ __forceinline__ void redsum2_128(float& a, float& b) {
    #pragma unroll
    for (int off = 32; off > 0; off >>= 1) {
        a += __shfl_down(a, off);
        b += __shfl_down(b, off);
    }
    __shared__ float sa[2], sb[2];
    int w = threadIdx.x >> 6;
    if ((threadIdx.x & 63) == 0) { sa[w] = a; sb[w] = b; }
    __syncthreads();
    a = sa[0] + sa[1];
    b = sb[0] + sb[1];
    __syncthreads();
}

// ---------- weight packing ----------
// Packed blob (8192 u32): Bt[((n<<6)+kp)^((n&7)<<2)] = bf16pair(W[2kp][n], W[2kp+1][n])

__global__ void packw12_kernel(const float* __restrict__ Wq, const float* __restrict__ Wk,
                               const float* __restrict__ Wv, const float* __restrict__ Ws,
                               unsigned* __restrict__ Wp) {
    int bid = blockIdx.x, y = blockIdx.y, d = threadIdx.x;  // 64 x 12, 128 thr
    int l = y >> 2, wt = y & 3;
    const float* W = (wt == 0 ? Wq : wt == 1 ? Wk : wt == 2 ? Wv : Ws) + (size_t)l * DD * DD;
    float w0 = W[(size_t)(2 * bid) * DD + d];
    float w1 = W[(size_t)(2 * bid + 1) * DD + d];
    Wp[y * 8192 + (((d << 6) + bid) ^ ((d & 7) << 2))] = packbf(w0, w1);
}

// folded edge weight W2@We_y packed; block 64 = bias fold (f32)
__global__ void wcombp_kernel(const float* __restrict__ W2, const float* __restrict__ b2,
                              const float* __restrict__ We, unsigned* __restrict__ Wp,
                              float* __restrict__ b2We) {
    int bid = blockIdx.x, y = blockIdx.y, d = threadIdx.x;  // 65 x 3 blocks, 128 thr
    const float* We_l = We + (size_t)y * DD * DD;
    __shared__ float sa0[DD], sa1[DD];
    if (bid < 64) { sa0[d] = W2[(2 * bid) * DD + d]; sa1[d] = W2[(2 * bid + 1) * DD + d]; }
    else          { sa0[d] = b2[d]; sa1[d] = 0.f; }
    __syncthreads();
    float acc0 = 0.f, acc1 = 0.f;
    #pragma unroll 8
    for (int kk = 0; kk < DD; ++kk) {
        float w = We_l[kk * DD + d];
        acc0 += sa0[kk] * w;
        acc1 += sa1[kk] * w;
    }
    if (bid < 64) Wp[y * 8192 + (((d << 6) + bid) ^ ((d & 7) << 2))] = packbf(acc0, acc1);
    else          b2We[y * DD + d] = acc0;
}

// ---------- merged projection kernel: ee GEMM (on-the-fly A) + q/k/v/skip GEMMs ----------
// qkv row layout: [q 0:64 | k 64:128 | v 128:192] (u32 pairs)
struct B4 { const float* b[4]; };

__global__ __launch_bounds__(256) void proj_kernel(
        const unsigned short* __restrict__ xb, const unsigned* __restrict__ Wp4, B4 bias,
        unsigned short* __restrict__ qkv, float* __restrict__ rbuf, int rowsN, int rtN,
        const float4* __restrict__ rel4, const float* __restrict__ pw,
        const float* __restrict__ bbp, const unsigned* __restrict__ Wpee,
        const float* __restrict__ biasee, unsigned short* __restrict__ eeout,
        int rowsE, int rtE) {
    __shared__ unsigned Bt[8192];
    __shared__ float sc[640];
    const int t = threadIdx.x;
    const int lane = t & 63, wid = t >> 6;
    const int kqo = (lane >> 4) * 8;

    if ((int)blockIdx.x < rtE) {
        // ---- ee GEMM: A generated from rel4 + constants ----
        const int rowBase = (int)blockIdx.x << 6;
        #pragma unroll
        for (int i = 0; i < 8; ++i)
            *(uint4*)&Bt[(i * 256 + t) * 4] = *(const uint4*)&Wpee[(i * 256 + t) * 4];
        for (int i = t; i < 640; i += 256)
            sc[i] = (i < 512) ? pw[i] : bbp[i - 512];
        int arow = rowBase + wid * 16 + (lane & 15);
        if (arow > rowsE - 1) arow = rowsE - 1;
        float4 rv = rel4[arow];
        __syncthreads();
        short8 a[4];
        #pragma unroll
        for (int kc = 0; kc < 4; ++kc) {
            union { short8 s; unsigned short u[8]; } cv;
            #pragma unroll
            for (int j = 0; j < 8; ++j) {
                int d = kc * 32 + kqo + j;
                float y = fmaf(rv.x, sc[d], fmaf(rv.y, sc[128 + d], fmaf(rv.z, sc[256 + d], sc[384 + d])));
                cv.u[j] = f2b(fmaxf(fmaf(y, rv.w, sc[512 + d]), 0.f));
            }
            a[kc] = cv.s;
        }
        f32x4 acc[8];
        #pragma unroll
        for (int i = 0; i < 8; ++i) acc[i] = (f32x4){0.f, 0.f, 0.f, 0.f};
        #pragma unroll
        for (int ng = 0; ng < 8; ++ng) {
            int col = ng * 16 + (lane & 15);
            #pragma unroll
            for (int kc = 0; kc < 4; ++kc) {
                int kidx = kc * 16 + (lane >> 4) * 4;
                const short8 b = *(const short8*)((const char*)Bt +
                        ((((col << 6) + kidx) ^ ((col & 7) << 2)) << 2));
                acc[ng] = __builtin_amdgcn_mfma_f32_16x16x32_bf16(a[kc], b, acc[ng], 0, 0, 0);
            }
        }
        __syncthreads();
        unsigned short* sb16 = (unsigned short*)Bt;
        #pragma unroll
        for (int ng = 0; ng < 8; ++ng) {
            int col = ng * 16 + (lane & 15);
            float bv = biasee[col];
            int cp = col >> 1, cb = col & 1;
            #pragma unroll
            for (int r = 0; r < 4; ++r) {
                int row = wid * 16 + (lane >> 4) * 4 + r;
                sb16[((row << 6) + (cp ^ ((row & 7) << 2))) * 2 + cb] = f2b(acc[ng][r] + bv);
            }
        }
        __syncthreads();
        unsigned* outw = (unsigned*)eeout;
        #pragma unroll
        for (int i = 0; i < 4; ++i) {
            int j = i * 1024 + t * 4;
            int row = j >> 6, cp = j & 63;
            uint4 v = *(const uint4*)&Bt[(row << 6) + (cp ^ ((row & 7) << 2))];
            int grow = rowBase + row;
            if (grow < rowsE) *(uint4*)&outw[(size_t)grow * 64 + cp] = v;
        }
        return;
    }

    // ---- q/k/v/skip single GEMMs (y = 0..3) ----
    int bidx = (int)blockIdx.x - rtE;
    const int y = bidx / rtN;
    const int rowBase = (bidx % rtN) << 6;
    const unsigned* Wp = Wp4 + y * 8192;
    #pragma unroll
    for (int i = 0; i < 8; ++i)
        *(uint4*)&Bt[(i * 256 + t) * 4] = *(const uint4*)&Wp[(i * 256 + t) * 4];
    int arow = rowBase + wid * 16 + (lane & 15);
    if (arow > rowsN - 1) arow = rowsN - 1;
    short8 a[4];
    #pragma unroll
    for (int kc = 0; kc < 4; ++kc)
        a[kc] = *(const short8*)(xb + (size_t)arow * DD + kc * 32 + kqo);
    __syncthreads();
    f32x4 acc[8];
    #pragma unroll
    for (int i = 0; i < 8; ++i) acc[i] = (f32x4){0.f, 0.f, 0.f, 0.f};
    #pragma unroll
    for (int ng = 0; ng < 8; ++ng) {
        int col = ng * 16 + (lane & 15);
        #pragma unroll
        for (int kc = 0; kc < 4; ++kc) {
            int kidx = kc * 16 + (lane >> 4) * 4;
            const short8 b = *(const short8*)((const char*)Bt +
                    ((((col << 6) + kidx) ^ ((col & 7) << 2)) << 2));
            acc[ng] = __builtin_amdgcn_mfma_f32_16x16x32_bf16(a[kc], b, acc[ng], 0, 0, 0);
        }
    }
    const float* bs = bias.b[y];
    if (y == 3) {
        #pragma unroll
        for (int ng = 0; ng < 8; ++ng) {
            int col = ng * 16 + (lane & 15);
            float bv = bs[col];
            #pragma unroll
            for (int r = 0; r < 4; ++r) {
                int grow = rowBase + wid * 16 + (lane >> 4) * 4 + r;
                if (grow < rowsN) rbuf[(size_t)grow * DD + col] = acc[ng][r] + bv;
            }
        }
        return;
    }
    __syncthreads();
    unsigned short* sb16 = (unsigned short*)Bt;
    #pragma unroll
    for (int ng = 0; ng < 8; ++ng) {
        int col = ng * 16 + (lane & 15);
        float bv = bs[col];
        int cp = col >> 1, cb = col & 1;
        #pragma unroll
        for (int r = 0; r < 4; ++r) {
            int row = wid * 16 + (lane >> 4) * 4 + r;
            sb16[((row << 6) + (cp ^ ((row & 7) << 2))) * 2 + cb] = f2b(acc[ng][r] + bv);
        }
    }
    __syncthreads();
    unsigned* outw = (unsigned*)qkv;
    #pragma unroll
    for (int i = 0; i < 4; ++i) {
        int j = i * 1024 + t * 4;
        int row = j >> 6, cp = j & 63;
        uint4 v = *(const uint4*)&Bt[(row << 6) + (cp ^ ((row & 7) << 2))];
        int grow = rowBase + row;
        if (grow < rowsN) *(uint4*)&outw[(size_t)grow * 192 + (y << 6) + cp] = v;
    }
}

// ---------- generic MFMA GEMM (f32 weights, bf16 A), bf16 out (used by heads) ----------
template <int ACT>
__global__ __launch_bounds__(256) void mgemm(
        const unsigned short* __restrict__ A, const float* __restrict__ W,
        const float* __restrict__ bias, unsigned short* __restrict__ out,
        int rows, int K, int Dout) {
    __shared__ unsigned Bt[8192];
    const int t = threadIdx.x;
    const int rowBase = blockIdx.x << 6;
    const int colBase = blockIdx.y << 7;
    const int lane = t & 63, wid = t >> 6;
    f32x4 acc[8];
    #pragma unroll
    for (int i = 0; i < 8; ++i) acc[i] = (f32x4){0.f, 0.f, 0.f, 0.f};
    int arow = rowBase + wid * 16 + (lane & 15);
    if (arow > rows - 1) arow = rows - 1;
    const int kqo = (lane >> 4) * 8;
    for (int k0 = 0; k0 < K; k0 += 128) {
        if (k0) __syncthreads();
        #pragma unroll 8
        for (int it = 0; it < 32; ++it) {
            int idx = it * 256 + t;
            int n = idx & 127, kp = idx >> 7;
            int krow = k0 + kp * 2;
            float w0 = W[(size_t)krow * Dout + colBase + n];
            float w1 = W[(size_t)(krow + 1) * Dout + colBase + n];
            Bt[((n << 6) + kp) ^ ((n & 7) << 2)] = packbf(w0, w1);
        }
        __syncthreads();
        short8 a[4];
        #pragma unroll
        for (int kc = 0; kc < 4; ++kc)
            a[kc] = *(const short8*)(A + (size_t)arow * K + k0 + kc * 32 + kqo);
        #pragma unroll
        for (int ng = 0; ng < 8; ++ng) {
            int col = ng * 16 + (lane & 15);
            #pragma unroll
            for (int kc = 0; kc < 4; ++kc) {
                int kidx = kc * 16 + (lane >> 4) * 4;
                const short8 b = *(const short8*)((const char*)Bt +
                        ((((col << 6) + kidx) ^ ((col & 7) << 2)) << 2));
                acc[ng] = __builtin_amdgcn_mfma_f32_16x16x32_bf16(a[kc], b, acc[ng], 0, 0, 0);
            }
        }
    }
    __syncthreads();
    unsigned short* sb16 = (unsigned short*)Bt;
    #pragma unroll
    for (int ng = 0; ng < 8; ++ng) {
        int col = ng * 16 + (lane & 15);
        float bv = bias[colBase + col];
        int cp = col >> 1, cb = col & 1;
        #pragma unroll
        for (int r = 0; r < 4; ++r) {
            int row = wid * 16 + (lane >> 4) * 4 + r;
            float val = acc[ng][r] + bv;
            if (ACT == 1) val = 0.5f * val * (1.f + erff(val * 0.70710678118654752f));
            else if (ACT == 2) val = fmaxf(val, 0.f);
            sb16[((row << 6) + (cp ^ ((row & 7) << 2))) * 2 + cb] = f2b(val);
        }
    }
    __syncthreads();
    unsigned* outw = (unsigned*)out;
    const int strideU = Dout >> 1, cbU = colBase >> 1;
    #pragma unroll
    for (int i = 0; i < 4; ++i) {
        int j = i * 1024 + t * 4;
        int row = j >> 6, cp = j & 63;
        uint4 v = *(const uint4*)&Bt[(row << 6) + (cp ^ ((row & 7) << 2))];
        int grow = rowBase + row;
        if (grow < rows) *(uint4*)&outw[(size_t)grow * strideU + cbU + cp] = v;
    }
}

// ---------- fused FFN: h1 = gelu(xb@fW1+fb1) in LDS; x,xb = LN(h1@fW2+fb2 + x) ----------
__global__ __launch_bounds__(256) void ffn_fused(
        const unsigned short* __restrict__ xbin, const float* __restrict__ W1,
        const float* __restrict__ b1f, const float* __restrict__ W2,
        const float* __restrict__ b2f, const float* __restrict__ g,
        const float* __restrict__ bbn, float* __restrict__ x,
        unsigned short* __restrict__ xb, int rows) {
    __shared__ unsigned Bt[8192];   // weight staging / final transpose-out
    __shared__ unsigned h1t[8192];  // 64 x 256 bf16 h1 tile
    const int t = threadIdx.x;
    const int rowBase = blockIdx.x << 6;
    const int lane = t & 63, wid = t >> 6;
    const int kqo = (lane >> 4) * 8;
    int arow = rowBase + wid * 16 + (lane & 15);
    if (arow > rows - 1) arow = rows - 1;

    short8 a[4];
    #pragma unroll
    for (int kc = 0; kc < 4; ++kc)
        a[kc] = *(const short8*)(xbin + (size_t)arow * DD + kc * 32 + kqo);

    unsigned short* h16 = (unsigned short*)h1t;
    for (int half = 0; half < 2; ++half) {
        if (half) __syncthreads();
        #pragma unroll 8
        for (int it = 0; it < 32; ++it) {
            int idx = it * 256 + t;
            int n = idx & 127, kp = idx >> 7;
            float w0 = W1[(size_t)(2 * kp) * 256 + half * 128 + n];
            float w1 = W1[(size_t)(2 * kp + 1) * 256 + half * 128 + n];
            Bt[((n << 6) + kp) ^ ((n & 7) << 2)] = packbf(w0, w1);
        }
        __syncthreads();
        f32x4 acc[8];
        #pragma unroll
        for (int i = 0; i < 8; ++i) acc[i] = (f32x4){0.f, 0.f, 0.f, 0.f};
        #pragma unroll
        for (int ng = 0; ng < 8; ++ng) {
            int col = ng * 16 + (lane & 15);
            #pragma unroll
            for (int kc = 0; kc < 4; ++kc) {
                int kidx = kc * 16 + (lane >> 4) * 4;
                const short8 b = *(const short8*)((const char*)Bt +
                        ((((col << 6) + kidx) ^ ((col & 7) << 2)) << 2));
                acc[ng] = __builtin_amdgcn_mfma_f32_16x16x32_bf16(a[kc], b, acc[ng], 0, 0, 0);
            }
        }
        #pragma unroll
        for (int ng = 0; ng < 8; ++ng) {
            int col = half * 128 + ng * 16 + (lane & 15);
            float bv = b1f[col];
            int cp = col >> 1, cb = col & 1;
            #pragma unroll
            for (int r = 0; r < 4; ++r) {
                int row = wid * 16 + (lane >> 4) * 4 + r;
                float val = acc[ng][r] + bv;
                val = 0.5f * val * (1.f + erff(val * 0.70710678118654752f));
                h16[((row << 7) + (cp ^ ((row & 7) << 2))) * 2 + cb] = f2b(val);
            }
        }
    }
    f32x4 accF[8];
    #pragma unroll
    for (int i = 0; i < 8; ++i) accF[i] = (f32x4){0.f, 0.f, 0.f, 0.f};
    const int lrow = wid * 16 + (lane & 15);
    for (int c = 0; c < 2; ++c) {
        __syncthreads();
        #pragma unroll 8
        for (int it = 0; it < 32; ++it) {
            int idx = it * 256 + t;
            int n = idx & 127, kp = idx >> 7;
            int krow = c * 128 + kp * 2;
            float w0 = W2[(size_t)krow * DD + n];
            float w1 = W2[(size_t)(krow + 1) * DD + n];
            Bt[((n << 6) + kp) ^ ((n & 7) << 2)] = packbf(w0, w1);
        }
        __syncthreads();
        short8 ah[4];
        #pragma unroll
        for (int kc = 0; kc < 4; ++kc) {
            int cp4 = c * 64 + kc * 16 + (lane >> 4) * 4;
            ah[kc] = *(const short8*)&h1t[(lrow << 7) + (cp4 ^ ((lrow & 7) << 2))];
        }
        #pragma unroll
        for (int ng = 0; ng < 8; ++ng) {
            int col = ng * 16 + (lane & 15);
            #pragma unroll
            for (int kc = 0; kc < 4; ++kc) {
                int kidx = kc * 16 + (lane >> 4) * 4;
                const short8 b = *(const short8*)((const char*)Bt +
                        ((((col << 6) + kidx) ^ ((col & 7) << 2)) << 2));
                accF[ng] = __builtin_amdgcn_mfma_f32_16x16x32_bf16(ah[kc], b, accF[ng], 0, 0, 0);
            }
        }
    }
    float tt[8][4];
    float rs[4] = {0.f, 0.f, 0.f, 0.f}, rs2[4] = {0.f, 0.f, 0.f, 0.f};
    #pragma unroll
    for (int ng = 0; ng < 8; ++ng) {
        int col = ng * 16 + (lane & 15);
        float bv = b2f[col];
        #pragma unroll
        for (int r = 0; r < 4; ++r) {
            int grow = rowBase + wid * 16 + (lane >> 4) * 4 + r;
            float xo = (grow < rows) ? x[(size_t)grow * DD + col] : 0.f;
            float v = accF[ng][r] + bv + xo;
            tt[ng][r] = v;
            rs[r] += v;
            rs2[r] += v * v;
        }
    }
    #pragma unroll
    for (int r = 0; r < 4; ++r) {
        #pragma unroll
        for (int m = 1; m < 16; m <<= 1) {
            rs[r] += __shfl_xor(rs[r], m);
            rs2[r] += __shfl_xor(rs2[r], m);
        }
    }
    __syncthreads();
    unsigned short* sb16 = (unsigned short*)Bt;
    #pragma unroll
    for (int ng = 0; ng < 8; ++ng) {
        int col = ng * 16 + (lane & 15);
        float gg = g[col], bbb = bbn[col];
        int cp = col >> 1, cb = col & 1;
        #pragma unroll
        for (int r = 0; r < 4; ++r) {
            int grow = rowBase + wid * 16 + (lane >> 4) * 4 + r;
            float mean = rs[r] * (1.f / DD);
            float var = rs2[r] * (1.f / DD) - mean * mean;
            float val = (tt[ng][r] - mean) * rsqrtf(var + 1e-5f) * gg + bbb;
            if (grow < rows) x[(size_t)grow * DD + col] = val;
            int row = wid * 16 + (lane >> 4) * 4 + r;
            sb16[((row << 6) + (cp ^ ((row & 7) << 2))) * 2 + cb] = f2b(val);
        }
    }
    __syncthreads();
    unsigned* outw = (unsigned*)xb;
    #pragma unroll
    for (int i = 0; i < 4; ++i) {
        int j = i * 1024 + t * 4;
        int row = j >> 6, cp = j & 63;
        uint4 v = *(const uint4*)&Bt[(row << 6) + (cp ^ ((row & 7) << 2))];
        int grow = rowBase + row;
        if (grow < rows) *(uint4*)&outw[(size_t)grow * 64 + cp] = v;
    }
}

// ---------- small kernels ----------

__global__ void enc_kernel(const float* __restrict__ xyz, const float* __restrict__ attr,
                           const float* __restrict__ W, const float* __restrict__ b,
                           const float* __restrict__ g, const float* __restrict__ bb,
                           float* __restrict__ x, unsigned short* __restrict__ xb) {
    int i = blockIdx.x, d = threadIdx.x;
    __shared__ float sin4[4];
    if (d < 3) sin4[d] = xyz[i * 3 + d];
    if (d == 3) sin4[3] = attr[i];
    __syncthreads();
    float y = b[d];
    #pragma unroll
    for (int kk = 0; kk < 4; ++kk) y += sin4[kk] * W[kk * DD + d];
    float s = y, s2 = y * y;
    redsum2_128(s, s2);
    float mean = s * (1.0f / DD);
    float var = s2 * (1.0f / DD) - mean * mean;
    float xn = fmaxf((y - mean) * rsqrtf(var + 1e-5f) * g[d] + bb[d], 0.f);
    x[i * DD + d] = xn;
    xb[(size_t)i * DD + d] = f2b(xn);
}

// pw[0:512): gc0,gc1,gc2,gbc (g-scaled centered cols); pw[512:522): quad consts
__global__ void posprep_kernel(const float* __restrict__ W1, const float* __restrict__ b1,
                               const float* __restrict__ g, float* __restrict__ pw) {
    int d = threadIdx.x;
    float w0 = W1[d], w1 = W1[DD + d], w2 = W1[2 * DD + d], b = b1[d];
    float s0 = w0, s1 = w1;
    redsum2_128(s0, s1);
    float s2 = w2, s3 = b;
    redsum2_128(s2, s3);
    float c0 = w0 - s0 * (1.f / DD), c1 = w1 - s1 * (1.f / DD);
    float c2 = w2 - s2 * (1.f / DD), bc = b - s3 * (1.f / DD);
    float gd = g[d];
    pw[d] = c0 * gd; pw[DD + d] = c1 * gd; pw[2 * DD + d] = c2 * gd; pw[3 * DD + d] = bc * gd;
    float p0 = c0 * c0, p1 = c0 * c1; redsum2_128(p0, p1);
    float p2 = c0 * c2, p3 = c1 * c1; redsum2_128(p2, p3);
    float p4 = c1 * c2, p5 = c2 * c2; redsum2_128(p4, p5);
    float p6 = c0 * bc, p7 = c1 * bc; redsum2_128(p6, p7);
    float p8 = c2 * bc, p9 = bc * bc; redsum2_128(p8, p9);
    if (d == 0) {
        pw[512] = p0 * (1.f / DD); pw[513] = p1 * (1.f / DD); pw[514] = p2 * (1.f / DD);
        pw[515] = p3 * (1.f / DD); pw[516] = p4 * (1.f / DD); pw[517] = p5 * (1.f / DD);
        pw[518] = p6 * (1.f / DD); pw[519] = p7 * (1.f / DD); pw[520] = p8 * (1.f / DD);
        pw[521] = p9 * (1.f / DD);
    }
}

// ---------- CSR build ----------

__global__ void hist_kernel(const int* __restrict__ ei, int* __restrict__ deg, int E) {
    int e = blockIdx.x * blockDim.x + threadIdx.x;
    if (e < E) atomicAdd(&deg[ei[E + e]], 1);
}

__global__ void scan_kernel(const int* __restrict__ deg, int* __restrict__ ptr, int n) {
    __shared__ int partial[1024];
    int t = threadIdx.x;
    int CH = (n + 1023) >> 10;
    int beg = t * CH;
    int end = beg + CH; if (end > n) end = n;
    int s = 0;
    for (int i = beg; i < end; ++i) s += deg[i];
    partial[t] = s;
    __syncthreads();
    for (int off = 1; off < 1024; off <<= 1) {
        int add = (t >= off) ? partial[t - off] : 0;
        __syncthreads();
        partial[t] += add;
        __syncthreads();
    }
    int base = (t == 0) ? 0 : partial[t - 1];
    for (int i = beg; i < end; ++i) {
        ptr[i] = base;
        base += deg[i];
    }
    if (end == n && beg < n) ptr[n] = base;
}

// scatter + per-edge rel/LN-inv (rel4, cs_src in CSR slot order)
__global__ void scatter_kernel(const int* __restrict__ ei, const float* __restrict__ xyz,
                               const float* __restrict__ pw, const int* __restrict__ ptr,
                               int* __restrict__ cur, int* __restrict__ cs_src,
                               float4* __restrict__ rel4, int E) {
    int e = blockIdx.x * blockDim.x + threadIdx.x;
    if (e >= E) return;
    int srcn = ei[e], dstn = ei[E + e];
    int p = atomicAdd(&cur[dstn], 1);
    int slot = ptr[dstn] + p;
    cs_src[slot] = srcn;
    float r0 = xyz[dstn * 3]     - xyz[srcn * 3];
    float r1 = xyz[dstn * 3 + 1] - xyz[srcn * 3 + 1];
    float r2 = xyz[dstn * 3 + 2] - xyz[srcn * 3 + 2];
    float var = pw[512] * r0 * r0 + pw[515] * r1 * r1 + pw[517] * r2 * r2
              + 2.f * (pw[513] * r0 * r1 + pw[514] * r0 * r2 + pw[516] * r1 * r2)
              + 2.f * (pw[518] * r0 + pw[519] * r1 + pw[520] * r2) + pw[521];
    rel4[slot] = make_float4(r0, r1, r2, rsqrtf(var + 1e-5f));
}

// ---------- fused agg: 4 waves per node (quarter edges each) + beta gate + LN1 ----------
__global__ __launch_bounds__(256) void aggc_kernel(
        const unsigned* __restrict__ qkv, const unsigned* __restrict__ ee,
        const int* __restrict__ ptr, const int* __restrict__ cs_src,
        const float* __restrict__ r, const float* __restrict__ Wb,
        const float* __restrict__ g1, const float* __restrict__ b1,
        float* __restrict__ x, unsigned* __restrict__ xbw, int N) {
    const int wave = threadIdx.x >> 6;        // 0..3
    const int lane = threadIdx.x & 63;
    const int node = blockIdx.x;
    __shared__ float sS[4];
    __shared__ float sA0[4][64];
    __shared__ float sA1[4][64];

    unsigned qp = qkv[(size_t)node * 192 + lane];
    float q0 = b2f((unsigned short)qp), q1 = b2f((unsigned short)(qp >> 16));
    int beg = ptr[node], end = ptr[node + 1];
    float s = 0.f, a0 = 0.f, a1 = 0.f;
    int idx = beg + wave;
    unsigned epN = 0, kpN = 0, vpN = 0;
    if (idx < end) {
        int j = cs_src[idx];
        epN = __builtin_nontemporal_load(&ee[(size_t)idx * 64 + lane]);
        kpN = qkv[(size_t)j * 192 + 64 + lane];
        vpN = qkv[(size_t)j * 192 + 128 + lane];
    }
    for (; idx < end; idx += 4) {
        unsigned ep = epN, kp = kpN, vp = vpN;
        int nidx = idx + 4;
        if (nidx < end) {
            int jn = cs_src[nidx];
            epN = __builtin_nontemporal_load(&ee[(size_t)nidx * 64 + lane]);
            kpN = qkv[(size_t)jn * 192 + 64 + lane];
            vpN = qkv[(size_t)jn * 192 + 128 + lane];
        }
        float e0 = b2f((unsigned short)ep), e1 = b2f((unsigned short)(ep >> 16));
        float kj0 = b2f((unsigned short)kp) + e0;
        float kj1 = b2f((unsigned short)(kp >> 16)) + e1;
        float p = q0 * kj0 + q1 * kj1;
        p += __shfl_xor(p, 1); p += __shfl_xor(p, 2);
        p += __shfl_xor(p, 4); p += __shfl_xor(p, 8);
        float w = __expf(p * 0.17677669529663687f);  // |alpha| << 1: max-shift not needed
        s += w;
        a0 += (b2f((unsigned short)vp) + e0) * w;
        a1 += (b2f((unsigned short)(vp >> 16)) + e1) * w;
    }
    sS[wave] = s;
    sA0[wave][lane] = a0;
    sA1[wave][lane] = a1;
    __syncthreads();
    if (wave != 0) return;
    s  = sS[0] + sS[1] + sS[2] + sS[3];
    a0 = sA0[0][lane] + sA0[1][lane] + sA0[2][lane] + sA0[3][lane];
    a1 = sA1[0][lane] + sA1[1][lane] + sA1[2][lane] + sA1[3][lane];

    float inv_s = (s > 0.f) ? 1.f / s : 0.f;
    float od0 = a0 * inv_s, od1 = a1 * inv_s;
    float2 rd = *(const float2*)&r[(size_t)node * DD + lane * 2];
    float2 wb0 = *(const float2*)&Wb[lane * 2];
    float2 wb1 = *(const float2*)&Wb[DD + lane * 2];
    float2 wb2 = *(const float2*)&Wb[2 * DD + lane * 2];
    float part = od0 * wb0.x + rd.x * wb1.x + (od0 - rd.x) * wb2.x
               + od1 * wb0.y + rd.y * wb1.y + (od1 - rd.y) * wb2.y;
    #pragma unroll
    for (int m = 1; m < 64; m <<= 1) part += __shfl_xor(part, m);
    float beta = 1.f / (1.f + __expf(-part));
    float2 xo = *(const float2*)&x[(size_t)node * DD + lane * 2];
    float t0 = beta * rd.x + (1.f - beta) * od0 + xo.x;
    float t1 = beta * rd.y + (1.f - beta) * od1 + xo.y;
    float ss = t0 + t1, ss2 = t0 * t0 + t1 * t1;
    #pragma unroll
    for (int m = 1; m < 64; m <<= 1) { ss += __shfl_xor(ss, m); ss2 += __shfl_xor(ss2, m); }
    float mean = ss * (1.f / DD);
    float var = ss2 * (1.f / DD) - mean * mean;
    float inv = rsqrtf(var + 1e-5f);
    float2 gg = *(const float2*)&g1[lane * 2];
    float2 bbv = *(const float2*)&b1[lane * 2];
    float2 res;
    res.x = (t0 - mean) * inv * gg.x + bbv.x;
    res.y = (t1 - mean) * inv * gg.y + bbv.y;
    *(float2*)&x[(size_t)node * DD + lane * 2] = res;
    xbw[(size_t)node * 64 + lane] = packbf(res.x, res.y);
}

// ---------- heads ----------

__global__ void headprep_kernel(const float* __restrict__ cW1, const float* __restrict__ cb1,
                                const float* __restrict__ bW1, const float* __restrict__ bb1,
                                float* __restrict__ W1cat, float* __restrict__ b1cat) {
    int kk = blockIdx.x, d = threadIdx.x;
    W1cat[kk * DD + d] = (d < 64) ? cW1[kk * 64 + d] : bW1[kk * 64 + (d - 64)];
    if (kk == 0) b1cat[d] = (d < 64) ? cb1[d] : bb1[d - 64];
}

__global__ __launch_bounds__(256) void heads2_kernel(
        const unsigned* __restrict__ hh, const float* __restrict__ cW2,
        const float* __restrict__ cb2, const float* __restrict__ bW2,
        const float* __restrict__ bb2, float* __restrict__ outc,
        float* __restrict__ outb, int N) {
    int node = (blockIdx.x << 2) + (threadIdx.x >> 6);
    if (node >= N) return;
    const int lane = threadIdx.x & 63;
    unsigned hp = hh[(size_t)node * 64 + lane];
    float h0 = b2f((unsigned short)hp), h1 = b2f((unsigned short)(hp >> 16));
    bool isCls = lane < 32;
    int dd = isCls ? 2 * lane : 2 * lane - 128 + 64;
    float c[4], bx[7];
    #pragma unroll
    for (int j = 0; j < 4; ++j)
        c[j] = isCls ? h0 * cW2[dd * 4 + j] + h1 * cW2[(dd + 1) * 4 + j] : 0.f;
    #pragma unroll
    for (int j = 0; j < 7; ++j)
        bx[j] = isCls ? 0.f : h0 * bW2[dd * 7 + j] + h1 * bW2[(dd + 1) * 7 + j];
    #pragma unroll
    for (int m = 1; m < 32; m <<= 1) {
        #pragma unroll
        for (int j = 0; j < 4; ++j) c[j] += __shfl_xor(c[j], m);
        #pragma unroll
        for (int j = 0; j < 7; ++j) bx[j] += __shfl_xor(bx[j], m);
    }
    if (lane == 0) {
        #pragma unroll
        for (int j = 0; j < 4; ++j) outc[(size_t)node * 4 + j] = c[j] + cb2[j];
    } else if (lane == 32) {
        #pragma unroll
        for (int j = 0; j < 7; ++j) outb[(size_t)node * 7 + j] = bx[j] + bb2[j];
    }
}

extern "C" void kernel_launch(void* const* d_in, const int* in_sizes, int n_in,
                              void* d_out, int out_size, void* d_ws, size_t ws_size,
                              hipStream_t stream) {
    const float* xyz   = (const float*)d_in[0];
    const float* attr  = (const float*)d_in[1];
    const int*   ei    = (const int*)d_in[2];
    const float* encW  = (const float*)d_in[3];
    const float* encb  = (const float*)d_in[4];
    const float* encg  = (const float*)d_in[5];
    const float* encbb = (const float*)d_in[6];
    const float* posW1 = (const float*)d_in[7];
    const float* posb1 = (const float*)d_in[8];
    const float* posg  = (const float*)d_in[9];
    const float* posbb = (const float*)d_in[10];
    const float* posW2 = (const float*)d_in[11];
    const float* posb2 = (const float*)d_in[12];
    const float* Wq    = (const float*)d_in[13];
    const float* bq    = (const float*)d_in[14];
    const float* Wk    = (const float*)d_in[15];
    const float* bk    = (const float*)d_in[16];
    const float* Wv    = (const float*)d_in[17];
    const float* bv    = (const float*)d_in[18];
    const float* We    = (const float*)d_in[19];
    const float* Wskip = (const float*)d_in[20];
    const float* bskip = (const float*)d_in[21];
    const float* Wbeta = (const float*)d_in[22];
    const float* ln1g  = (const float*)d_in[23];
    const float* ln1b  = (const float*)d_in[24];
    const float* ln2g  = (const float*)d_in[25];
    const float* ln2b  = (const float*)d_in[26];
    const float* fW1   = (const float*)d_in[27];
    const float* fb1   = (const float*)d_in[28];
    const float* fW2   = (const float*)d_in[29];
    const float* fb2   = (const float*)d_in[30];
    const float* cW1   = (const float*)d_in[31];
    const float* cb1   = (const float*)d_in[32];
    const float* cW2   = (const float*)d_in[33];
    const float* cb2   = (const float*)d_in[34];
    const float* bW1   = (const float*)d_in[35];
    const float* bb1   = (const float*)d_in[36];
    const float* bW2   = (const float*)d_in[37];
    const float* bb2   = (const float*)d_in[38];

    const int N = in_sizes[0] / 3;
    const int E = in_sizes[2] / 2;

    size_t off = 0;
    auto alloc = [&](size_t nelem) {
        char* p = (char*)d_ws + off;
        off += nelem * sizeof(float);
        return (float*)p;
    };
    float* x     = alloc((size_t)N * DD);
    unsigned short* qkv = (unsigned short*)alloc((size_t)N * 192);   // N*384 bf16 [q|k|v]
    float* r     = alloc((size_t)N * DD);
    unsigned short* h1 = (unsigned short*)alloc((size_t)N * 128);    // heads temp
    unsigned short* xb = (unsigned short*)alloc((size_t)N * 64);     // N*128 bf16
    float4* rel4 = (float4*)alloc((size_t)E * 4);                    // CSR-order rel + inv
    unsigned short* eeb = (unsigned short*)alloc((size_t)E * 64);    // E*128 bf16 (CSR order)
    unsigned* W2Wep = (unsigned*)alloc(3 * 8192);                    // folded packed weights
    float* b2We  = alloc(3 * DD);
    unsigned* Wp12 = (unsigned*)alloc(12 * 8192);                    // q/k/v/skip packed
    float* pw    = alloc(544);
    float* W1cat = alloc(DD * DD);
    float* b1cat = alloc(DD);
    int* deg     = (int*)alloc(N);
    int* ptr     = (int*)alloc(N + 1);
    int* cur     = (int*)alloc(N);
    int* cs_src  = (int*)alloc(E);

    const int rtN = (N + 63) / 64;
    const int rtE = (E + 63) / 64;

    // ---- once: encoder, CSR build (+rel4), packed weights ----
    enc_kernel<<<N, DD, 0, stream>>>(xyz, attr, encW, encb, encg, encbb, x, xb);
    hipMemsetAsync(deg, 0, N * sizeof(int), stream);
    hipMemsetAsync(cur, 0, N * sizeof(int), stream);
    hist_kernel<<<(E + 255) / 256, 256, 0, stream>>>(ei, deg, E);
    scan_kernel<<<1, 1024, 0, stream>>>(deg, ptr, N);
    posprep_kernel<<<1, DD, 0, stream>>>(posW1, posb1, posg, pw);
    scatter_kernel<<<(E + 255) / 256, 256, 0, stream>>>(ei, xyz, pw, ptr, cur, cs_src, rel4, E);
    wcombp_kernel<<<dim3(65, 3), DD, 0, stream>>>(posW2, posb2, We, W2Wep, b2We);
    packw12_kernel<<<dim3(64, 12), DD, 0, stream>>>(Wq, Wk, Wv, Wskip, Wp12);
    headprep_kernel<<<DD, DD, 0, stream>>>(cW1, cb1, bW1, bb1, W1cat, b1cat);

    for (int l = 0; l < 3; ++l) {
        const float* Wb_l = Wbeta + (size_t)l * 3 * DD;
        const float* fW1_l = fW1 + (size_t)l * DD * 256;
        const float* fW2_l = fW2 + (size_t)l * 256 * DD;
        B4 bs;
        bs.b[0] = bq + l * DD; bs.b[1] = bk + l * DD;
        bs.b[2] = bv + l * DD; bs.b[3] = bskip + l * DD;

        // merged: ee GEMM (on-the-fly A) + q/k/v/skip GEMMs in one dispatch
        proj_kernel<<<rtE + 4 * rtN, 256, 0, stream>>>(
            xb, Wp12 + (size_t)l * 4 * 8192, bs, qkv, r, N, rtN,
            rel4, pw, posbb, W2Wep + l * 8192, b2We + l * DD, eeb, E, rtE);

        // fused: softmax agg (4 waves/node, pipelined) + beta gate + residual + LN1
        aggc_kernel<<<N, 256, 0, stream>>>((const unsigned*)qkv, (const unsigned*)eeb,
                                           ptr, cs_src, r, Wb_l,
                                           ln1g + l * DD, ln1b + l * DD,
                                           x, (unsigned*)xb, N);

        // fused FFN: h1 in LDS; x,xb = LN(gelu(xb@fW1+fb1)@fW2+fb2 + x)
        ffn_fused<<<rtN, 256, 0, stream>>>(xb, fW1_l, fb1 + l * 256, fW2_l, fb2 + l * DD,
                                           ln2g + l * DD, ln2b + l * DD, x, xb, N);
    }

    // ---- heads ----
    float* outc  = (float*)d_out;
    float* outbx = (float*)d_out + (size_t)N * 4;
    mgemm<2><<<dim3(rtN, 1), 256, 0, stream>>>(xb, W1cat, b1cat, h1, N, DD, DD);
    heads2_kernel<<<(N + 3) / 4, 256, 0, stream>>>((const unsigned*)h1, cW2, cb2, bW2, bb2,
                                                   outc, outbx, N);
}

// Round 15
// 371.677 us; speedup vs baseline: 1.1887x; 1.1483x over previous
//
#include <hip/hip_runtime.h>
#include <hip/hip_bf16.h>
#include <math.h>

#define DD 128

typedef __attribute__((ext_vector_type(8))) short short8;
typedef __attribute__((ext_vector_type(4))) float f32x4;

// ---------- helpers ----------

__device__ __forceinline__ unsigned short f2b(float f) {
    unsigned u = __float_as_uint(f);
    return (unsigned short)((u + 0x7FFFu + ((u >> 16) & 1u)) >> 16);
}
__device__ __forceinline__ float b2f(unsigned short b) {
    return __uint_as_float(((unsigned)b) << 16);
}
__device__ __forceinline__ unsigned packbf(float a, float b) {
    return (unsigned)f2b(a) | ((unsigned)f2b(b) << 16);
}

// block = 256 thr, two independent 128-thread halves; returns per-half sums
__device__ __forceinline__ void redsum2_half(float& a, float& b) {
    #pragma unroll
    for (int off = 32; off > 0; off >>= 1) {
        a += __shfl_down(a, off);
        b += __shfl_down(b, off);
    }
    __shared__ float sa[4], sb4[4];
    int w = threadIdx.x >> 6;
    if ((threadIdx.x & 63) == 0) { sa[w] = a; sb4[w] = b; }
    __syncthreads();
    int h = threadIdx.x >> 7;
    a = sa[2 * h] + sa[2 * h + 1];
    b = sb4[2 * h] + sb4[2 * h + 1];
    __syncthreads();
}

// ---------- setup1: enc (2 nodes/block) | posprep | hist ----------
__global__ __launch_bounds__(256) void setup1_kernel(
        const float* __restrict__ xyz, const float* __restrict__ attr,
        const float* __restrict__ encW, const float* __restrict__ encb,
        const float* __restrict__ encg, const float* __restrict__ encbb,
        float* __restrict__ x, unsigned short* __restrict__ xbuf,
        const float* __restrict__ posW1, const float* __restrict__ posb1,
        const float* __restrict__ posg, float* __restrict__ pw,
        const int* __restrict__ ei, int* __restrict__ deg,
        int N, int E, int encBlocks) {
    const int b = blockIdx.x, t = threadIdx.x;
    if (b < encBlocks) {
        const int h = t >> 7, d = t & 127;
        const int node = b * 2 + h;
        const bool ok = node < N;
        __shared__ float sin4[2][4];
        if (ok && d < 3) sin4[h][d] = xyz[node * 3 + d];
        if (ok && d == 3) sin4[h][3] = attr[node];
        __syncthreads();
        float y = encb[d];
        if (ok) {
            #pragma unroll
            for (int kk = 0; kk < 4; ++kk) y += sin4[h][kk] * encW[kk * DD + d];
        }
        float s = y, s2 = y * y;
        redsum2_half(s, s2);
        if (ok) {
            float mean = s * (1.0f / DD);
            float var = s2 * (1.0f / DD) - mean * mean;
            float xn = fmaxf((y - mean) * rsqrtf(var + 1e-5f) * encg[d] + encbb[d], 0.f);
            x[(size_t)node * DD + d] = xn;
            xbuf[(size_t)node * DD + d] = f2b(xn);
        }
    } else if (b == encBlocks) {
        // posprep (both halves duplicate the same work; writes idempotent)
        const int d = t & 127;
        float w0 = posW1[d], w1 = posW1[DD + d], w2 = posW1[2 * DD + d], bb = posb1[d];
        float s0 = w0, s1 = w1;
        redsum2_half(s0, s1);
        float s2 = w2, s3 = bb;
        redsum2_half(s2, s3);
        float c0 = w0 - s0 * (1.f / DD), c1 = w1 - s1 * (1.f / DD);
        float c2 = w2 - s2 * (1.f / DD), bc = bb - s3 * (1.f / DD);
        float gd = posg[d];
        pw[d] = c0 * gd; pw[DD + d] = c1 * gd; pw[2 * DD + d] = c2 * gd; pw[3 * DD + d] = bc * gd;
        float p0 = c0 * c0, p1 = c0 * c1; redsum2_half(p0, p1);
        float p2 = c0 * c2, p3 = c1 * c1; redsum2_half(p2, p3);
        float p4 = c1 * c2, p5 = c2 * c2; redsum2_half(p4, p5);
        float p6 = c0 * bc, p7 = c1 * bc; redsum2_half(p6, p7);
        float p8 = c2 * bc, p9 = bc * bc; redsum2_half(p8, p9);
        if ((t & 127) == 0) {
            pw[512] = p0 * (1.f / DD); pw[513] = p1 * (1.f / DD); pw[514] = p2 * (1.f / DD);
            pw[515] = p3 * (1.f / DD); pw[516] = p4 * (1.f / DD); pw[517] = p5 * (1.f / DD);
            pw[518] = p6 * (1.f / DD); pw[519] = p7 * (1.f / DD); pw[520] = p8 * (1.f / DD);
            pw[521] = p9 * (1.f / DD);
        }
    } else {
        int e = (b - encBlocks - 1) * 256 + t;
        if (e < E) atomicAdd(&deg[ei[E + e]], 1);
    }
}

// ---------- scan (unchanged) ----------
__global__ void scan_kernel(const int* __restrict__ deg, int* __restrict__ ptr, int n) {
    __shared__ int partial[1024];
    int t = threadIdx.x;
    int CH = (n + 1023) >> 10;
    int beg = t * CH;
    int end = beg + CH; if (end > n) end = n;
    int s = 0;
    for (int i = beg; i < end; ++i) s += deg[i];
    partial[t] = s;
    __syncthreads();
    for (int off = 1; off < 1024; off <<= 1) {
        int add = (t >= off) ? partial[t - off] : 0;
        __syncthreads();
        partial[t] += add;
        __syncthreads();
    }
    int base = (t == 0) ? 0 : partial[t - 1];
    for (int i = beg; i < end; ++i) {
        ptr[i] = base;
        base += deg[i];
    }
    if (end == n && beg < n) ptr[n] = base;
}

// ---------- setup2: scatter | wcombp | pack(qkvr+ffn) | headpack | b1cat ----------
// packed blob (8192 u32): blob[((d<<6)+kp)^((d&7)<<2)] = bf16pair(row 2kp, row 2kp+1) at col d
__global__ __launch_bounds__(256) void setup2_kernel(
        const int* __restrict__ ei, const float* __restrict__ xyz,
        const float* __restrict__ pw, const int* __restrict__ ptr,
        int* __restrict__ cur, int* __restrict__ cs_src, float4* __restrict__ rel4, int E,
        const float* __restrict__ W2, const float* __restrict__ b2,
        const float* __restrict__ We, unsigned* __restrict__ W2Wep, float* __restrict__ b2We,
        const float* __restrict__ Wq, const float* __restrict__ Wk,
        const float* __restrict__ Wv, const float* __restrict__ Ws,
        const float* __restrict__ fW1, const float* __restrict__ fW2,
        unsigned* __restrict__ Wpall,
        const float* __restrict__ cW1, const float* __restrict__ bW1,
        unsigned* __restrict__ Whp,
        const float* __restrict__ cb1, const float* __restrict__ bb1,
        float* __restrict__ b1cat, int SC) {
    const int b = blockIdx.x, t = threadIdx.x;
    if (b < SC) {
        int e = b * 256 + t;
        if (e >= E) return;
        int srcn = ei[e], dstn = ei[E + e];
        int p = atomicAdd(&cur[dstn], 1);
        int slot = ptr[dstn] + p;
        cs_src[slot] = srcn;
        float r0 = xyz[dstn * 3]     - xyz[srcn * 3];
        float r1 = xyz[dstn * 3 + 1] - xyz[srcn * 3 + 1];
        float r2 = xyz[dstn * 3 + 2] - xyz[srcn * 3 + 2];
        float var = pw[512] * r0 * r0 + pw[515] * r1 * r1 + pw[517] * r2 * r2
                  + 2.f * (pw[513] * r0 * r1 + pw[514] * r0 * r2 + pw[516] * r1 * r2)
                  + 2.f * (pw[518] * r0 + pw[519] * r1 + pw[520] * r2) + pw[521];
        rel4[slot] = make_float4(r0, r1, r2, rsqrtf(var + 1e-5f));
        return;
    }
    if (b < SC + 99) {
        int z = b - SC;
        int y = z / 33, bp = z % 33;
        int sub = t >> 7, d = t & 127;
        int bid = bp * 2 + sub;
        const float* We_l = We + (size_t)y * DD * DD;
        __shared__ float s0[2][DD], s1[2][DD];
        if (bid < 64)       { s0[sub][d] = W2[(2 * bid) * DD + d]; s1[sub][d] = W2[(2 * bid + 1) * DD + d]; }
        else if (bid == 64) { s0[sub][d] = b2[d]; s1[sub][d] = 0.f; }
        __syncthreads();
        if (bid <= 64) {
            float a0 = 0.f, a1 = 0.f;
            #pragma unroll 8
            for (int kk = 0; kk < DD; ++kk) {
                float w = We_l[kk * DD + d];
                a0 += s0[sub][kk] * w;
                a1 += s1[sub][kk] * w;
            }
            if (bid < 64) W2Wep[y * 8192 + (((d << 6) + bid) ^ ((d & 7) << 2))] = packbf(a0, a1);
            else          b2We[y * DD + d] = a0;
        }
        return;
    }
    if (b < SC + 99 + 768) {
        int z = b - SC - 99;
        int blob = z >> 5, bp = z & 31;
        int kp = bp * 2 + (t >> 7), d = t & 127;
        float w0, w1;
        if (blob < 12) {
            int l = blob >> 2, wt = blob & 3;
            const float* W = (wt == 0 ? Wq : wt == 1 ? Wk : wt == 2 ? Wv : Ws) + (size_t)l * DD * DD;
            w0 = W[(size_t)(2 * kp) * DD + d];
            w1 = W[(size_t)(2 * kp + 1) * DD + d];
        } else if (blob < 18) {
            int i = blob - 12, l = i >> 1, hf = i & 1;
            const float* W = fW1 + (size_t)l * DD * 256;
            w0 = W[(size_t)(2 * kp) * 256 + hf * 128 + d];
            w1 = W[(size_t)(2 * kp + 1) * 256 + hf * 128 + d];
        } else {
            int i = blob - 18, l = i >> 1, c = i & 1;
            const float* W = fW2 + (size_t)l * 256 * DD;
            w0 = W[(size_t)(c * 128 + 2 * kp) * DD + d];
            w1 = W[(size_t)(c * 128 + 2 * kp + 1) * DD + d];
        }
        Wpall[blob * 8192 + (((d << 6) + kp) ^ ((d & 7) << 2))] = packbf(w0, w1);
        return;
    }
    if (b < SC + 99 + 768 + 32) {
        int bp = b - (SC + 99 + 768);
        int kp = bp * 2 + (t >> 7), d = t & 127;
        int k0 = 2 * kp, k1 = 2 * kp + 1;
        float w0 = (d < 64) ? cW1[k0 * 64 + d] : bW1[k0 * 64 + (d - 64)];
        float w1 = (d < 64) ? cW1[k1 * 64 + d] : bW1[k1 * 64 + (d - 64)];
        Whp[((d << 6) + kp) ^ ((d & 7) << 2)] = packbf(w0, w1);
        return;
    }
    if (t < 128) b1cat[t] = (t < 64) ? cb1[t] : bb1[t - 64];
}

// ---------- merged projection kernel: ee GEMM (on-the-fly A) + q/k/v/skip GEMMs ----------
struct B4 { const float* b[4]; };

__global__ __launch_bounds__(256) void proj_kernel(
        const unsigned short* __restrict__ xb, const unsigned* __restrict__ Wp4, B4 bias,
        unsigned short* __restrict__ qkv, float* __restrict__ rbuf, int rowsN, int rtN,
        const float4* __restrict__ rel4, const float* __restrict__ pw,
        const float* __restrict__ bbp, const unsigned* __restrict__ Wpee,
        const float* __restrict__ biasee, unsigned short* __restrict__ eeout,
        int rowsE, int rtE) {
    __shared__ unsigned Bt[8192];
    __shared__ float sc[640];
    const int t = threadIdx.x;
    const int lane = t & 63, wid = t >> 6;
    const int kqo = (lane >> 4) * 8;

    if ((int)blockIdx.x < rtE) {
        const int rowBase = (int)blockIdx.x << 6;
        #pragma unroll
        for (int i = 0; i < 8; ++i)
            *(uint4*)&Bt[(i * 256 + t) * 4] = *(const uint4*)&Wpee[(i * 256 + t) * 4];
        for (int i = t; i < 640; i += 256)
            sc[i] = (i < 512) ? pw[i] : bbp[i - 512];
        int arow = rowBase + wid * 16 + (lane & 15);
        if (arow > rowsE - 1) arow = rowsE - 1;
        float4 rv = rel4[arow];
        __syncthreads();
        short8 a[4];
        #pragma unroll
        for (int kc = 0; kc < 4; ++kc) {
            union { short8 s; unsigned short u[8]; } cv;
            #pragma unroll
            for (int j = 0; j < 8; ++j) {
                int d = kc * 32 + kqo + j;
                float y = fmaf(rv.x, sc[d], fmaf(rv.y, sc[128 + d], fmaf(rv.z, sc[256 + d], sc[384 + d])));
                cv.u[j] = f2b(fmaxf(fmaf(y, rv.w, sc[512 + d]), 0.f));
            }
            a[kc] = cv.s;
        }
        f32x4 acc[8];
        #pragma unroll
        for (int i = 0; i < 8; ++i) acc[i] = (f32x4){0.f, 0.f, 0.f, 0.f};
        #pragma unroll
        for (int ng = 0; ng < 8; ++ng) {
            int col = ng * 16 + (lane & 15);
            #pragma unroll
            for (int kc = 0; kc < 4; ++kc) {
                int kidx = kc * 16 + (lane >> 4) * 4;
                const short8 b = *(const short8*)((const char*)Bt +
                        ((((col << 6) + kidx) ^ ((col & 7) << 2)) << 2));
                acc[ng] = __builtin_amdgcn_mfma_f32_16x16x32_bf16(a[kc], b, acc[ng], 0, 0, 0);
            }
        }
        __syncthreads();
        unsigned short* sb16 = (unsigned short*)Bt;
        #pragma unroll
        for (int ng = 0; ng < 8; ++ng) {
            int col = ng * 16 + (lane & 15);
            float bv = biasee[col];
            int cp = col >> 1, cb = col & 1;
            #pragma unroll
            for (int r = 0; r < 4; ++r) {
                int row = wid * 16 + (lane >> 4) * 4 + r;
                sb16[((row << 6) + (cp ^ ((row & 7) << 2))) * 2 + cb] = f2b(acc[ng][r] + bv);
            }
        }
        __syncthreads();
        unsigned* outw = (unsigned*)eeout;
        #pragma unroll
        for (int i = 0; i < 4; ++i) {
            int j = i * 1024 + t * 4;
            int row = j >> 6, cp = j & 63;
            uint4 v = *(const uint4*)&Bt[(row << 6) + (cp ^ ((row & 7) << 2))];
            int grow = rowBase + row;
            if (grow < rowsE) *(uint4*)&outw[(size_t)grow * 64 + cp] = v;
        }
        return;
    }

    int bidx = (int)blockIdx.x - rtE;
    const int y = bidx / rtN;
    const int rowBase = (bidx % rtN) << 6;
    const unsigned* Wp = Wp4 + y * 8192;
    #pragma unroll
    for (int i = 0; i < 8; ++i)
        *(uint4*)&Bt[(i * 256 + t) * 4] = *(const uint4*)&Wp[(i * 256 + t) * 4];
    int arow = rowBase + wid * 16 + (lane & 15);
    if (arow > rowsN - 1) arow = rowsN - 1;
    short8 a[4];
    #pragma unroll
    for (int kc = 0; kc < 4; ++kc)
        a[kc] = *(const short8*)(xb + (size_t)arow * DD + kc * 32 + kqo);
    __syncthreads();
    f32x4 acc[8];
    #pragma unroll
    for (int i = 0; i < 8; ++i) acc[i] = (f32x4){0.f, 0.f, 0.f, 0.f};
    #pragma unroll
    for (int ng = 0; ng < 8; ++ng) {
        int col = ng * 16 + (lane & 15);
        #pragma unroll
        for (int kc = 0; kc < 4; ++kc) {
            int kidx = kc * 16 + (lane >> 4) * 4;
            const short8 b = *(const short8*)((const char*)Bt +
                    ((((col << 6) + kidx) ^ ((col & 7) << 2)) << 2));
            acc[ng] = __builtin_amdgcn_mfma_f32_16x16x32_bf16(a[kc], b, acc[ng], 0, 0, 0);
        }
    }
    const float* bs = bias.b[y];
    if (y == 3) {
        #pragma unroll
        for (int ng = 0; ng < 8; ++ng) {
            int col = ng * 16 + (lane & 15);
            float bv = bs[col];
            #pragma unroll
            for (int r = 0; r < 4; ++r) {
                int grow = rowBase + wid * 16 + (lane >> 4) * 4 + r;
                if (grow < rowsN) rbuf[(size_t)grow * DD + col] = acc[ng][r] + bv;
            }
        }
        return;
    }
    __syncthreads();
    unsigned short* sb16 = (unsigned short*)Bt;
    #pragma unroll
    for (int ng = 0; ng < 8; ++ng) {
        int col = ng * 16 + (lane & 15);
        float bv = bs[col];
        int cp = col >> 1, cb = col & 1;
        #pragma unroll
        for (int r = 0; r < 4; ++r) {
            int row = wid * 16 + (lane >> 4) * 4 + r;
            sb16[((row << 6) + (cp ^ ((row & 7) << 2))) * 2 + cb] = f2b(acc[ng][r] + bv);
        }
    }
    __syncthreads();
    unsigned* outw = (unsigned*)qkv;
    #pragma unroll
    for (int i = 0; i < 4; ++i) {
        int j = i * 1024 + t * 4;
        int row = j >> 6, cp = j & 63;
        uint4 v = *(const uint4*)&Bt[(row << 6) + (cp ^ ((row & 7) << 2))];
        int grow = rowBase + row;
        if (grow < rowsN) *(uint4*)&outw[(size_t)grow * 192 + (y << 6) + cp] = v;
    }
}

// ---------- fused agg: 4 waves per node (quarter edges each) + beta gate + LN1 ----------
__global__ __launch_bounds__(256) void aggc_kernel(
        const unsigned* __restrict__ qkv, const unsigned* __restrict__ ee,
        const int* __restrict__ ptr, const int* __restrict__ cs_src,
        const float* __restrict__ r, const float* __restrict__ Wb,
        const float* __restrict__ g1, const float* __restrict__ b1,
        float* __restrict__ x, unsigned* __restrict__ xbw, int N) {
    const int wave = threadIdx.x >> 6;
    const int lane = threadIdx.x & 63;
    const int node = blockIdx.x;
    __shared__ float sS[4];
    __shared__ float sA0[4][64];
    __shared__ float sA1[4][64];

    unsigned qp = qkv[(size_t)node * 192 + lane];
    float q0 = b2f((unsigned short)qp), q1 = b2f((unsigned short)(qp >> 16));
    int beg = ptr[node], end = ptr[node + 1];
    float s = 0.f, a0 = 0.f, a1 = 0.f;
    int idx = beg + wave;
    unsigned epN = 0, kpN = 0, vpN = 0;
    if (idx < end) {
        int j = cs_src[idx];
        epN = __builtin_nontemporal_load(&ee[(size_t)idx * 64 + lane]);
        kpN = qkv[(size_t)j * 192 + 64 + lane];
        vpN = qkv[(size_t)j * 192 + 128 + lane];
    }
    for (; idx < end; idx += 4) {
        unsigned ep = epN, kp = kpN, vp = vpN;
        int nidx = idx + 4;
        if (nidx < end) {
            int jn = cs_src[nidx];
            epN = __builtin_nontemporal_load(&ee[(size_t)nidx * 64 + lane]);
            kpN = qkv[(size_t)jn * 192 + 64 + lane];
            vpN = qkv[(size_t)jn * 192 + 128 + lane];
        }
        float e0 = b2f((unsigned short)ep), e1 = b2f((unsigned short)(ep >> 16));
        float kj0 = b2f((unsigned short)kp) + e0;
        float kj1 = b2f((unsigned short)(kp >> 16)) + e1;
        float p = q0 * kj0 + q1 * kj1;
        p += __shfl_xor(p, 1); p += __shfl_xor(p, 2);
        p += __shfl_xor(p, 4); p += __shfl_xor(p, 8);
        float w = __expf(p * 0.17677669529663687f);  // |alpha| << 1: max-shift not needed
        s += w;
        a0 += (b2f((unsigned short)vp) + e0) * w;
        a1 += (b2f((unsigned short)(vp >> 16)) + e1) * w;
    }
    sS[wave] = s;
    sA0[wave][lane] = a0;
    sA1[wave][lane] = a1;
    __syncthreads();
    if (wave != 0) return;
    s  = sS[0] + sS[1] + sS[2] + sS[3];
    a0 = sA0[0][lane] + sA0[1][lane] + sA0[2][lane] + sA0[3][lane];
    a1 = sA1[0][lane] + sA1[1][lane] + sA1[2][lane] + sA1[3][lane];

    float inv_s = (s > 0.f) ? 1.f / s : 0.f;
    float od0 = a0 * inv_s, od1 = a1 * inv_s;
    float2 rd = *(const float2*)&r[(size_t)node * DD + lane * 2];
    float2 wb0 = *(const float2*)&Wb[lane * 2];
    float2 wb1 = *(const float2*)&Wb[DD + lane * 2];
    float2 wb2 = *(const float2*)&Wb[2 * DD + lane * 2];
    float part = od0 * wb0.x + rd.x * wb1.x + (od0 - rd.x) * wb2.x
               + od1 * wb0.y + rd.y * wb1.y + (od1 - rd.y) * wb2.y;
    #pragma unroll
    for (int m = 1; m < 64; m <<= 1) part += __shfl_xor(part, m);
    float beta = 1.f / (1.f + __expf(-part));
    float2 xo = *(const float2*)&x[(size_t)node * DD + lane * 2];
    float t0 = beta * rd.x + (1.f - beta) * od0 + xo.x;
    float t1 = beta * rd.y + (1.f - beta) * od1 + xo.y;
    float ss = t0 + t1, ss2 = t0 * t0 + t1 * t1;
    #pragma unroll
    for (int m = 1; m < 64; m <<= 1) { ss += __shfl_xor(ss, m); ss2 += __shfl_xor(ss2, m); }
    float mean = ss * (1.f / DD);
    float var = ss2 * (1.f / DD) - mean * mean;
    float inv = rsqrtf(var + 1e-5f);
    float2 gg = *(const float2*)&g1[lane * 2];
    float2 bbv = *(const float2*)&b1[lane * 2];
    float2 res;
    res.x = (t0 - mean) * inv * gg.x + bbv.x;
    res.y = (t1 - mean) * inv * gg.y + bbv.y;
    *(float2*)&x[(size_t)node * DD + lane * 2] = res;
    xbw[(size_t)node * 64 + lane] = packbf(res.x, res.y);
}

// ---------- fused FFN: packed weights; h1 in LDS; x,xb = LN(...) ----------
__global__ __launch_bounds__(256) void ffn_fused(
        const unsigned short* __restrict__ xbin, const unsigned* __restrict__ Wp1,
        const float* __restrict__ b1f, const unsigned* __restrict__ Wp2,
        const float* __restrict__ b2f, const float* __restrict__ g,
        const float* __restrict__ bbn, float* __restrict__ x,
        unsigned short* __restrict__ xb, int rows) {
    __shared__ unsigned Bt[8192];
    __shared__ unsigned h1t[8192];  // 64 x 256 bf16 tile
    const int t = threadIdx.x;
    const int rowBase = blockIdx.x << 6;
    const int lane = t & 63, wid = t >> 6;
    const int kqo = (lane >> 4) * 8;
    int arow = rowBase + wid * 16 + (lane & 15);
    if (arow > rows - 1) arow = rows - 1;

    short8 a[4];
    #pragma unroll
    for (int kc = 0; kc < 4; ++kc)
        a[kc] = *(const short8*)(xbin + (size_t)arow * DD + kc * 32 + kqo);

    unsigned short* h16 = (unsigned short*)h1t;
    for (int half = 0; half < 2; ++half) {
        if (half) __syncthreads();
        const unsigned* Wp = Wp1 + half * 8192;
        #pragma unroll
        for (int i = 0; i < 8; ++i)
            *(uint4*)&Bt[(i * 256 + t) * 4] = *(const uint4*)&Wp[(i * 256 + t) * 4];
        __syncthreads();
        f32x4 acc[8];
        #pragma unroll
        for (int i = 0; i < 8; ++i) acc[i] = (f32x4){0.f, 0.f, 0.f, 0.f};
        #pragma unroll
        for (int ng = 0; ng < 8; ++ng) {
            int col = ng * 16 + (lane & 15);
            #pragma unroll
            for (int kc = 0; kc < 4; ++kc) {
                int kidx = kc * 16 + (lane >> 4) * 4;
                const short8 b = *(const short8*)((const char*)Bt +
                        ((((col << 6) + kidx) ^ ((col & 7) << 2)) << 2));
                acc[ng] = __builtin_amdgcn_mfma_f32_16x16x32_bf16(a[kc], b, acc[ng], 0, 0, 0);
            }
        }
        #pragma unroll
        for (int ng = 0; ng < 8; ++ng) {
            int col = half * 128 + ng * 16 + (lane & 15);
            float bv = b1f[col];
            int cp = col >> 1, cb = col & 1;
            #pragma unroll
            for (int r = 0; r < 4; ++r) {
                int row = wid * 16 + (lane >> 4) * 4 + r;
                float val = acc[ng][r] + bv;
                val = 0.5f * val * (1.f + erff(val * 0.70710678118654752f));
                h16[((row << 7) + (cp ^ ((row & 7) << 2))) * 2 + cb] = f2b(val);
            }
        }
    }
    f32x4 accF[8];
    #pragma unroll
    for (int i = 0; i < 8; ++i) accF[i] = (f32x4){0.f, 0.f, 0.f, 0.f};
    const int lrow = wid * 16 + (lane & 15);
    for (int c = 0; c < 2; ++c) {
        __syncthreads();
        const unsigned* Wp = Wp2 + c * 8192;
        #pragma unroll
        for (int i = 0; i < 8; ++i)
            *(uint4*)&Bt[(i * 256 + t) * 4] = *(const uint4*)&Wp[(i * 256 + t) * 4];
        __syncthreads();
        short8 ah[4];
        #pragma unroll
        for (int kc = 0; kc < 4; ++kc) {
            int cp4 = c * 64 + kc * 16 + (lane >> 4) * 4;
            ah[kc] = *(const short8*)&h1t[(lrow << 7) + (cp4 ^ ((lrow & 7) << 2))];
        }
        #pragma unroll
        for (int ng = 0; ng < 8; ++ng) {
            int col = ng * 16 + (lane & 15);
            #pragma unroll
            for (int kc = 0; kc < 4; ++kc) {
                int kidx = kc * 16 + (lane >> 4) * 4;
                const short8 b = *(const short8*)((const char*)Bt +
                        ((((col << 6) + kidx) ^ ((col & 7) << 2)) << 2));
                accF[ng] = __builtin_amdgcn_mfma_f32_16x16x32_bf16(ah[kc], b, accF[ng], 0, 0, 0);
            }
        }
    }
    float tt[8][4];
    float rs[4] = {0.f, 0.f, 0.f, 0.f}, rs2[4] = {0.f, 0.f, 0.f, 0.f};
    #pragma unroll
    for (int ng = 0; ng < 8; ++ng) {
        int col = ng * 16 + (lane & 15);
        float bv = b2f[col];
        #pragma unroll
        for (int r = 0; r < 4; ++r) {
            int grow = rowBase + wid * 16 + (lane >> 4) * 4 + r;
            float xo = (grow < rows) ? x[(size_t)grow * DD + col] : 0.f;
            float v = accF[ng][r] + bv + xo;
            tt[ng][r] = v;
            rs[r] += v;
            rs2[r] += v * v;
        }
    }
    #pragma unroll
    for (int r = 0; r < 4; ++r) {
        #pragma unroll
        for (int m = 1; m < 16; m <<= 1) {
            rs[r] += __shfl_xor(rs[r], m);
            rs2[r] += __shfl_xor(rs2[r], m);
        }
    }
    __syncthreads();
    unsigned short* sb16 = (unsigned short*)Bt;
    #pragma unroll
    for (int ng = 0; ng < 8; ++ng) {
        int col = ng * 16 + (lane & 15);
        float gg = g[col], bbb = bbn[col];
        int cp = col >> 1, cb = col & 1;
        #pragma unroll
        for (int r = 0; r < 4; ++r) {
            int grow = rowBase + wid * 16 + (lane >> 4) * 4 + r;
            float mean = rs[r] * (1.f / DD);
            float var = rs2[r] * (1.f / DD) - mean * mean;
            float val = (tt[ng][r] - mean) * rsqrtf(var + 1e-5f) * gg + bbb;
            if (grow < rows) x[(size_t)grow * DD + col] = val;
            int row = wid * 16 + (lane >> 4) * 4 + r;
            sb16[((row << 6) + (cp ^ ((row & 7) << 2))) * 2 + cb] = f2b(val);
        }
    }
    __syncthreads();
    unsigned* outw = (unsigned*)xb;
    #pragma unroll
    for (int i = 0; i < 4; ++i) {
        int j = i * 1024 + t * 4;
        int row = j >> 6, cp = j & 63;
        uint4 v = *(const uint4*)&Bt[(row << 6) + (cp ^ ((row & 7) << 2))];
        int grow = rowBase + row;
        if (grow < rows) *(uint4*)&outw[(size_t)grow * 64 + cp] = v;
    }
}

// ---------- fused heads: MFMA hidden tile + in-block finish ----------
__global__ __launch_bounds__(256) void heads_fused(
        const unsigned short* __restrict__ xb, const unsigned* __restrict__ Whp,
        const float* __restrict__ b1cat, const float* __restrict__ cW2,
        const float* __restrict__ cb2, const float* __restrict__ bW2,
        const float* __restrict__ bb2, float* __restrict__ outc,
        float* __restrict__ outb, int rows) {
    __shared__ unsigned Bt[8192];
    __shared__ unsigned ht[4096];  // 64 rows x 64 u32 (128 bf16)
    const int t = threadIdx.x;
    const int rowBase = blockIdx.x << 6;
    const int lane = t & 63, wid = t >> 6;
    const int kqo = (lane >> 4) * 8;
    #pragma unroll
    for (int i = 0; i < 8; ++i)
        *(uint4*)&Bt[(i * 256 + t) * 4] = *(const uint4*)&Whp[(i * 256 + t) * 4];
    int arow = rowBase + wid * 16 + (lane & 15);
    if (arow > rows - 1) arow = rows - 1;
    short8 a[4];
    #pragma unroll
    for (int kc = 0; kc < 4; ++kc)
        a[kc] = *(const short8*)(xb + (size_t)arow * DD + kc * 32 + kqo);
    __syncthreads();
    f32x4 acc[8];
    #pragma unroll
    for (int i = 0; i < 8; ++i) acc[i] = (f32x4){0.f, 0.f, 0.f, 0.f};
    #pragma unroll
    for (int ng = 0; ng < 8; ++ng) {
        int col = ng * 16 + (lane & 15);
        #pragma unroll
        for (int kc = 0; kc < 4; ++kc) {
            int kidx = kc * 16 + (lane >> 4) * 4;
            const short8 b = *(const short8*)((const char*)Bt +
                    ((((col << 6) + kidx) ^ ((col & 7) << 2)) << 2));
            acc[ng] = __builtin_amdgcn_mfma_f32_16x16x32_bf16(a[kc], b, acc[ng], 0, 0, 0);
        }
    }
    unsigned short* h16 = (unsigned short*)ht;
    #pragma unroll
    for (int ng = 0; ng < 8; ++ng) {
        int col = ng * 16 + (lane & 15);
        float bv = b1cat[col];
        int cp = col >> 1, cb = col & 1;
        #pragma unroll
        for (int r = 0; r < 4; ++r) {
            int row = wid * 16 + (lane >> 4) * 4 + r;
            h16[((row << 6) + (cp ^ ((row & 7) << 2))) * 2 + cb] = f2b(fmaxf(acc[ng][r] + bv, 0.f));
        }
    }
    __syncthreads();
    for (int i = t; i < 704; i += 256) {
        int n = i / 11, j = i % 11;
        int grow = rowBase + n;
        if (grow >= rows) continue;
        int sw = (n & 7) << 2;
        if (j < 4) {
            float accv = cb2[j];
            #pragma unroll 8
            for (int kp = 0; kp < 32; ++kp) {
                unsigned w = ht[(n << 6) + (kp ^ sw)];
                accv += b2f((unsigned short)w) * cW2[(2 * kp) * 4 + j];
                accv += b2f((unsigned short)(w >> 16)) * cW2[(2 * kp + 1) * 4 + j];
            }
            outc[(size_t)grow * 4 + j] = accv;
        } else {
            int jj = j - 4;
            float accv = bb2[jj];
            #pragma unroll 8
            for (int kp = 0; kp < 32; ++kp) {
                unsigned w = ht[(n << 6) + ((32 + kp) ^ sw)];
                accv += b2f((unsigned short)w) * bW2[(2 * kp) * 7 + jj];
                accv += b2f((unsigned short)(w >> 16)) * bW2[(2 * kp + 1) * 7 + jj];
            }
            outb[(size_t)grow * 7 + jj] = accv;
        }
    }
}

extern "C" void kernel_launch(void* const* d_in, const int* in_sizes, int n_in,
                              void* d_out, int out_size, void* d_ws, size_t ws_size,
                              hipStream_t stream) {
    const float* xyz   = (const float*)d_in[0];
    const float* attr  = (const float*)d_in[1];
    const int*   ei    = (const int*)d_in[2];
    const float* encW  = (const float*)d_in[3];
    const float* encb  = (const float*)d_in[4];
    const float* encg  = (const float*)d_in[5];
    const float* encbb = (const float*)d_in[6];
    const float* posW1 = (const float*)d_in[7];
    const float* posb1 = (const float*)d_in[8];
    const float* posg  = (const float*)d_in[9];
    const float* posbb = (const float*)d_in[10];
    const float* posW2 = (const float*)d_in[11];
    const float* posb2 = (const float*)d_in[12];
    const float* Wq    = (const float*)d_in[13];
    const float* bq    = (const float*)d_in[14];
    const float* Wk    = (const float*)d_in[15];
    const float* bk    = (const float*)d_in[16];
    const float* Wv    = (const float*)d_in[17];
    const float* bv    = (const float*)d_in[18];
    const float* We    = (const float*)d_in[19];
    const float* Wskip = (const float*)d_in[20];
    const float* bskip = (const float*)d_in[21];
    const float* Wbeta = (const float*)d_in[22];
    const float* ln1g  = (const float*)d_in[23];
    const float* ln1b  = (const float*)d_in[24];
    const float* ln2g  = (const float*)d_in[25];
    const float* ln2b  = (const float*)d_in[26];
    const float* fW1   = (const float*)d_in[27];
    const float* fb1   = (const float*)d_in[28];
    const float* fW2   = (const float*)d_in[29];
    const float* fb2   = (const float*)d_in[30];
    const float* cW1   = (const float*)d_in[31];
    const float* cb1   = (const float*)d_in[32];
    const float* cW2   = (const float*)d_in[33];
    const float* cb2   = (const float*)d_in[34];
    const float* bW1   = (const float*)d_in[35];
    const float* bb1   = (const float*)d_in[36];
    const float* bW2   = (const float*)d_in[37];
    const float* bb2   = (const float*)d_in[38];

    const int N = in_sizes[0] / 3;
    const int E = in_sizes[2] / 2;

    size_t off = 0;
    auto alloc = [&](size_t nelem) {
        char* p = (char*)d_ws + off;
        off += nelem * sizeof(float);
        return (float*)p;
    };
    float* x     = alloc((size_t)N * DD);
    unsigned short* qkv = (unsigned short*)alloc((size_t)N * 192);   // N*384 bf16 [q|k|v]
    float* r     = alloc((size_t)N * DD);
    unsigned short* xb = (unsigned short*)alloc((size_t)N * 64);     // N*128 bf16
    float4* rel4 = (float4*)alloc((size_t)E * 4);                    // CSR-order rel + inv
    unsigned short* eeb = (unsigned short*)alloc((size_t)E * 64);    // E*128 bf16 (CSR order)
    unsigned* W2Wep = (unsigned*)alloc(3 * 8192);                    // folded edge weights packed
    float* b2We  = alloc(3 * DD);
    unsigned* Wpall = (unsigned*)alloc(24 * 8192);                   // qkvr(12) + fW1(6) + fW2(6)
    unsigned* Whp   = (unsigned*)alloc(8192);                        // heads W1cat packed
    float* pw    = alloc(544);
    float* b1cat = alloc(DD);
    int* deg     = (int*)alloc(N);
    int* cur     = (int*)alloc(N);   // adjacent to deg: one memset covers both
    int* ptr     = (int*)alloc(N + 1);
    int* cs_src  = (int*)alloc(E);

    const int rtN = (N + 63) / 64;
    const int rtE = (E + 63) / 64;
    const int encBlocks = (N + 1) / 2;
    const int SC = (E + 255) / 256;

    // ---- preamble: 4 dispatches ----
    hipMemsetAsync(deg, 0, 2 * (size_t)N * sizeof(int), stream);
    setup1_kernel<<<encBlocks + 1 + SC, 256, 0, stream>>>(
        xyz, attr, encW, encb, encg, encbb, x, xb,
        posW1, posb1, posg, pw, ei, deg, N, E, encBlocks);
    scan_kernel<<<1, 1024, 0, stream>>>(deg, ptr, N);
    setup2_kernel<<<SC + 99 + 768 + 32 + 1, 256, 0, stream>>>(
        ei, xyz, pw, ptr, cur, cs_src, rel4, E,
        posW2, posb2, We, W2Wep, b2We,
        Wq, Wk, Wv, Wskip, fW1, fW2, Wpall,
        cW1, bW1, Whp, cb1, bb1, b1cat, SC);

    for (int l = 0; l < 3; ++l) {
        const float* Wb_l = Wbeta + (size_t)l * 3 * DD;
        B4 bs;
        bs.b[0] = bq + l * DD; bs.b[1] = bk + l * DD;
        bs.b[2] = bv + l * DD; bs.b[3] = bskip + l * DD;

        proj_kernel<<<rtE + 4 * rtN, 256, 0, stream>>>(
            xb, Wpall + (size_t)l * 4 * 8192, bs, qkv, r, N, rtN,
            rel4, pw, posbb, W2Wep + l * 8192, b2We + l * DD, eeb, E, rtE);

        aggc_kernel<<<N, 256, 0, stream>>>((const unsigned*)qkv, (const unsigned*)eeb,
                                           ptr, cs_src, r, Wb_l,
                                           ln1g + l * DD, ln1b + l * DD,
                                           x, (unsigned*)xb, N);

        ffn_fused<<<rtN, 256, 0, stream>>>(xb, Wpall + (size_t)(12 + 2 * l) * 8192,
                                           fb1 + l * 256, Wpall + (size_t)(18 + 2 * l) * 8192,
                                           fb2 + l * DD, ln2g + l * DD, ln2b + l * DD,
                                           x, xb, N);
    }

    // ---- heads (single fused dispatch) ----
    float* outc  = (float*)d_out;
    float* outbx = (float*)d_out + (size_t)N * 4;
    heads_fused<<<rtN, 256, 0, stream>>>(xb, Whp, b1cat, cW2, cb2, bW2, bb2,
                                         outc, outbx, N);
}

// Round 16
// 364.299 us; speedup vs baseline: 1.2128x; 1.0203x over previous
//
#include <hip/hip_runtime.h>
#include <hip/hip_bf16.h>
#include <math.h>

#define DD 128

typedef __attribute__((ext_vector_type(8))) short short8;
typedef __attribute__((ext_vector_type(4))) float f32x4;

// ---------- helpers ----------

__device__ __forceinline__ unsigned short f2b(float f) {
    unsigned u = __float_as_uint(f);
    return (unsigned short)((u + 0x7FFFu + ((u >> 16) & 1u)) >> 16);
}
__device__ __forceinline__ float b2f(unsigned short b) {
    return __uint_as_float(((unsigned)b) << 16);
}
__device__ __forceinline__ unsigned packbf(float a, float b) {
    return (unsigned)f2b(a) | ((unsigned)f2b(b) << 16);
}

// block = 256 thr, two independent 128-thread halves; returns per-half sums
__device__ __forceinline__ void redsum2_half(float& a, float& b) {
    #pragma unroll
    for (int off = 32; off > 0; off >>= 1) {
        a += __shfl_down(a, off);
        b += __shfl_down(b, off);
    }
    __shared__ float sa[4], sb4[4];
    int w = threadIdx.x >> 6;
    if ((threadIdx.x & 63) == 0) { sa[w] = a; sb4[w] = b; }
    __syncthreads();
    int h = threadIdx.x >> 7;
    a = sa[2 * h] + sa[2 * h + 1];
    b = sb4[2 * h] + sb4[2 * h + 1];
    __syncthreads();
}

// ---------- setup1: enc (2 nodes/block) | posprep | hist ----------
__global__ __launch_bounds__(256) void setup1_kernel(
        const float* __restrict__ xyz, const float* __restrict__ attr,
        const float* __restrict__ encW, const float* __restrict__ encb,
        const float* __restrict__ encg, const float* __restrict__ encbb,
        float* __restrict__ x, unsigned short* __restrict__ xbuf,
        const float* __restrict__ posW1, const float* __restrict__ posb1,
        const float* __restrict__ posg, float* __restrict__ pw,
        const int* __restrict__ ei, int* __restrict__ deg,
        int N, int E, int encBlocks) {
    const int b = blockIdx.x, t = threadIdx.x;
    if (b < encBlocks) {
        const int h = t >> 7, d = t & 127;
        const int node = b * 2 + h;
        const bool ok = node < N;
        __shared__ float sin4[2][4];
        if (ok && d < 3) sin4[h][d] = xyz[node * 3 + d];
        if (ok && d == 3) sin4[h][3] = attr[node];
        __syncthreads();
        float y = encb[d];
        if (ok) {
            #pragma unroll
            for (int kk = 0; kk < 4; ++kk) y += sin4[h][kk] * encW[kk * DD + d];
        }
        float s = y, s2 = y * y;
        redsum2_half(s, s2);
        if (ok) {
            float mean = s * (1.0f / DD);
            float var = s2 * (1.0f / DD) - mean * mean;
            float xn = fmaxf((y - mean) * rsqrtf(var + 1e-5f) * encg[d] + encbb[d], 0.f);
            x[(size_t)node * DD + d] = xn;
            xbuf[(size_t)node * DD + d] = f2b(xn);
        }
    } else if (b == encBlocks) {
        const int d = t & 127;
        float w0 = posW1[d], w1 = posW1[DD + d], w2 = posW1[2 * DD + d], bb = posb1[d];
        float s0 = w0, s1 = w1;
        redsum2_half(s0, s1);
        float s2 = w2, s3 = bb;
        redsum2_half(s2, s3);
        float c0 = w0 - s0 * (1.f / DD), c1 = w1 - s1 * (1.f / DD);
        float c2 = w2 - s2 * (1.f / DD), bc = bb - s3 * (1.f / DD);
        float gd = posg[d];
        pw[d] = c0 * gd; pw[DD + d] = c1 * gd; pw[2 * DD + d] = c2 * gd; pw[3 * DD + d] = bc * gd;
        float p0 = c0 * c0, p1 = c0 * c1; redsum2_half(p0, p1);
        float p2 = c0 * c2, p3 = c1 * c1; redsum2_half(p2, p3);
        float p4 = c1 * c2, p5 = c2 * c2; redsum2_half(p4, p5);
        float p6 = c0 * bc, p7 = c1 * bc; redsum2_half(p6, p7);
        float p8 = c2 * bc, p9 = bc * bc; redsum2_half(p8, p9);
        if ((t & 127) == 0) {
            pw[512] = p0 * (1.f / DD); pw[513] = p1 * (1.f / DD); pw[514] = p2 * (1.f / DD);
            pw[515] = p3 * (1.f / DD); pw[516] = p4 * (1.f / DD); pw[517] = p5 * (1.f / DD);
            pw[518] = p6 * (1.f / DD); pw[519] = p7 * (1.f / DD); pw[520] = p8 * (1.f / DD);
            pw[521] = p9 * (1.f / DD);
        }
    } else {
        int e = (b - encBlocks - 1) * 256 + t;
        if (e < E) atomicAdd(&deg[ei[E + e]], 1);
    }
}

// ---------- scan ----------
__global__ void scan_kernel(const int* __restrict__ deg, int* __restrict__ ptr, int n) {
    __shared__ int partial[1024];
    int t = threadIdx.x;
    int CH = (n + 1023) >> 10;
    int beg = t * CH;
    int end = beg + CH; if (end > n) end = n;
    int s = 0;
    for (int i = beg; i < end; ++i) s += deg[i];
    partial[t] = s;
    __syncthreads();
    for (int off = 1; off < 1024; off <<= 1) {
        int add = (t >= off) ? partial[t - off] : 0;
        __syncthreads();
        partial[t] += add;
        __syncthreads();
    }
    int base = (t == 0) ? 0 : partial[t - 1];
    for (int i = beg; i < end; ++i) {
        ptr[i] = base;
        base += deg[i];
    }
    if (end == n && beg < n) ptr[n] = base;
}

// ---------- setup2: scatter | wcombp | pack(qkvr+ffn) | headpack | b1cat ----------
__global__ __launch_bounds__(256) void setup2_kernel(
        const int* __restrict__ ei, const float* __restrict__ xyz,
        const float* __restrict__ pw, const int* __restrict__ ptr,
        int* __restrict__ cur, int* __restrict__ cs_src, float4* __restrict__ rel4, int E,
        const float* __restrict__ W2, const float* __restrict__ b2,
        const float* __restrict__ We, unsigned* __restrict__ W2Wep, float* __restrict__ b2We,
        const float* __restrict__ Wq, const float* __restrict__ Wk,
        const float* __restrict__ Wv, const float* __restrict__ Ws,
        const float* __restrict__ fW1, const float* __restrict__ fW2,
        unsigned* __restrict__ Wpall,
        const float* __restrict__ cW1, const float* __restrict__ bW1,
        unsigned* __restrict__ Whp,
        const float* __restrict__ cb1, const float* __restrict__ bb1,
        float* __restrict__ b1cat, int SC) {
    const int b = blockIdx.x, t = threadIdx.x;
    if (b < SC) {
        int e = b * 256 + t;
        if (e >= E) return;
        int srcn = ei[e], dstn = ei[E + e];
        int p = atomicAdd(&cur[dstn], 1);
        int slot = ptr[dstn] + p;
        cs_src[slot] = srcn;
        float r0 = xyz[dstn * 3]     - xyz[srcn * 3];
        float r1 = xyz[dstn * 3 + 1] - xyz[srcn * 3 + 1];
        float r2 = xyz[dstn * 3 + 2] - xyz[srcn * 3 + 2];
        float var = pw[512] * r0 * r0 + pw[515] * r1 * r1 + pw[517] * r2 * r2
                  + 2.f * (pw[513] * r0 * r1 + pw[514] * r0 * r2 + pw[516] * r1 * r2)
                  + 2.f * (pw[518] * r0 + pw[519] * r1 + pw[520] * r2) + pw[521];
        rel4[slot] = make_float4(r0, r1, r2, rsqrtf(var + 1e-5f));
        return;
    }
    if (b < SC + 99) {
        int z = b - SC;
        int y = z / 33, bp = z % 33;
        int sub = t >> 7, d = t & 127;
        int bid = bp * 2 + sub;
        const float* We_l = We + (size_t)y * DD * DD;
        __shared__ float s0[2][DD], s1[2][DD];
        if (bid < 64)       { s0[sub][d] = W2[(2 * bid) * DD + d]; s1[sub][d] = W2[(2 * bid + 1) * DD + d]; }
        else if (bid == 64) { s0[sub][d] = b2[d]; s1[sub][d] = 0.f; }
        __syncthreads();
        if (bid <= 64) {
            float a0 = 0.f, a1 = 0.f;
            #pragma unroll 8
            for (int kk = 0; kk < DD; ++kk) {
                float w = We_l[kk * DD + d];
                a0 += s0[sub][kk] * w;
                a1 += s1[sub][kk] * w;
            }
            if (bid < 64) W2Wep[y * 8192 + (((d << 6) + bid) ^ ((d & 7) << 2))] = packbf(a0, a1);
            else          b2We[y * DD + d] = a0;
        }
        return;
    }
    if (b < SC + 99 + 768) {
        int z = b - SC - 99;
        int blob = z >> 5, bp = z & 31;
        int kp = bp * 2 + (t >> 7), d = t & 127;
        float w0, w1;
        if (blob < 12) {
            int l = blob >> 2, wt = blob & 3;
            const float* W = (wt == 0 ? Wq : wt == 1 ? Wk : wt == 2 ? Wv : Ws) + (size_t)l * DD * DD;
            w0 = W[(size_t)(2 * kp) * DD + d];
            w1 = W[(size_t)(2 * kp + 1) * DD + d];
        } else if (blob < 18) {
            int i = blob - 12, l = i >> 1, hf = i & 1;
            const float* W = fW1 + (size_t)l * DD * 256;
            w0 = W[(size_t)(2 * kp) * 256 + hf * 128 + d];
            w1 = W[(size_t)(2 * kp + 1) * 256 + hf * 128 + d];
        } else {
            int i = blob - 18, l = i >> 1, c = i & 1;
            const float* W = fW2 + (size_t)l * 256 * DD;
            w0 = W[(size_t)(c * 128 + 2 * kp) * DD + d];
            w1 = W[(size_t)(c * 128 + 2 * kp + 1) * DD + d];
        }
        Wpall[blob * 8192 + (((d << 6) + kp) ^ ((d & 7) << 2))] = packbf(w0, w1);
        return;
    }
    if (b < SC + 99 + 768 + 32) {
        int bp = b - (SC + 99 + 768);
        int kp = bp * 2 + (t >> 7), d = t & 127;
        int k0 = 2 * kp, k1 = 2 * kp + 1;
        float w0 = (d < 64) ? cW1[k0 * 64 + d] : bW1[k0 * 64 + (d - 64)];
        float w1 = (d < 64) ? cW1[k1 * 64 + d] : bW1[k1 * 64 + (d - 64)];
        Whp[((d << 6) + kp) ^ ((d & 7) << 2)] = packbf(w0, w1);
        return;
    }
    if (t < 128) b1cat[t] = (t < 64) ? cb1[t] : bb1[t - 64];
}

// ---------- merged projection kernel: ee GEMM (on-the-fly A) + q/k/v/skip GEMMs ----------
struct B4 { const float* b[4]; };

__global__ __launch_bounds__(256) void proj_kernel(
        const unsigned short* __restrict__ xb, const unsigned* __restrict__ Wp4, B4 bias,
        unsigned short* __restrict__ qkv, float* __restrict__ rbuf, int rowsN, int rtN,
        const float4* __restrict__ rel4, const float* __restrict__ pw,
        const float* __restrict__ bbp, const unsigned* __restrict__ Wpee,
        const float* __restrict__ biasee, unsigned short* __restrict__ eeout,
        int rowsE, int rtE) {
    __shared__ unsigned Bt[8192];
    __shared__ float sc[640];
    const int t = threadIdx.x;
    const int lane = t & 63, wid = t >> 6;
    const int kqo = (lane >> 4) * 8;

    if ((int)blockIdx.x < rtE) {
        const int rowBase = (int)blockIdx.x << 6;
        #pragma unroll
        for (int i = 0; i < 8; ++i)
            *(uint4*)&Bt[(i * 256 + t) * 4] = *(const uint4*)&Wpee[(i * 256 + t) * 4];
        for (int i = t; i < 640; i += 256)
            sc[i] = (i < 512) ? pw[i] : bbp[i - 512];
        int arow = rowBase + wid * 16 + (lane & 15);
        if (arow > rowsE - 1) arow = rowsE - 1;
        float4 rv = rel4[arow];
        __syncthreads();
        short8 a[4];
        #pragma unroll
        for (int kc = 0; kc < 4; ++kc) {
            union { short8 s; unsigned short u[8]; } cv;
            #pragma unroll
            for (int j = 0; j < 8; ++j) {
                int d = kc * 32 + kqo + j;
                float y = fmaf(rv.x, sc[d], fmaf(rv.y, sc[128 + d], fmaf(rv.z, sc[256 + d], sc[384 + d])));
                cv.u[j] = f2b(fmaxf(fmaf(y, rv.w, sc[512 + d]), 0.f));
            }
            a[kc] = cv.s;
        }
        f32x4 acc[8];
        #pragma unroll
        for (int i = 0; i < 8; ++i) acc[i] = (f32x4){0.f, 0.f, 0.f, 0.f};
        #pragma unroll
        for (int ng = 0; ng < 8; ++ng) {
            int col = ng * 16 + (lane & 15);
            #pragma unroll
            for (int kc = 0; kc < 4; ++kc) {
                int kidx = kc * 16 + (lane >> 4) * 4;
                const short8 b = *(const short8*)((const char*)Bt +
                        ((((col << 6) + kidx) ^ ((col & 7) << 2)) << 2));
                acc[ng] = __builtin_amdgcn_mfma_f32_16x16x32_bf16(a[kc], b, acc[ng], 0, 0, 0);
            }
        }
        __syncthreads();
        unsigned short* sb16 = (unsigned short*)Bt;
        #pragma unroll
        for (int ng = 0; ng < 8; ++ng) {
            int col = ng * 16 + (lane & 15);
            float bv = biasee[col];
            int cp = col >> 1, cb = col & 1;
            #pragma unroll
            for (int r = 0; r < 4; ++r) {
                int row = wid * 16 + (lane >> 4) * 4 + r;
                sb16[((row << 6) + (cp ^ ((row & 7) << 2))) * 2 + cb] = f2b(acc[ng][r] + bv);
            }
        }
        __syncthreads();
        unsigned* outw = (unsigned*)eeout;
        #pragma unroll
        for (int i = 0; i < 4; ++i) {
            int j = i * 1024 + t * 4;
            int row = j >> 6, cp = j & 63;
            uint4 v = *(const uint4*)&Bt[(row << 6) + (cp ^ ((row & 7) << 2))];
            int grow = rowBase + row;
            if (grow < rowsE) *(uint4*)&outw[(size_t)grow * 64 + cp] = v;
        }
        return;
    }

    int bidx = (int)blockIdx.x - rtE;
    const int y = bidx / rtN;
    const int rowBase = (bidx % rtN) << 6;
    const unsigned* Wp = Wp4 + y * 8192;
    #pragma unroll
    for (int i = 0; i < 8; ++i)
        *(uint4*)&Bt[(i * 256 + t) * 4] = *(const uint4*)&Wp[(i * 256 + t) * 4];
    int arow = rowBase + wid * 16 + (lane & 15);
    if (arow > rowsN - 1) arow = rowsN - 1;
    short8 a[4];
    #pragma unroll
    for (int kc = 0; kc < 4; ++kc)
        a[kc] = *(const short8*)(xb + (size_t)arow * DD + kc * 32 + kqo);
    __syncthreads();
    f32x4 acc[8];
    #pragma unroll
    for (int i = 0; i < 8; ++i) acc[i] = (f32x4){0.f, 0.f, 0.f, 0.f};
    #pragma unroll
    for (int ng = 0; ng < 8; ++ng) {
        int col = ng * 16 + (lane & 15);
        #pragma unroll
        for (int kc = 0; kc < 4; ++kc) {
            int kidx = kc * 16 + (lane >> 4) * 4;
            const short8 b = *(const short8*)((const char*)Bt +
                    ((((col << 6) + kidx) ^ ((col & 7) << 2)) << 2));
            acc[ng] = __builtin_amdgcn_mfma_f32_16x16x32_bf16(a[kc], b, acc[ng], 0, 0, 0);
        }
    }
    const float* bs = bias.b[y];
    if (y == 3) {
        #pragma unroll
        for (int ng = 0; ng < 8; ++ng) {
            int col = ng * 16 + (lane & 15);
            float bv = bs[col];
            #pragma unroll
            for (int r = 0; r < 4; ++r) {
                int grow = rowBase + wid * 16 + (lane >> 4) * 4 + r;
                if (grow < rowsN) rbuf[(size_t)grow * DD + col] = acc[ng][r] + bv;
            }
        }
        return;
    }
    __syncthreads();
    unsigned short* sb16 = (unsigned short*)Bt;
    #pragma unroll
    for (int ng = 0; ng < 8; ++ng) {
        int col = ng * 16 + (lane & 15);
        float bv = bs[col];
        int cp = col >> 1, cb = col & 1;
        #pragma unroll
        for (int r = 0; r < 4; ++r) {
            int row = wid * 16 + (lane >> 4) * 4 + r;
            sb16[((row << 6) + (cp ^ ((row & 7) << 2))) * 2 + cb] = f2b(acc[ng][r] + bv);
        }
    }
    __syncthreads();
    unsigned* outw = (unsigned*)qkv;
    #pragma unroll
    for (int i = 0; i < 4; ++i) {
        int j = i * 1024 + t * 4;
        int row = j >> 6, cp = j & 63;
        uint4 v = *(const uint4*)&Bt[(row << 6) + (cp ^ ((row & 7) << 2))];
        int grow = rowBase + row;
        if (grow < rowsN) *(uint4*)&outw[(size_t)grow * 192 + (y << 6) + cp] = v;
    }
}

// ---------- fused agg: 4 waves per node + beta gate + LN1 ----------
__global__ __launch_bounds__(256) void aggc_kernel(
        const unsigned* __restrict__ qkv, const unsigned* __restrict__ ee,
        const int* __restrict__ ptr, const int* __restrict__ cs_src,
        const float* __restrict__ r, const float* __restrict__ Wb,
        const float* __restrict__ g1, const float* __restrict__ b1,
        float* __restrict__ x, unsigned* __restrict__ xbw, int N) {
    const int wave = threadIdx.x >> 6;
    const int lane = threadIdx.x & 63;
    const int node = blockIdx.x;
    __shared__ float sS[4];
    __shared__ float sA0[4][64];
    __shared__ float sA1[4][64];

    unsigned qp = qkv[(size_t)node * 192 + lane];
    float q0 = b2f((unsigned short)qp), q1 = b2f((unsigned short)(qp >> 16));
    int beg = ptr[node], end = ptr[node + 1];
    float s = 0.f, a0 = 0.f, a1 = 0.f;
    int idx = beg + wave;
    unsigned epN = 0, kpN = 0, vpN = 0;
    if (idx < end) {
        int j = cs_src[idx];
        epN = __builtin_nontemporal_load(&ee[(size_t)idx * 64 + lane]);
        kpN = qkv[(size_t)j * 192 + 64 + lane];
        vpN = qkv[(size_t)j * 192 + 128 + lane];
    }
    for (; idx < end; idx += 4) {
        unsigned ep = epN, kp = kpN, vp = vpN;
        int nidx = idx + 4;
        if (nidx < end) {
            int jn = cs_src[nidx];
            epN = __builtin_nontemporal_load(&ee[(size_t)nidx * 64 + lane]);
            kpN = qkv[(size_t)jn * 192 + 64 + lane];
            vpN = qkv[(size_t)jn * 192 + 128 + lane];
        }
        float e0 = b2f((unsigned short)ep), e1 = b2f((unsigned short)(ep >> 16));
        float kj0 = b2f((unsigned short)kp) + e0;
        float kj1 = b2f((unsigned short)(kp >> 16)) + e1;
        float p = q0 * kj0 + q1 * kj1;
        p += __shfl_xor(p, 1); p += __shfl_xor(p, 2);
        p += __shfl_xor(p, 4); p += __shfl_xor(p, 8);
        float w = __expf(p * 0.17677669529663687f);  // |alpha| << 1: max-shift not needed
        s += w;
        a0 += (b2f((unsigned short)vp) + e0) * w;
        a1 += (b2f((unsigned short)(vp >> 16)) + e1) * w;
    }
    sS[wave] = s;
    sA0[wave][lane] = a0;
    sA1[wave][lane] = a1;
    __syncthreads();
    if (wave != 0) return;
    s  = sS[0] + sS[1] + sS[2] + sS[3];
    a0 = sA0[0][lane] + sA0[1][lane] + sA0[2][lane] + sA0[3][lane];
    a1 = sA1[0][lane] + sA1[1][lane] + sA1[2][lane] + sA1[3][lane];

    float inv_s = (s > 0.f) ? 1.f / s : 0.f;
    float od0 = a0 * inv_s, od1 = a1 * inv_s;
    float2 rd = *(const float2*)&r[(size_t)node * DD + lane * 2];
    float2 wb0 = *(const float2*)&Wb[lane * 2];
    float2 wb1 = *(const float2*)&Wb[DD + lane * 2];
    float2 wb2 = *(const float2*)&Wb[2 * DD + lane * 2];
    float part = od0 * wb0.x + rd.x * wb1.x + (od0 - rd.x) * wb2.x
               + od1 * wb0.y + rd.y * wb1.y + (od1 - rd.y) * wb2.y;
    #pragma unroll
    for (int m = 1; m < 64; m <<= 1) part += __shfl_xor(part, m);
    float beta = 1.f / (1.f + __expf(-part));
    float2 xo = *(const float2*)&x[(size_t)node * DD + lane * 2];
    float t0 = beta * rd.x + (1.f - beta) * od0 + xo.x;
    float t1 = beta * rd.y + (1.f - beta) * od1 + xo.y;
    float ss = t0 + t1, ss2 = t0 * t0 + t1 * t1;
    #pragma unroll
    for (int m = 1; m < 64; m <<= 1) { ss += __shfl_xor(ss, m); ss2 += __shfl_xor(ss2, m); }
    float mean = ss * (1.f / DD);
    float var = ss2 * (1.f / DD) - mean * mean;
    float inv = rsqrtf(var + 1e-5f);
    float2 gg = *(const float2*)&g1[lane * 2];
    float2 bbv = *(const float2*)&b1[lane * 2];
    float2 res;
    res.x = (t0 - mean) * inv * gg.x + bbv.x;
    res.y = (t1 - mean) * inv * gg.y + bbv.y;
    *(float2*)&x[(size_t)node * DD + lane * 2] = res;
    xbw[(size_t)node * 64 + lane] = packbf(res.x, res.y);
}

// ---------- fused FFN, 32-row tiles: h1 in LDS; x,xb = LN(...) ----------
// waves {0,1}: rows 0-15; {2,3}: rows 16-31. Wave owns 64-col half (wid&1).
__global__ __launch_bounds__(256) void ffn_fused(
        const unsigned short* __restrict__ xbin, const unsigned* __restrict__ Wp1,
        const float* __restrict__ b1f, const unsigned* __restrict__ Wp2,
        const float* __restrict__ b2f, const float* __restrict__ g,
        const float* __restrict__ bbn, float* __restrict__ x,
        unsigned short* __restrict__ xb, int rows) {
    __shared__ unsigned Bt[8192];   // staged weight blob / final transpose-out
    __shared__ unsigned h1t[4096];  // 32 x 256 bf16 tile
    __shared__ float sRS[4][16], sRS2[4][16];
    const int t = threadIdx.x;
    const int rowBase = blockIdx.x << 5;
    const int lane = t & 63, wid = t >> 6;
    const int wrow = (wid >> 1) * 16;      // 0 or 16
    const int wcol = (wid & 1) * 64;       // 0 or 64
    const int kqo = (lane >> 4) * 8;
    int arow = rowBase + wrow + (lane & 15);
    if (arow > rows - 1) arow = rows - 1;

    short8 a[4];
    #pragma unroll
    for (int kc = 0; kc < 4; ++kc)
        a[kc] = *(const short8*)(xbin + (size_t)arow * DD + kc * 32 + kqo);

    unsigned short* h16 = (unsigned short*)h1t;
    // ---- ffn1: two col-halves (each 128 cols; wave covers 64 of them) ----
    for (int half = 0; half < 2; ++half) {
        if (half) __syncthreads();
        const unsigned* Wp = Wp1 + half * 8192;
        #pragma unroll
        for (int i = 0; i < 8; ++i)
            *(uint4*)&Bt[(i * 256 + t) * 4] = *(const uint4*)&Wp[(i * 256 + t) * 4];
        __syncthreads();
        f32x4 acc[4];
        #pragma unroll
        for (int i = 0; i < 4; ++i) acc[i] = (f32x4){0.f, 0.f, 0.f, 0.f};
        #pragma unroll
        for (int ng = 0; ng < 4; ++ng) {
            int col = wcol + ng * 16 + (lane & 15);
            #pragma unroll
            for (int kc = 0; kc < 4; ++kc) {
                int kidx = kc * 16 + (lane >> 4) * 4;
                const short8 b = *(const short8*)((const char*)Bt +
                        ((((col << 6) + kidx) ^ ((col & 7) << 2)) << 2));
                acc[ng] = __builtin_amdgcn_mfma_f32_16x16x32_bf16(a[kc], b, acc[ng], 0, 0, 0);
            }
        }
        #pragma unroll
        for (int ng = 0; ng < 4; ++ng) {
            int col = half * 128 + wcol + ng * 16 + (lane & 15);
            float bv = b1f[col];
            int cp = col >> 1, cb = col & 1;
            #pragma unroll
            for (int r = 0; r < 4; ++r) {
                int row = wrow + (lane >> 4) * 4 + r;
                float val = acc[ng][r] + bv;
                val = 0.5f * val * (1.f + erff(val * 0.70710678118654752f));
                h16[((row << 7) + (cp ^ ((row & 7) << 2))) * 2 + cb] = f2b(val);
            }
        }
    }
    // ---- ffn2: K=256 in two chunks; wave outputs its 64 cols ----
    f32x4 accF[4];
    #pragma unroll
    for (int i = 0; i < 4; ++i) accF[i] = (f32x4){0.f, 0.f, 0.f, 0.f};
    const int lrow = wrow + (lane & 15);
    for (int c = 0; c < 2; ++c) {
        __syncthreads();
        const unsigned* Wp = Wp2 + c * 8192;
        #pragma unroll
        for (int i = 0; i < 8; ++i)
            *(uint4*)&Bt[(i * 256 + t) * 4] = *(const uint4*)&Wp[(i * 256 + t) * 4];
        __syncthreads();
        short8 ah[4];
        #pragma unroll
        for (int kc = 0; kc < 4; ++kc) {
            int cp4 = c * 64 + kc * 16 + (lane >> 4) * 4;
            ah[kc] = *(const short8*)&h1t[(lrow << 7) + (cp4 ^ ((lrow & 7) << 2))];
        }
        #pragma unroll
        for (int ng = 0; ng < 4; ++ng) {
            int col = wcol + ng * 16 + (lane & 15);
            #pragma unroll
            for (int kc = 0; kc < 4; ++kc) {
                int kidx = kc * 16 + (lane >> 4) * 4;
                const short8 b = *(const short8*)((const char*)Bt +
                        ((((col << 6) + kidx) ^ ((col & 7) << 2)) << 2));
                accF[ng] = __builtin_amdgcn_mfma_f32_16x16x32_bf16(ah[kc], b, accF[ng], 0, 0, 0);
            }
        }
    }
    // ---- residual + LN (cross-wave 64+64 col combine) ----
    float tt[4][4];
    float rs[4] = {0.f, 0.f, 0.f, 0.f}, rs2[4] = {0.f, 0.f, 0.f, 0.f};
    #pragma unroll
    for (int ng = 0; ng < 4; ++ng) {
        int col = wcol + ng * 16 + (lane & 15);
        float bv = b2f[col];
        #pragma unroll
        for (int r = 0; r < 4; ++r) {
            int grow = rowBase + wrow + (lane >> 4) * 4 + r;
            float xo = (grow < rows) ? x[(size_t)grow * DD + col] : 0.f;
            float v = accF[ng][r] + bv + xo;
            tt[ng][r] = v;
            rs[r] += v;
            rs2[r] += v * v;
        }
    }
    #pragma unroll
    for (int r = 0; r < 4; ++r) {
        #pragma unroll
        for (int m = 1; m < 16; m <<= 1) {
            rs[r] += __shfl_xor(rs[r], m);
            rs2[r] += __shfl_xor(rs2[r], m);
        }
    }
    if ((lane & 15) == 0) {
        #pragma unroll
        for (int r = 0; r < 4; ++r) {
            sRS[wid][(lane >> 4) * 4 + r] = rs[r];
            sRS2[wid][(lane >> 4) * 4 + r] = rs2[r];
        }
    }
    __syncthreads();
    unsigned short* sb16 = (unsigned short*)Bt;
    #pragma unroll
    for (int ng = 0; ng < 4; ++ng) {
        int col = wcol + ng * 16 + (lane & 15);
        float gg = g[col], bbb = bbn[col];
        int cp = col >> 1, cb = col & 1;
        #pragma unroll
        for (int r = 0; r < 4; ++r) {
            int ri = (lane >> 4) * 4 + r;
            float st = sRS[wid][ri] + sRS[wid ^ 1][ri];
            float st2 = sRS2[wid][ri] + sRS2[wid ^ 1][ri];
            int grow = rowBase + wrow + ri;
            float mean = st * (1.f / DD);
            float var = st2 * (1.f / DD) - mean * mean;
            float val = (tt[ng][r] - mean) * rsqrtf(var + 1e-5f) * gg + bbb;
            if (grow < rows) x[(size_t)grow * DD + col] = val;
            int row = wrow + ri;
            sb16[((row << 6) + (cp ^ ((row & 7) << 2))) * 2 + cb] = f2b(val);
        }
    }
    __syncthreads();
    unsigned* outw = (unsigned*)xb;
    #pragma unroll
    for (int i = 0; i < 2; ++i) {
        int j = i * 256 + t;          // uint4 index, 512 total
        int row = j >> 4, c4 = j & 15;
        uint4 v = *(const uint4*)&Bt[(row << 6) + ((c4 << 2) ^ ((row & 7) << 2))];
        int grow = rowBase + row;
        if (grow < rows) *(uint4*)&outw[(size_t)grow * 64 + (c4 << 2)] = v;
    }
}

// ---------- fused heads: MFMA hidden tile + in-block finish ----------
__global__ __launch_bounds__(256) void heads_fused(
        const unsigned short* __restrict__ xb, const unsigned* __restrict__ Whp,
        const float* __restrict__ b1cat, const float* __restrict__ cW2,
        const float* __restrict__ cb2, const float* __restrict__ bW2,
        const float* __restrict__ bb2, float* __restrict__ outc,
        float* __restrict__ outb, int rows) {
    __shared__ unsigned Bt[8192];
    __shared__ unsigned ht[4096];
    const int t = threadIdx.x;
    const int rowBase = blockIdx.x << 6;
    const int lane = t & 63, wid = t >> 6;
    const int kqo = (lane >> 4) * 8;
    #pragma unroll
    for (int i = 0; i < 8; ++i)
        *(uint4*)&Bt[(i * 256 + t) * 4] = *(const uint4*)&Whp[(i * 256 + t) * 4];
    int arow = rowBase + wid * 16 + (lane & 15);
    if (arow > rows - 1) arow = rows - 1;
    short8 a[4];
    #pragma unroll
    for (int kc = 0; kc < 4; ++kc)
        a[kc] = *(const short8*)(xb + (size_t)arow * DD + kc * 32 + kqo);
    __syncthreads();
    f32x4 acc[8];
    #pragma unroll
    for (int i = 0; i < 8; ++i) acc[i] = (f32x4){0.f, 0.f, 0.f, 0.f};
    #pragma unroll
    for (int ng = 0; ng < 8; ++ng) {
        int col = ng * 16 + (lane & 15);
        #pragma unroll
        for (int kc = 0; kc < 4; ++kc) {
            int kidx = kc * 16 + (lane >> 4) * 4;
            const short8 b = *(const short8*)((const char*)Bt +
                    ((((col << 6) + kidx) ^ ((col & 7) << 2)) << 2));
            acc[ng] = __builtin_amdgcn_mfma_f32_16x16x32_bf16(a[kc], b, acc[ng], 0, 0, 0);
        }
    }
    unsigned short* h16 = (unsigned short*)ht;
    #pragma unroll
    for (int ng = 0; ng < 8; ++ng) {
        int col = ng * 16 + (lane & 15);
        float bv = b1cat[col];
        int cp = col >> 1, cb = col & 1;
        #pragma unroll
        for (int r = 0; r < 4; ++r) {
            int row = wid * 16 + (lane >> 4) * 4 + r;
            h16[((row << 6) + (cp ^ ((row & 7) << 2))) * 2 + cb] = f2b(fmaxf(acc[ng][r] + bv, 0.f));
        }
    }
    __syncthreads();
    for (int i = t; i < 704; i += 256) {
        int n = i / 11, j = i % 11;
        int grow = rowBase + n;
        if (grow >= rows) continue;
        int sw = (n & 7) << 2;
        if (j < 4) {
            float accv = cb2[j];
            #pragma unroll 8
            for (int kp = 0; kp < 32; ++kp) {
                unsigned w = ht[(n << 6) + (kp ^ sw)];
                accv += b2f((unsigned short)w) * cW2[(2 * kp) * 4 + j];
                accv += b2f((unsigned short)(w >> 16)) * cW2[(2 * kp + 1) * 4 + j];
            }
            outc[(size_t)grow * 4 + j] = accv;
        } else {
            int jj = j - 4;
            float accv = bb2[jj];
            #pragma unroll 8
            for (int kp = 0; kp < 32; ++kp) {
                unsigned w = ht[(n << 6) + ((32 + kp) ^ sw)];
                accv += b2f((unsigned short)w) * bW2[(2 * kp) * 7 + jj];
                accv += b2f((unsigned short)(w >> 16)) * bW2[(2 * kp + 1) * 7 + jj];
            }
            outb[(size_t)grow * 7 + jj] = accv;
        }
    }
}

extern "C" void kernel_launch(void* const* d_in, const int* in_sizes, int n_in,
                              void* d_out, int out_size, void* d_ws, size_t ws_size,
                              hipStream_t stream) {
    const float* xyz   = (const float*)d_in[0];
    const float* attr  = (const float*)d_in[1];
    const int*   ei    = (const int*)d_in[2];
    const float* encW  = (const float*)d_in[3];
    const float* encb  = (const float*)d_in[4];
    const float* encg  = (const float*)d_in[5];
    const float* encbb = (const float*)d_in[6];
    const float* posW1 = (const float*)d_in[7];
    const float* posb1 = (const float*)d_in[8];
    const float* posg  = (const float*)d_in[9];
    const float* posbb = (const float*)d_in[10];
    const float* posW2 = (const float*)d_in[11];
    const float* posb2 = (const float*)d_in[12];
    const float* Wq    = (const float*)d_in[13];
    const float* bq    = (const float*)d_in[14];
    const float* Wk    = (const float*)d_in[15];
    const float* bk    = (const float*)d_in[16];
    const float* Wv    = (const float*)d_in[17];
    const float* bv    = (const float*)d_in[18];
    const float* We    = (const float*)d_in[19];
    const float* Wskip = (const float*)d_in[20];
    const float* bskip = (const float*)d_in[21];
    const float* Wbeta = (const float*)d_in[22];
    const float* ln1g  = (const float*)d_in[23];
    const float* ln1b  = (const float*)d_in[24];
    const float* ln2g  = (const float*)d_in[25];
    const float* ln2b  = (const float*)d_in[26];
    const float* fW1   = (const float*)d_in[27];
    const float* fb1   = (const float*)d_in[28];
    const float* fW2   = (const float*)d_in[29];
    const float* fb2   = (const float*)d_in[30];
    const float* cW1   = (const float*)d_in[31];
    const float* cb1   = (const float*)d_in[32];
    const float* cW2   = (const float*)d_in[33];
    const float* cb2   = (const float*)d_in[34];
    const float* bW1   = (const float*)d_in[35];
    const float* bb1   = (const float*)d_in[36];
    const float* bW2   = (const float*)d_in[37];
    const float* bb2   = (const float*)d_in[38];

    const int N = in_sizes[0] / 3;
    const int E = in_sizes[2] / 2;

    size_t off = 0;
    auto alloc = [&](size_t nelem) {
        char* p = (char*)d_ws + off;
        off += nelem * sizeof(float);
        return (float*)p;
    };
    float* x     = alloc((size_t)N * DD);
    unsigned short* qkv = (unsigned short*)alloc((size_t)N * 192);   // N*384 bf16 [q|k|v]
    float* r     = alloc((size_t)N * DD);
    unsigned short* xb = (unsigned short*)alloc((size_t)N * 64);     // N*128 bf16
    float4* rel4 = (float4*)alloc((size_t)E * 4);                    // CSR-order rel + inv
    unsigned short* eeb = (unsigned short*)alloc((size_t)E * 64);    // E*128 bf16 (CSR order)
    unsigned* W2Wep = (unsigned*)alloc(3 * 8192);                    // folded edge weights packed
    float* b2We  = alloc(3 * DD);
    unsigned* Wpall = (unsigned*)alloc(24 * 8192);                   // qkvr(12) + fW1(6) + fW2(6)
    unsigned* Whp   = (unsigned*)alloc(8192);                        // heads W1cat packed
    float* pw    = alloc(544);
    float* b1cat = alloc(DD);
    int* deg     = (int*)alloc(N);
    int* cur     = (int*)alloc(N);   // adjacent to deg: one memset covers both
    int* ptr     = (int*)alloc(N + 1);
    int* cs_src  = (int*)alloc(E);

    const int rtN = (N + 63) / 64;
    const int rtN2 = (N + 31) / 32;
    const int rtE = (E + 63) / 64;
    const int encBlocks = (N + 1) / 2;
    const int SC = (E + 255) / 256;

    // ---- preamble: 4 dispatches ----
    hipMemsetAsync(deg, 0, 2 * (size_t)N * sizeof(int), stream);
    setup1_kernel<<<encBlocks + 1 + SC, 256, 0, stream>>>(
        xyz, attr, encW, encb, encg, encbb, x, xb,
        posW1, posb1, posg, pw, ei, deg, N, E, encBlocks);
    scan_kernel<<<1, 1024, 0, stream>>>(deg, ptr, N);
    setup2_kernel<<<SC + 99 + 768 + 32 + 1, 256, 0, stream>>>(
        ei, xyz, pw, ptr, cur, cs_src, rel4, E,
        posW2, posb2, We, W2Wep, b2We,
        Wq, Wk, Wv, Wskip, fW1, fW2, Wpall,
        cW1, bW1, Whp, cb1, bb1, b1cat, SC);

    for (int l = 0; l < 3; ++l) {
        const float* Wb_l = Wbeta + (size_t)l * 3 * DD;
        B4 bs;
        bs.b[0] = bq + l * DD; bs.b[1] = bk + l * DD;
        bs.b[2] = bv + l * DD; bs.b[3] = bskip + l * DD;

        proj_kernel<<<rtE + 4 * rtN, 256, 0, stream>>>(
            xb, Wpall + (size_t)l * 4 * 8192, bs, qkv, r, N, rtN,
            rel4, pw, posbb, W2Wep + l * 8192, b2We + l * DD, eeb, E, rtE);

        aggc_kernel<<<N, 256, 0, stream>>>((const unsigned*)qkv, (const unsigned*)eeb,
                                           ptr, cs_src, r, Wb_l,
                                           ln1g + l * DD, ln1b + l * DD,
                                           x, (unsigned*)xb, N);

        ffn_fused<<<rtN2, 256, 0, stream>>>(xb, Wpall + (size_t)(12 + 2 * l) * 8192,
                                            fb1 + l * 256, Wpall + (size_t)(18 + 2 * l) * 8192,
                                            fb2 + l * DD, ln2g + l * DD, ln2b + l * DD,
                                            x, xb, N);
    }

    // ---- heads (single fused dispatch) ----
    float* outc  = (float*)d_out;
    float* outbx = (float*)d_out + (size_t)N * 4;
    heads_fused<<<rtN, 256, 0, stream>>>(xb, Whp, b1cat, cW2, cb2, bW2, bb2,
                                         outc, outbx, N);
}